// Round 2
// baseline (10671.400 us; speedup 1.0000x reference)
//
#include <hip/hip_runtime.h>
#include <hip/hip_bf16.h>
#include <float.h>

// Problem constants (from reference setup_inputs)
#define B_   4
#define N_   4096
#define J_   24
#define KR_  4
#define KNN_ 20
#define SLOPE 0.2f

// ---------- per-point squared norm + transpose to [B,C,N] ----------
__global__ void k_prep(const float* __restrict__ h, float* __restrict__ xx,
                       float* __restrict__ hT, int C) {
    int i = blockIdx.x * blockDim.x + threadIdx.x;  // b*N + n
    if (i >= B_ * N_) return;
    int b = i / N_, n = i % N_;
    const float* hp = h + (size_t)i * C;
    float s = 0.f;
    for (int c = 0; c < C; ++c) {
        float v = hp[c];
        s += v * v;
        hT[((size_t)b * C + c) * N_ + n] = v;
    }
    xx[i] = s;
}

// ---------- kNN: one block per (b,n); distances in LDS; 20 argmin rounds ----------
__global__ __launch_bounds__(256) void k_knn(const float* __restrict__ hT,
                                             const float* __restrict__ xx,
                                             int C, int* __restrict__ idx) {
    __shared__ float center[128];
    __shared__ float d[N_];
    __shared__ float rv[256];
    __shared__ int   ri[256];

    int bn = blockIdx.x;              // b*N + n
    int b  = bn >> 12;
    int n  = bn & (N_ - 1);
    int tid = threadIdx.x;

    const float* hTb = hT + (size_t)b * C * N_;
    for (int c = tid; c < C; c += 256) center[c] = hTb[(size_t)c * N_ + n];
    __syncthreads();

    float xxn = xx[bn];
    const float* xxb = xx + b * N_;
    for (int m = tid; m < N_; m += 256) {
        float dot = 0.f;
        for (int c = 0; c < C; ++c) dot += hTb[(size_t)c * N_ + m] * center[c];
        d[m] = xxn + xxb[m] - 2.f * dot;
    }
    __syncthreads();

    for (int kk = 0; kk < KNN_; ++kk) {
        float bv = FLT_MAX; int bi = N_;
        for (int m = tid; m < N_; m += 256) {
            float v = d[m];
            if (v < bv || (v == bv && m < bi)) { bv = v; bi = m; }
        }
        rv[tid] = bv; ri[tid] = bi;
        __syncthreads();
        for (int s = 128; s > 0; s >>= 1) {
            if (tid < s) {
                float ov = rv[tid + s]; int oi = ri[tid + s];
                if (ov < rv[tid] || (ov == rv[tid] && oi < ri[tid])) { rv[tid] = ov; ri[tid] = oi; }
            }
            __syncthreads();
        }
        if (tid == 0) {
            idx[(size_t)bn * KNN_ + kk] = ri[0];
            d[ri[0]] = FLT_MAX;
        }
        __syncthreads();
    }
}

// ---------- generic edge conv: grid = B*R blocks, blockDim = O ----------
// out[b,r,o] = leaky( max_k sum_c w[o,c]*(h[b,idx[b,r,k],c]-h[b,r,c]) + sum_c w[o,C+c]*h[b,r,c] + bias[o] )
__global__ void k_edgeconv(const float* __restrict__ h, int C, int R,
                           const int* __restrict__ idx, int kcount,
                           const float* __restrict__ w,
                           const float* __restrict__ bias,
                           float* __restrict__ out) {
    extern __shared__ float sm[];       // center[C] + diff[C]
    float* center = sm;
    float* diff   = sm + C;

    int br = blockIdx.x;                // b*R + r
    int b  = br / R;
    int tid = threadIdx.x;              // output channel o
    int O = blockDim.x;

    const float* cen = h + (size_t)br * C;
    for (int c = tid; c < C; c += O) center[c] = cen[c];
    __syncthreads();

    const float* wrow = w + (size_t)tid * 2 * C;
    float base = bias[tid];
    for (int c = 0; c < C; ++c) base += wrow[C + c] * center[c];

    float best = -FLT_MAX;
    const int* ip = idx + (size_t)br * kcount;
    const float* hb = h + (size_t)b * R * C;
    for (int k = 0; k < kcount; ++k) {
        int m = ip[k];
        const float* nb = hb + (size_t)m * C;
        __syncthreads();                             // protect diff[] from previous iter readers
        for (int c = tid; c < C; c += O) diff[c] = nb[c] - center[c];
        __syncthreads();
        float v = 0.f;
        for (int c = 0; c < C; ++c) v += wrow[c] * diff[c];
        best = fmaxf(best, v);
    }
    float r = base + best;                           // max then leaky (monotonic)
    out[(size_t)br * O + tid] = r >= 0.f ? r : SLOPE * r;
}

// ---------- weighted pooling onto joints: grid = B*J, 256 threads ----------
__global__ __launch_bounds__(256) void k_pool(const float* __restrict__ Vf,
                                              const float* __restrict__ l1,
                                              const float* __restrict__ l2,
                                              const float* __restrict__ l3,
                                              const float* __restrict__ W,
                                              float* __restrict__ pooled) {
    __shared__ float red[256];
    int bj = blockIdx.x;
    int b  = bj / J_;
    int tid = threadIdx.x;
    const float* Wp = W + (size_t)bj * N_;

    // sum of weights
    float s = 0.f;
    for (int n = tid; n < N_; n += 256) s += Wp[n];
    red[tid] = s; __syncthreads();
    for (int st = 128; st > 0; st >>= 1) {
        if (tid < st) red[tid] += red[tid + st];
        __syncthreads();
    }
    float inv = 1.f / (red[0] + 1e-5f);

    // channel -> (base ptr, stride)
    auto chan = [&](int c, const float*& p, int& st) {
        if (c < 3)        { st = 3;   p = Vf + (size_t)b * N_ * 3   + c; }
        else if (c < 67)  { st = 64;  p = l1 + (size_t)b * N_ * 64  + (c - 3); }
        else if (c < 195) { st = 128; p = l2 + (size_t)b * N_ * 128 + (c - 67); }
        else              { st = 256; p = l3 + (size_t)b * N_ * 256 + (c - 195); }
    };

    int c0 = tid, c1 = tid + 256;
    const float *p0 = nullptr, *p1 = nullptr; int s0 = 0, s1 = 0;
    chan(c0, p0, s0);
    bool has1 = (c1 < 451);
    if (has1) chan(c1, p1, s1);

    float a0 = 0.f, a1 = 0.f;
    for (int n = 0; n < N_; ++n) {
        float wv = Wp[n];
        a0 += wv * p0[(size_t)n * s0];
        if (has1) a1 += wv * p1[(size_t)n * s1];
    }
    pooled[(size_t)bj * 451 + c0] = a0 * inv;
    if (has1) pooled[(size_t)bj * 451 + c1] = a1 * inv;
}

// ---------- joint MLP: grid = B*J, 256 threads ----------
__global__ __launch_bounds__(256) void k_mlp(const float* __restrict__ v1,
                                             const float* __restrict__ v2,
                                             const float* __restrict__ v3,
                                             const float* __restrict__ w1,
                                             const float* __restrict__ b1,
                                             const float* __restrict__ w2,
                                             const float* __restrict__ b2,
                                             const float* __restrict__ w3,
                                             const float* __restrict__ b3,
                                             float* __restrict__ out) {
    __shared__ float jn[448];
    __shared__ float h1[512];
    __shared__ float h2[256];
    int bj = blockIdx.x;
    int tid = threadIdx.x;

    jn[tid] = v1[(size_t)bj * 256 + tid];
    if (tid < 128) jn[256 + tid] = v2[(size_t)bj * 128 + tid];
    if (tid < 64)  jn[384 + tid] = v3[(size_t)bj * 64 + tid];
    __syncthreads();

    for (int o = tid; o < 512; o += 256) {
        float s = b1[o];
        const float* wr = w1 + (size_t)o * 448;
        for (int c = 0; c < 448; ++c) s += wr[c] * jn[c];
        h1[o] = s >= 0.f ? s : SLOPE * s;
    }
    __syncthreads();
    {
        float s = b2[tid];
        const float* wr = w2 + (size_t)tid * 512;
        for (int c = 0; c < 512; ++c) s += wr[c] * h1[c];
        h2[tid] = s >= 0.f ? s : SLOPE * s;
    }
    __syncthreads();
    if (tid < 3) {
        float s = b3[tid];
        const float* wr = w3 + (size_t)tid * 256;
        for (int c = 0; c < 256; ++c) s += wr[c] * h2[c];
        out[bj * 3 + tid] = s;
    }
}

extern "C" void kernel_launch(void* const* d_in, const int* in_sizes, int n_in,
                              void* d_out, int out_size, void* d_ws, size_t ws_size,
                              hipStream_t stream) {
    const float* V  = (const float*)d_in[0];   // [4,4096,3]
    const float* W  = (const float*)d_in[1];   // [4,24,4096]
    const int* ringIdx = (const int*)d_in[2];  // [4,24,4]
    const float* g1w = (const float*)d_in[3];
    const float* g1b = (const float*)d_in[4];
    const float* g2w = (const float*)d_in[5];
    const float* g2b = (const float*)d_in[6];
    const float* g3w = (const float*)d_in[7];
    const float* g3b = (const float*)d_in[8];
    const float* s1w = (const float*)d_in[9];
    const float* s1b = (const float*)d_in[10];
    const float* s2w = (const float*)d_in[11];
    const float* s2b = (const float*)d_in[12];
    const float* s3w = (const float*)d_in[13];
    const float* s3b = (const float*)d_in[14];
    const float* m1w = (const float*)d_in[15];
    const float* m1b = (const float*)d_in[16];
    const float* m2w = (const float*)d_in[17];
    const float* m2b = (const float*)d_in[18];
    const float* m3w = (const float*)d_in[19];
    const float* m3b = (const float*)d_in[20];

    // workspace layout (f32), ~39 MB total
    float* ws = (float*)d_ws;
    size_t off = 0;
    float* l1 = ws + off; off += (size_t)B_ * N_ * 64;
    float* l2 = ws + off; off += (size_t)B_ * N_ * 128;
    float* l3 = ws + off; off += (size_t)B_ * N_ * 256;
    float* xx = ws + off; off += (size_t)B_ * N_;
    float* hT = ws + off; off += (size_t)B_ * 128 * N_;
    int* knnIdx = (int*)(ws + off); off += (size_t)B_ * N_ * KNN_;
    float* pooled = ws + off; off += (size_t)B_ * J_ * 451;
    float* v1 = ws + off; off += (size_t)B_ * J_ * 256;
    float* v2 = ws + off; off += (size_t)B_ * J_ * 128;
    float* v3 = ws + off; off += (size_t)B_ * J_ * 64;
    (void)ws_size; (void)n_in; (void)in_sizes; (void)out_size;

    // ---- geoNet layer 1 (C=3 -> O=64)
    k_prep<<<(B_ * N_ + 255) / 256, 256, 0, stream>>>(V, xx, hT, 3);
    k_knn<<<B_ * N_, 256, 0, stream>>>(hT, xx, 3, knnIdx);
    k_edgeconv<<<B_ * N_, 64, 2 * 3 * sizeof(float), stream>>>(V, 3, N_, knnIdx, KNN_, g1w, g1b, l1);

    // ---- layer 2 (C=64 -> O=128)
    k_prep<<<(B_ * N_ + 255) / 256, 256, 0, stream>>>(l1, xx, hT, 64);
    k_knn<<<B_ * N_, 256, 0, stream>>>(hT, xx, 64, knnIdx);
    k_edgeconv<<<B_ * N_, 128, 2 * 64 * sizeof(float), stream>>>(l1, 64, N_, knnIdx, KNN_, g2w, g2b, l2);

    // ---- layer 3 (C=128 -> O=256)
    k_prep<<<(B_ * N_ + 255) / 256, 256, 0, stream>>>(l2, xx, hT, 128);
    k_knn<<<B_ * N_, 256, 0, stream>>>(hT, xx, 128, knnIdx);
    k_edgeconv<<<B_ * N_, 256, 2 * 128 * sizeof(float), stream>>>(l2, 128, N_, knnIdx, KNN_, g3w, g3b, l3);

    // ---- pooling onto joints
    k_pool<<<B_ * J_, 256, 0, stream>>>(V, l1, l2, l3, W, pooled);

    // ---- skeleton edge convs (fixed one-ring, KR=4)
    k_edgeconv<<<B_ * J_, 256, 2 * 451 * sizeof(float), stream>>>(pooled, 451, J_, ringIdx, KR_, s1w, s1b, v1);
    k_edgeconv<<<B_ * J_, 128, 2 * 256 * sizeof(float), stream>>>(v1, 256, J_, ringIdx, KR_, s2w, s2b, v2);
    k_edgeconv<<<B_ * J_, 64, 2 * 128 * sizeof(float), stream>>>(v2, 128, J_, ringIdx, KR_, s3w, s3b, v3);

    // ---- joint MLP -> output [4,24,3] f32
    k_mlp<<<B_ * J_, 256, 0, stream>>>(v1, v2, v3, m1w, m1b, m2w, m2b, m3w, m3b,
                                       (float*)d_out);
}

// Round 3
// 4750.303 us; speedup vs baseline: 2.2465x; 2.2465x over previous
//
#include <hip/hip_runtime.h>
#include <hip/hip_bf16.h>
#include <float.h>

// Problem constants (from reference setup_inputs)
#define B_   4
#define N_   4096
#define J_   24
#define KR_  4
#define KNN_ 20
#define SLOPE 0.2f

// ---------- per-point squared norm + transpose to [B,C,N] ----------
__global__ void k_prep(const float* __restrict__ h, float* __restrict__ xx,
                       float* __restrict__ hT, int C) {
    int i = blockIdx.x * blockDim.x + threadIdx.x;  // b*N + n
    if (i >= B_ * N_) return;
    int b = i / N_, n = i % N_;
    const float* hp = h + (size_t)i * C;
    float s = 0.f;
    for (int c = 0; c < C; ++c) {
        float v = hp[c];
        s += v * v;
        hT[((size_t)b * C + c) * N_ + n] = v;
    }
    xx[i] = s;
}

// ---------- kNN: one block per (b,n); distances in LDS; 20 argmin rounds ----------
__global__ __launch_bounds__(256) void k_knn(const float* __restrict__ hT,
                                             const float* __restrict__ xx,
                                             int C, int* __restrict__ idx) {
    __shared__ float center[128];
    __shared__ float d[N_];
    __shared__ float rv[256];
    __shared__ int   ri[256];

    int bn = blockIdx.x;              // b*N + n
    int b  = bn >> 12;
    int n  = bn & (N_ - 1);
    int tid = threadIdx.x;

    const float* hTb = hT + (size_t)b * C * N_;
    for (int c = tid; c < C; c += 256) center[c] = hTb[(size_t)c * N_ + n];
    __syncthreads();

    float xxn = xx[bn];
    const float* xxb = xx + b * N_;
    for (int m = tid; m < N_; m += 256) {
        float dot = 0.f;
        for (int c = 0; c < C; ++c) dot += hTb[(size_t)c * N_ + m] * center[c];
        d[m] = xxn + xxb[m] - 2.f * dot;
    }
    __syncthreads();

    for (int kk = 0; kk < KNN_; ++kk) {
        float bv = FLT_MAX; int bi = N_;
        for (int m = tid; m < N_; m += 256) {
            float v = d[m];
            if (v < bv || (v == bv && m < bi)) { bv = v; bi = m; }
        }
        rv[tid] = bv; ri[tid] = bi;
        __syncthreads();
        for (int s = 128; s > 0; s >>= 1) {
            if (tid < s) {
                float ov = rv[tid + s]; int oi = ri[tid + s];
                if (ov < rv[tid] || (ov == rv[tid] && oi < ri[tid])) { rv[tid] = ov; ri[tid] = oi; }
            }
            __syncthreads();
        }
        if (tid == 0) {
            idx[(size_t)bn * KNN_ + kk] = ri[0];
            d[ri[0]] = FLT_MAX;
        }
        __syncthreads();
    }
}

// ---------- build projection P[K=C][2O]: [wA^T | (wB-wA)^T], bias2[2O]=[0|bias] ----------
__global__ void k_prepP(const float* __restrict__ w, const float* __restrict__ bias,
                        int C, int O, float* __restrict__ P, float* __restrict__ bias2) {
    int i = blockIdx.x * blockDim.x + threadIdx.x;
    int O2 = 2 * O;
    if (i < O2) bias2[i] = (i < O) ? 0.f : bias[i - O];
    int total = C * O2;
    if (i >= total) return;
    int k = i / O2, col = i % O2;
    float v;
    if (col < O) {
        v = w[(size_t)col * 2 * C + k];                       // wA^T
    } else {
        int o = col - O;
        v = w[(size_t)o * 2 * C + C + k] - w[(size_t)o * 2 * C + k];  // (wB - wA)^T
    }
    P[i] = v;
}

// ---------- transpose w[O][K] -> wT[K][O] ----------
__global__ void k_transp(const float* __restrict__ w, int O, int K, float* __restrict__ wT) {
    int i = blockIdx.x * blockDim.x + threadIdx.x;
    if (i >= O * K) return;
    int k = i / O, o = i % O;
    wT[i] = w[(size_t)o * K + k];
}

// ---------- tiled f32 GEMM: C[M,N] = A[M,K](lda) @ Bm[K,N] (+bias per col, opt leaky) ----------
__global__ __launch_bounds__(256) void k_gemm(const float* __restrict__ A, int lda,
                                              const float* __restrict__ Bm,
                                              float* __restrict__ Cm, int ldc,
                                              int M, int N, int K,
                                              const float* __restrict__ bias, int leaky) {
    __shared__ float As[16][65];
    __shared__ float Bs[16][64];
    int tid = threadIdx.x;
    int row0 = blockIdx.y * 64, col0 = blockIdx.x * 64;
    int tr = tid >> 4, tc = tid & 15;
    float acc[4][4] = {{0.f}};
    for (int kt = 0; kt < K; kt += 16) {
#pragma unroll
        for (int i = 0; i < 4; ++i) {           // A tile: 64 rows x 16 k
            int e = tid + 256 * i;
            int r = e >> 4, kk = e & 15;
            int gr = row0 + r, gk = kt + kk;
            float v = 0.f;
            if (gr < M && gk < K) v = A[(size_t)gr * lda + gk];
            As[kk][r] = v;
        }
#pragma unroll
        for (int i = 0; i < 4; ++i) {           // B tile: 16 k x 64 cols
            int e = tid + 256 * i;
            int kk = e >> 6, c = e & 63;
            int gk = kt + kk, gc = col0 + c;
            float v = 0.f;
            if (gk < K && gc < N) v = Bm[(size_t)gk * N + gc];
            Bs[kk][c] = v;
        }
        __syncthreads();
#pragma unroll
        for (int kk = 0; kk < 16; ++kk) {
            float a[4], bv[4];
#pragma unroll
            for (int i = 0; i < 4; ++i) a[i] = As[kk][tr + 16 * i];
#pragma unroll
            for (int j = 0; j < 4; ++j) bv[j] = Bs[kk][tc + 16 * j];
#pragma unroll
            for (int i = 0; i < 4; ++i)
#pragma unroll
                for (int j = 0; j < 4; ++j) acc[i][j] += a[i] * bv[j];
        }
        __syncthreads();
    }
#pragma unroll
    for (int i = 0; i < 4; ++i) {
        int r = row0 + tr + 16 * i;
        if (r >= M) continue;
#pragma unroll
        for (int j = 0; j < 4; ++j) {
            int c = col0 + tc + 16 * j;
            if (c >= N) continue;
            float v = acc[i][j];
            if (bias) v += bias[c];
            if (leaky) v = v >= 0.f ? v : SLOPE * v;
            Cm[(size_t)r * ldc + c] = v;
        }
    }
}

// ---------- gather-max epilogue: out[r, ooff+o] = leaky(Z[r,o] + max_k Y1[idx[r,k],o]) ----------
// Y layout [B*R][2O]: cols [0,O) = Y1 (no bias), cols [O,2O) = Z (bias already added by GEMM)
__global__ void k_gathermax(const float* __restrict__ Y, int O, int R,
                            const int* __restrict__ idx, int kc,
                            float* __restrict__ out, int ldo, int ooff) {
    extern __shared__ int sidx[];
    int br = blockIdx.x;
    int b  = br / R;
    int o  = threadIdx.x;
    if (o < kc) sidx[o] = idx[(size_t)br * kc + o];
    __syncthreads();
    int O2 = 2 * O;
    float z = Y[(size_t)br * O2 + O + o];
    float best = -FLT_MAX;
    for (int k = 0; k < kc; ++k) {
        int m = sidx[k];
        best = fmaxf(best, Y[(size_t)(b * R + m) * O2 + o]);
    }
    float r = z + best;
    out[(size_t)br * ldo + ooff + o] = r >= 0.f ? r : SLOPE * r;
}

// ---------- weighted pooling onto joints: grid = B*J, 256 threads ----------
__global__ __launch_bounds__(256) void k_pool(const float* __restrict__ Vf,
                                              const float* __restrict__ l1,
                                              const float* __restrict__ l2,
                                              const float* __restrict__ l3,
                                              const float* __restrict__ W,
                                              float* __restrict__ pooled) {
    __shared__ float red[256];
    int bj = blockIdx.x;
    int b  = bj / J_;
    int tid = threadIdx.x;
    const float* Wp = W + (size_t)bj * N_;

    float s = 0.f;
    for (int n = tid; n < N_; n += 256) s += Wp[n];
    red[tid] = s; __syncthreads();
    for (int st = 128; st > 0; st >>= 1) {
        if (tid < st) red[tid] += red[tid + st];
        __syncthreads();
    }
    float inv = 1.f / (red[0] + 1e-5f);

    auto chan = [&](int c, const float*& p, int& st) {
        if (c < 3)        { st = 3;   p = Vf + (size_t)b * N_ * 3   + c; }
        else if (c < 67)  { st = 64;  p = l1 + (size_t)b * N_ * 64  + (c - 3); }
        else if (c < 195) { st = 128; p = l2 + (size_t)b * N_ * 128 + (c - 67); }
        else              { st = 256; p = l3 + (size_t)b * N_ * 256 + (c - 195); }
    };

    int c0 = tid, c1 = tid + 256;
    const float *p0 = nullptr, *p1 = nullptr; int s0 = 0, s1 = 0;
    chan(c0, p0, s0);
    bool has1 = (c1 < 451);
    if (has1) chan(c1, p1, s1);

    float a0 = 0.f, a1 = 0.f;
    for (int n = 0; n < N_; ++n) {
        float wv = Wp[n];
        a0 += wv * p0[(size_t)n * s0];
        if (has1) a1 += wv * p1[(size_t)n * s1];
    }
    pooled[(size_t)bj * 451 + c0] = a0 * inv;
    if (has1) pooled[(size_t)bj * 451 + c1] = a1 * inv;
}

extern "C" void kernel_launch(void* const* d_in, const int* in_sizes, int n_in,
                              void* d_out, int out_size, void* d_ws, size_t ws_size,
                              hipStream_t stream) {
    const float* V  = (const float*)d_in[0];   // [4,4096,3]
    const float* W  = (const float*)d_in[1];   // [4,24,4096]
    const int* ringIdx = (const int*)d_in[2];  // [4,24,4]
    const float* g1w = (const float*)d_in[3];
    const float* g1b = (const float*)d_in[4];
    const float* g2w = (const float*)d_in[5];
    const float* g2b = (const float*)d_in[6];
    const float* g3w = (const float*)d_in[7];
    const float* g3b = (const float*)d_in[8];
    const float* s1w = (const float*)d_in[9];
    const float* s1b = (const float*)d_in[10];
    const float* s2w = (const float*)d_in[11];
    const float* s2b = (const float*)d_in[12];
    const float* s3w = (const float*)d_in[13];
    const float* s3b = (const float*)d_in[14];
    const float* m1w = (const float*)d_in[15];
    const float* m1b = (const float*)d_in[16];
    const float* m2w = (const float*)d_in[17];
    const float* m2b = (const float*)d_in[18];
    const float* m3w = (const float*)d_in[19];
    const float* m3b = (const float*)d_in[20];
    (void)ws_size; (void)n_in; (void)in_sizes; (void)out_size;

    // ---- workspace layout (floats) ----
    float* ws = (float*)d_ws;
    size_t off = 0;
    float* l1 = ws + off; off += (size_t)B_ * N_ * 64;    // 4MB
    float* l2 = ws + off; off += (size_t)B_ * N_ * 128;   // 8MB
    float* l3 = ws + off; off += (size_t)B_ * N_ * 256;   // 16MB
    float* xx = ws + off; off += (size_t)B_ * N_;
    // hT (8MB) and Y (32MB) alias: hT consumed by k_knn before k_gemm writes Y;
    // next layer's k_prep writes hT only after previous gathermax consumed Y.
    float* Y  = ws + off; off += (size_t)B_ * N_ * 512;   // 32MB (also used as hT)
    float* hT = Y;
    int* knnIdx = (int*)(ws + off); off += (size_t)B_ * N_ * KNN_;
    float* pooled = ws + off; off += (size_t)B_ * J_ * 451;
    float* joints = ws + off; off += (size_t)B_ * J_ * 448;
    float* h1 = ws + off; off += (size_t)B_ * J_ * 512;
    float* h2 = ws + off; off += (size_t)B_ * J_ * 256;
    float* P  = ws + off; off += (size_t)451 * 512;       // reused for all P / wT
    float* bias2 = ws + off; off += 512;

    const int M = B_ * N_;   // 16384
    const int MJ = B_ * J_;  // 96

    // ======== geoNet layer 1: C=3 -> O=64 ========
    k_prep<<<(M + 255) / 256, 256, 0, stream>>>(V, xx, hT, 3);
    k_knn<<<M, 256, 0, stream>>>(hT, xx, 3, knnIdx);
    k_prepP<<<(3 * 128 + 255) / 256, 256, 0, stream>>>(g1w, g1b, 3, 64, P, bias2);
    k_gemm<<<dim3(2, M / 64), 256, 0, stream>>>(V, 3, P, Y, 128, M, 128, 3, bias2, 0);
    k_gathermax<<<M, 64, KNN_ * sizeof(int), stream>>>(Y, 64, N_, knnIdx, KNN_, l1, 64, 0);

    // ======== layer 2: C=64 -> O=128 ========
    k_prep<<<(M + 255) / 256, 256, 0, stream>>>(l1, xx, hT, 64);
    k_knn<<<M, 256, 0, stream>>>(hT, xx, 64, knnIdx);
    k_prepP<<<(64 * 256 + 255) / 256, 256, 0, stream>>>(g2w, g2b, 64, 128, P, bias2);
    k_gemm<<<dim3(4, M / 64), 256, 0, stream>>>(l1, 64, P, Y, 256, M, 256, 64, bias2, 0);
    k_gathermax<<<M, 128, KNN_ * sizeof(int), stream>>>(Y, 128, N_, knnIdx, KNN_, l2, 128, 0);

    // ======== layer 3: C=128 -> O=256 ========
    k_prep<<<(M + 255) / 256, 256, 0, stream>>>(l2, xx, hT, 128);
    k_knn<<<M, 256, 0, stream>>>(hT, xx, 128, knnIdx);
    k_prepP<<<(128 * 512 + 255) / 256, 256, 0, stream>>>(g3w, g3b, 128, 256, P, bias2);
    k_gemm<<<dim3(8, M / 64), 256, 0, stream>>>(l2, 128, P, Y, 512, M, 512, 128, bias2, 0);
    k_gathermax<<<M, 256, KNN_ * sizeof(int), stream>>>(Y, 256, N_, knnIdx, KNN_, l3, 256, 0);

    // ======== pooling onto joints ========
    k_pool<<<MJ, 256, 0, stream>>>(V, l1, l2, l3, W, pooled);

    // ======== skeleton conv 1: C=451 -> O=256 ========
    k_prepP<<<(451 * 512 + 255) / 256, 256, 0, stream>>>(s1w, s1b, 451, 256, P, bias2);
    k_gemm<<<dim3(8, 2), 256, 0, stream>>>(pooled, 451, P, Y, 512, MJ, 512, 451, bias2, 0);
    k_gathermax<<<MJ, 256, KR_ * sizeof(int), stream>>>(Y, 256, J_, ringIdx, KR_, joints, 448, 0);

    // ======== skeleton conv 2: C=256 -> O=128 ========
    k_prepP<<<(256 * 256 + 255) / 256, 256, 0, stream>>>(s2w, s2b, 256, 128, P, bias2);
    k_gemm<<<dim3(4, 2), 256, 0, stream>>>(joints, 448, P, Y, 256, MJ, 256, 256, bias2, 0);
    k_gathermax<<<MJ, 128, KR_ * sizeof(int), stream>>>(Y, 128, J_, ringIdx, KR_, joints, 448, 256);

    // ======== skeleton conv 3: C=128 -> O=64 ========
    k_prepP<<<(128 * 128 + 255) / 256, 256, 0, stream>>>(s3w, s3b, 128, 64, P, bias2);
    k_gemm<<<dim3(2, 2), 256, 0, stream>>>(joints + 256, 448, P, Y, 128, MJ, 128, 128, bias2, 0);
    k_gathermax<<<MJ, 64, KR_ * sizeof(int), stream>>>(Y, 64, J_, ringIdx, KR_, joints, 448, 384);

    // ======== joint MLP ========
    k_transp<<<(512 * 448 + 255) / 256, 256, 0, stream>>>(m1w, 512, 448, P);
    k_gemm<<<dim3(8, 2), 256, 0, stream>>>(joints, 448, P, h1, 512, MJ, 512, 448, m1b, 1);
    k_transp<<<(256 * 512 + 255) / 256, 256, 0, stream>>>(m2w, 256, 512, P);
    k_gemm<<<dim3(4, 2), 256, 0, stream>>>(h1, 512, P, h2, 256, MJ, 256, 512, m2b, 1);
    k_transp<<<(3 * 256 + 255) / 256, 256, 0, stream>>>(m3w, 3, 256, P);
    k_gemm<<<dim3(1, 2), 256, 0, stream>>>(h2, 256, P, (float*)d_out, 3, MJ, 3, 256, m3b, 0);
}

// Round 5
// 4702.338 us; speedup vs baseline: 2.2694x; 1.0102x over previous
//
#include <hip/hip_runtime.h>
#include <hip/hip_bf16.h>
#include <float.h>

// Problem constants (from reference setup_inputs)
#define B_   4
#define N_   4096
#define J_   24
#define KR_  4
#define KNN_ 20
#define SLOPE 0.2f
#define ROWT 2048   // rows per distance slab (slab = ROWT x N_ f32 = 32 MB)

// ---------- per-point squared norm ----------
__global__ void k_norm(const float* __restrict__ h, float* __restrict__ xx, int C) {
    int i = blockIdx.x * blockDim.x + threadIdx.x;  // b*N + n
    if (i >= B_ * N_) return;
    const float* hp = h + (size_t)i * C;
    float s = 0.f;
    for (int c = 0; c < C; ++c) { float v = hp[c]; s += v * v; }
    xx[i] = s;
}

// ---------- distance GEMM, one row-slab of one batch ----------
// D[grow-rowbase, m] = xx[grow] + xx[m] - 2*dot(X[grow], X[m])
// 128x128 tile, 8x8 register block, float4 LDS reads. LDS rows are 128 wide (+8 pad).
__global__ __launch_bounds__(256) void k_dist(const float* __restrict__ X, int C,
                                              const float* __restrict__ xxb,
                                              float* __restrict__ D, int rowbase) {
    __shared__ float As[16][136];   // [k][row], 136*4=544B rows: float4-aligned
    __shared__ float Bs[16][136];
    int tid = threadIdx.x;
    int row0 = rowbase + blockIdx.y * 128;   // global row
    int col0 = blockIdx.x * 128;             // global col
    int tr = tid >> 4, tc = tid & 15;
    float acc[8][8] = {{0.f}};
    for (int kt = 0; kt < C; kt += 16) {
#pragma unroll
        for (int i = 0; i < 8; ++i) {
            int e = tid + 256 * i;
            int r = e >> 4, kk = e & 15;     // r in [0,128), kk in [0,16)
            int gk = kt + kk;
            As[kk][r] = (gk < C) ? X[(size_t)(row0 + r) * C + gk] : 0.f;
            Bs[kk][r] = (gk < C) ? X[(size_t)(col0 + r) * C + gk] : 0.f;
        }
        __syncthreads();
#pragma unroll
        for (int kk = 0; kk < 16; ++kk) {
            float a[8], bv[8];
            *(float4*)&a[0]  = *(const float4*)&As[kk][tr * 8];
            *(float4*)&a[4]  = *(const float4*)&As[kk][tr * 8 + 4];
            *(float4*)&bv[0] = *(const float4*)&Bs[kk][tc * 8];
            *(float4*)&bv[4] = *(const float4*)&Bs[kk][tc * 8 + 4];
#pragma unroll
            for (int i = 0; i < 8; ++i)
#pragma unroll
                for (int j = 0; j < 8; ++j) acc[i][j] += a[i] * bv[j];
        }
        __syncthreads();
    }
    float xc[8];
#pragma unroll
    for (int j = 0; j < 8; ++j) xc[j] = xxb[col0 + tc * 8 + j];
#pragma unroll
    for (int i = 0; i < 8; ++i) {
        int grow = row0 + tr * 8 + i;
        float xr = xxb[grow];
        float4 o0, o1;
        o0.x = xr + xc[0] - 2.f * acc[i][0];
        o0.y = xr + xc[1] - 2.f * acc[i][1];
        o0.z = xr + xc[2] - 2.f * acc[i][2];
        o0.w = xr + xc[3] - 2.f * acc[i][3];
        o1.x = xr + xc[4] - 2.f * acc[i][4];
        o1.y = xr + xc[5] - 2.f * acc[i][5];
        o1.z = xr + xc[6] - 2.f * acc[i][6];
        o1.w = xr + xc[7] - 2.f * acc[i][7];
        float* dp = D + (size_t)(grow - rowbase) * N_ + col0 + tc * 8;
        *(float4*)dp       = o0;
        *(float4*)(dp + 4) = o1;
    }
}

// ---------- top-20 selection: one wave per query, u64-key tournament ----------
// key = (monotone_map(dist) << 32) | index -> u64 min == (smallest dist, then smallest idx)
__device__ __forceinline__ unsigned mapf(float f) {
    unsigned u = __float_as_uint(f);
    return (u & 0x80000000u) ? ~u : (u | 0x80000000u);
}

__global__ __launch_bounds__(256) void k_select(const float* __restrict__ Db,
                                                int* __restrict__ idxout, int qbase) {
    const unsigned long long SENT = ~0ull;
    int ql   = blockIdx.x * 4 + (threadIdx.x >> 6);   // local row in slab
    int lane = threadIdx.x & 63;
    const float* row = Db + (size_t)ql * N_;
    int qg = qbase + ql;                              // global query in batch

    unsigned long long b0 = SENT, b1 = SENT;
    unsigned long long emask = 0;                     // popped elements of my chunk
#pragma unroll 8
    for (int j = 0; j < 64; ++j) {
        float v = row[j * 64 + lane];                 // coalesced
        unsigned long long key = ((unsigned long long)mapf(v) << 32) | (unsigned)(j * 64 + lane);
        if (key < b1) { if (key < b0) { b1 = b0; b0 = key; } else b1 = key; }
    }
    for (int k = 0; k < KNN_; ++k) {
        if (b0 == SENT) {                             // rare refill
            b1 = SENT;
            for (int j = 0; j < 64; ++j) {
                if ((emask >> j) & 1ull) continue;
                float v = row[j * 64 + lane];
                unsigned long long key = ((unsigned long long)mapf(v) << 32) | (unsigned)(j * 64 + lane);
                if (key < b1) { if (key < b0) { b1 = b0; b0 = key; } else b1 = key; }
            }
        }
        unsigned long long m = b0;
#pragma unroll
        for (int s = 32; s > 0; s >>= 1) {
            unsigned long long o = (unsigned long long)__shfl_xor((long long)m, s, 64);
            if (o < m) m = o;
        }
        unsigned idx = (unsigned)(m & 0xFFFFFFFFull);
        if (lane == (int)(idx & 63u)) {               // owner pops
            emask |= 1ull << (idx >> 6);
            b0 = b1; b1 = SENT;
        }
        if (lane == 0) idxout[qg * KNN_ + k] = (int)idx;
    }
}

// ---------- build projection P[K=C][2O]: [wA^T | (wB-wA)^T], bias2[2O]=[0|bias] ----------
__global__ void k_prepP(const float* __restrict__ w, const float* __restrict__ bias,
                        int C, int O, float* __restrict__ P, float* __restrict__ bias2) {
    int i = blockIdx.x * blockDim.x + threadIdx.x;
    int O2 = 2 * O;
    if (i < O2) bias2[i] = (i < O) ? 0.f : bias[i - O];
    int total = C * O2;
    if (i >= total) return;
    int k = i / O2, col = i % O2;
    float v;
    if (col < O) {
        v = w[(size_t)col * 2 * C + k];                               // wA^T
    } else {
        int o = col - O;
        v = w[(size_t)o * 2 * C + C + k] - w[(size_t)o * 2 * C + k]; // (wB - wA)^T
    }
    P[i] = v;
}

// ---------- transpose w[O][K] -> wT[K][O] ----------
__global__ void k_transp(const float* __restrict__ w, int O, int K, float* __restrict__ wT) {
    int i = blockIdx.x * blockDim.x + threadIdx.x;
    if (i >= O * K) return;
    int k = i / O, o = i % O;
    wT[i] = w[(size_t)o * K + k];
}

// ---------- tiled f32 GEMM: C[M,N] = A[M,K](lda) @ Bm[K,N] (+bias per col, opt leaky) ----------
__global__ __launch_bounds__(256) void k_gemm(const float* __restrict__ A, int lda,
                                              const float* __restrict__ Bm,
                                              float* __restrict__ Cm, int ldc,
                                              int M, int N, int K,
                                              const float* __restrict__ bias, int leaky) {
    __shared__ float As[16][65];
    __shared__ float Bs[16][64];
    int tid = threadIdx.x;
    int row0 = blockIdx.y * 64, col0 = blockIdx.x * 64;
    int tr = tid >> 4, tc = tid & 15;
    float acc[4][4] = {{0.f}};
    for (int kt = 0; kt < K; kt += 16) {
#pragma unroll
        for (int i = 0; i < 4; ++i) {           // A tile: 64 rows x 16 k
            int e = tid + 256 * i;
            int r = e >> 4, kk = e & 15;
            int gr = row0 + r, gk = kt + kk;
            float v = 0.f;
            if (gr < M && gk < K) v = A[(size_t)gr * lda + gk];
            As[kk][r] = v;
        }
#pragma unroll
        for (int i = 0; i < 4; ++i) {           // B tile: 16 k x 64 cols
            int e = tid + 256 * i;
            int kk = e >> 6, c = e & 63;
            int gk = kt + kk, gc = col0 + c;
            float v = 0.f;
            if (gk < K && gc < N) v = Bm[(size_t)gk * N + gc];
            Bs[kk][c] = v;
        }
        __syncthreads();
#pragma unroll
        for (int kk = 0; kk < 16; ++kk) {
            float a[4], bv[4];
#pragma unroll
            for (int i = 0; i < 4; ++i) a[i] = As[kk][tr + 16 * i];
#pragma unroll
            for (int j = 0; j < 4; ++j) bv[j] = Bs[kk][tc + 16 * j];
#pragma unroll
            for (int i = 0; i < 4; ++i)
#pragma unroll
                for (int j = 0; j < 4; ++j) acc[i][j] += a[i] * bv[j];
        }
        __syncthreads();
    }
#pragma unroll
    for (int i = 0; i < 4; ++i) {
        int r = row0 + tr + 16 * i;
        if (r >= M) continue;
#pragma unroll
        for (int j = 0; j < 4; ++j) {
            int c = col0 + tc + 16 * j;
            if (c >= N) continue;
            float v = acc[i][j];
            if (bias) v += bias[c];
            if (leaky) v = v >= 0.f ? v : SLOPE * v;
            Cm[(size_t)r * ldc + c] = v;
        }
    }
}

// ---------- gather-max epilogue: out[r, ooff+o] = leaky(Z[r,o] + max_k Y1[idx[r,k],o]) ----------
// Y layout [B*R][2O]: cols [0,O) = Y1 (no bias), cols [O,2O) = Z (bias added by GEMM)
__global__ void k_gathermax(const float* __restrict__ Y, int O, int R,
                            const int* __restrict__ idx, int kc,
                            float* __restrict__ out, int ldo, int ooff) {
    extern __shared__ int sidx[];
    int br = blockIdx.x;
    int b  = br / R;
    int o  = threadIdx.x;
    if (o < kc) sidx[o] = idx[(size_t)br * kc + o];
    __syncthreads();
    int O2 = 2 * O;
    float z = Y[(size_t)br * O2 + O + o];
    float best = -FLT_MAX;
    for (int k = 0; k < kc; ++k) {
        int m = sidx[k];
        best = fmaxf(best, Y[(size_t)(b * R + m) * O2 + o]);
    }
    float r = z + best;
    out[(size_t)br * ldo + ooff + o] = r >= 0.f ? r : SLOPE * r;
}

// ---------- weighted pooling onto joints: grid = B*J, 256 threads ----------
__global__ __launch_bounds__(256) void k_pool(const float* __restrict__ Vf,
                                              const float* __restrict__ l1,
                                              const float* __restrict__ l2,
                                              const float* __restrict__ l3,
                                              const float* __restrict__ W,
                                              float* __restrict__ pooled) {
    __shared__ float red[256];
    int bj = blockIdx.x;
    int b  = bj / J_;
    int tid = threadIdx.x;
    const float* Wp = W + (size_t)bj * N_;

    float s = 0.f;
    for (int n = tid; n < N_; n += 256) s += Wp[n];
    red[tid] = s; __syncthreads();
    for (int st = 128; st > 0; st >>= 1) {
        if (tid < st) red[tid] += red[tid + st];
        __syncthreads();
    }
    float inv = 1.f / (red[0] + 1e-5f);

    auto chan = [&](int c, const float*& p, int& st) {
        if (c < 3)        { st = 3;   p = Vf + (size_t)b * N_ * 3   + c; }
        else if (c < 67)  { st = 64;  p = l1 + (size_t)b * N_ * 64  + (c - 3); }
        else if (c < 195) { st = 128; p = l2 + (size_t)b * N_ * 128 + (c - 67); }
        else              { st = 256; p = l3 + (size_t)b * N_ * 256 + (c - 195); }
    };

    int c0 = tid, c1 = tid + 256;
    const float *p0 = nullptr, *p1 = nullptr; int s0 = 0, s1 = 0;
    chan(c0, p0, s0);
    bool has1 = (c1 < 451);
    if (has1) chan(c1, p1, s1);

    float a0 = 0.f, a1 = 0.f;
    for (int n = 0; n < N_; ++n) {
        float wv = Wp[n];
        a0 += wv * p0[(size_t)n * s0];
        if (has1) a1 += wv * p1[(size_t)n * s1];
    }
    pooled[(size_t)bj * 451 + c0] = a0 * inv;
    if (has1) pooled[(size_t)bj * 451 + c1] = a1 * inv;
}

extern "C" void kernel_launch(void* const* d_in, const int* in_sizes, int n_in,
                              void* d_out, int out_size, void* d_ws, size_t ws_size,
                              hipStream_t stream) {
    const float* V  = (const float*)d_in[0];   // [4,4096,3]
    const float* W  = (const float*)d_in[1];   // [4,24,4096]
    const int* ringIdx = (const int*)d_in[2];  // [4,24,4]
    const float* g1w = (const float*)d_in[3];
    const float* g1b = (const float*)d_in[4];
    const float* g2w = (const float*)d_in[5];
    const float* g2b = (const float*)d_in[6];
    const float* g3w = (const float*)d_in[7];
    const float* g3b = (const float*)d_in[8];
    const float* s1w = (const float*)d_in[9];
    const float* s1b = (const float*)d_in[10];
    const float* s2w = (const float*)d_in[11];
    const float* s2b = (const float*)d_in[12];
    const float* s3w = (const float*)d_in[13];
    const float* s3b = (const float*)d_in[14];
    const float* m1w = (const float*)d_in[15];
    const float* m1b = (const float*)d_in[16];
    const float* m2w = (const float*)d_in[17];
    const float* m2b = (const float*)d_in[18];
    const float* m3w = (const float*)d_in[19];
    const float* m3b = (const float*)d_in[20];
    (void)ws_size; (void)n_in; (void)in_sizes; (void)out_size;

    // ---- workspace layout (floats), ~62.5 MB (same footprint as the passing round 3) ----
    float* ws = (float*)d_ws;
    size_t off = 0;
    float* l1 = ws + off; off += (size_t)B_ * N_ * 64;    // 4MB
    float* l2 = ws + off; off += (size_t)B_ * N_ * 128;   // 8MB
    float* l3 = ws + off; off += (size_t)B_ * N_ * 256;   // 16MB
    float* xx = ws + off; off += (size_t)B_ * N_;
    // D slab (ROWT x N_ = 32MB) aliases Y (max 32MB): D dead before k_gemm writes Y;
    // Y dead before next layer's k_dist writes D.
    float* D  = ws + off; off += (size_t)ROWT * N_;
    float* Y  = D;
    int* knnIdx = (int*)(ws + off); off += (size_t)B_ * N_ * KNN_;
    float* pooled = ws + off; off += (size_t)B_ * J_ * 451;
    float* joints = ws + off; off += (size_t)B_ * J_ * 448;
    float* h1 = ws + off; off += (size_t)B_ * J_ * 512;
    float* h2 = ws + off; off += (size_t)B_ * J_ * 256;
    float* P  = ws + off; off += (size_t)451 * 512;       // reused for all P / wT
    float* bias2 = ws + off; off += 512;

    const int M = B_ * N_;   // 16384
    const int MJ = B_ * J_;  // 96

    // ======== geoNet layer 1: C=3 -> O=64 ========
    k_norm<<<(M + 255) / 256, 256, 0, stream>>>(V, xx, 3);
    for (int b = 0; b < B_; ++b)
        for (int rb = 0; rb < N_; rb += ROWT) {
            k_dist<<<dim3(32, ROWT / 128), 256, 0, stream>>>(V + (size_t)b * N_ * 3, 3, xx + b * N_, D, rb);
            k_select<<<ROWT / 4, 256, 0, stream>>>(D, knnIdx + (size_t)b * N_ * KNN_, rb);
        }
    k_prepP<<<(3 * 128 + 255) / 256, 256, 0, stream>>>(g1w, g1b, 3, 64, P, bias2);
    k_gemm<<<dim3(2, M / 64), 256, 0, stream>>>(V, 3, P, Y, 128, M, 128, 3, bias2, 0);
    k_gathermax<<<M, 64, KNN_ * sizeof(int), stream>>>(Y, 64, N_, knnIdx, KNN_, l1, 64, 0);

    // ======== layer 2: C=64 -> O=128 ========
    k_norm<<<(M + 255) / 256, 256, 0, stream>>>(l1, xx, 64);
    for (int b = 0; b < B_; ++b)
        for (int rb = 0; rb < N_; rb += ROWT) {
            k_dist<<<dim3(32, ROWT / 128), 256, 0, stream>>>(l1 + (size_t)b * N_ * 64, 64, xx + b * N_, D, rb);
            k_select<<<ROWT / 4, 256, 0, stream>>>(D, knnIdx + (size_t)b * N_ * KNN_, rb);
        }
    k_prepP<<<(64 * 256 + 255) / 256, 256, 0, stream>>>(g2w, g2b, 64, 128, P, bias2);
    k_gemm<<<dim3(4, M / 64), 256, 0, stream>>>(l1, 64, P, Y, 256, M, 256, 64, bias2, 0);
    k_gathermax<<<M, 128, KNN_ * sizeof(int), stream>>>(Y, 128, N_, knnIdx, KNN_, l2, 128, 0);

    // ======== layer 3: C=128 -> O=256 ========
    k_norm<<<(M + 255) / 256, 256, 0, stream>>>(l2, xx, 128);
    for (int b = 0; b < B_; ++b)
        for (int rb = 0; rb < N_; rb += ROWT) {
            k_dist<<<dim3(32, ROWT / 128), 256, 0, stream>>>(l2 + (size_t)b * N_ * 128, 128, xx + b * N_, D, rb);
            k_select<<<ROWT / 4, 256, 0, stream>>>(D, knnIdx + (size_t)b * N_ * KNN_, rb);
        }
    k_prepP<<<(128 * 512 + 255) / 256, 256, 0, stream>>>(g3w, g3b, 128, 256, P, bias2);
    k_gemm<<<dim3(8, M / 64), 256, 0, stream>>>(l2, 128, P, Y, 512, M, 512, 128, bias2, 0);
    k_gathermax<<<M, 256, KNN_ * sizeof(int), stream>>>(Y, 256, N_, knnIdx, KNN_, l3, 256, 0);

    // ======== pooling onto joints ========
    k_pool<<<MJ, 256, 0, stream>>>(V, l1, l2, l3, W, pooled);

    // ======== skeleton conv 1: C=451 -> O=256 ========
    k_prepP<<<(451 * 512 + 255) / 256, 256, 0, stream>>>(s1w, s1b, 451, 256, P, bias2);
    k_gemm<<<dim3(8, 2), 256, 0, stream>>>(pooled, 451, P, Y, 512, MJ, 512, 451, bias2, 0);
    k_gathermax<<<MJ, 256, KR_ * sizeof(int), stream>>>(Y, 256, J_, ringIdx, KR_, joints, 448, 0);

    // ======== skeleton conv 2: C=256 -> O=128 ========
    k_prepP<<<(256 * 256 + 255) / 256, 256, 0, stream>>>(s2w, s2b, 256, 128, P, bias2);
    k_gemm<<<dim3(4, 2), 256, 0, stream>>>(joints, 448, P, Y, 256, MJ, 256, 256, bias2, 0);
    k_gathermax<<<MJ, 128, KR_ * sizeof(int), stream>>>(Y, 128, J_, ringIdx, KR_, joints, 448, 256);

    // ======== skeleton conv 3: C=128 -> O=64 ========
    k_prepP<<<(128 * 128 + 255) / 256, 256, 0, stream>>>(s3w, s3b, 128, 64, P, bias2);
    k_gemm<<<dim3(2, 2), 256, 0, stream>>>(joints + 256, 448, P, Y, 128, MJ, 128, 128, bias2, 0);
    k_gathermax<<<MJ, 64, KR_ * sizeof(int), stream>>>(Y, 64, J_, ringIdx, KR_, joints, 448, 384);

    // ======== joint MLP ========
    k_transp<<<(512 * 448 + 255) / 256, 256, 0, stream>>>(m1w, 512, 448, P);
    k_gemm<<<dim3(8, 2), 256, 0, stream>>>(joints, 448, P, h1, 512, MJ, 512, 448, m1b, 1);
    k_transp<<<(256 * 512 + 255) / 256, 256, 0, stream>>>(m2w, 256, 512, P);
    k_gemm<<<dim3(4, 2), 256, 0, stream>>>(h1, 512, P, h2, 256, MJ, 256, 512, m2b, 1);
    k_transp<<<(3 * 256 + 255) / 256, 256, 0, stream>>>(m3w, 3, 256, P);
    k_gemm<<<dim3(1, 2), 256, 0, stream>>>(h2, 256, P, (float*)d_out, 3, MJ, 3, 256, m3b, 0);
}

// Round 6
// 3551.212 us; speedup vs baseline: 3.0050x; 1.3242x over previous
//
#include <hip/hip_runtime.h>
#include <hip/hip_bf16.h>
#include <float.h>

// Problem constants (from reference setup_inputs)
#define B_   4
#define N_   4096
#define J_   24
#define KR_  4
#define KNN_ 20
#define SLOPE 0.2f
#define ROWT 2048   // rows per distance slab (slab = ROWT x N_ f32 = 32 MB)
#define SLABN 256   // points per pooling slab
#define NSLAB (N_ / SLABN)   // 16

// ---------- per-point squared norm ----------
__global__ void k_norm(const float* __restrict__ h, float* __restrict__ xx, int C) {
    int i = blockIdx.x * blockDim.x + threadIdx.x;  // b*N + n
    if (i >= B_ * N_) return;
    const float* hp = h + (size_t)i * C;
    float s = 0.f;
    for (int c = 0; c < C; ++c) { float v = hp[c]; s += v * v; }
    xx[i] = s;
}

// ---------- distance GEMM, one row-slab of one batch ----------
// D[grow-rowbase, m] = xx[grow] + xx[m] - 2*dot(X[grow], X[m])
__global__ __launch_bounds__(256) void k_dist(const float* __restrict__ X, int C,
                                              const float* __restrict__ xxb,
                                              float* __restrict__ D, int rowbase) {
    __shared__ float As[16][136];   // [k][row], 136*4=544B rows: float4-aligned
    __shared__ float Bs[16][136];
    int tid = threadIdx.x;
    int row0 = rowbase + blockIdx.y * 128;   // global row
    int col0 = blockIdx.x * 128;             // global col
    int tr = tid >> 4, tc = tid & 15;
    float acc[8][8] = {{0.f}};
    for (int kt = 0; kt < C; kt += 16) {
#pragma unroll
        for (int i = 0; i < 8; ++i) {
            int e = tid + 256 * i;
            int r = e >> 4, kk = e & 15;     // r in [0,128), kk in [0,16)
            int gk = kt + kk;
            As[kk][r] = (gk < C) ? X[(size_t)(row0 + r) * C + gk] : 0.f;
            Bs[kk][r] = (gk < C) ? X[(size_t)(col0 + r) * C + gk] : 0.f;
        }
        __syncthreads();
#pragma unroll
        for (int kk = 0; kk < 16; ++kk) {
            float a[8], bv[8];
            *(float4*)&a[0]  = *(const float4*)&As[kk][tr * 8];
            *(float4*)&a[4]  = *(const float4*)&As[kk][tr * 8 + 4];
            *(float4*)&bv[0] = *(const float4*)&Bs[kk][tc * 8];
            *(float4*)&bv[4] = *(const float4*)&Bs[kk][tc * 8 + 4];
#pragma unroll
            for (int i = 0; i < 8; ++i)
#pragma unroll
                for (int j = 0; j < 8; ++j) acc[i][j] += a[i] * bv[j];
        }
        __syncthreads();
    }
    float xc[8];
#pragma unroll
    for (int j = 0; j < 8; ++j) xc[j] = xxb[col0 + tc * 8 + j];
#pragma unroll
    for (int i = 0; i < 8; ++i) {
        int grow = row0 + tr * 8 + i;
        float xr = xxb[grow];
        float4 o0, o1;
        o0.x = xr + xc[0] - 2.f * acc[i][0];
        o0.y = xr + xc[1] - 2.f * acc[i][1];
        o0.z = xr + xc[2] - 2.f * acc[i][2];
        o0.w = xr + xc[3] - 2.f * acc[i][3];
        o1.x = xr + xc[4] - 2.f * acc[i][4];
        o1.y = xr + xc[5] - 2.f * acc[i][5];
        o1.z = xr + xc[6] - 2.f * acc[i][6];
        o1.w = xr + xc[7] - 2.f * acc[i][7];
        float* dp = D + (size_t)(grow - rowbase) * N_ + col0 + tc * 8;
        *(float4*)dp       = o0;
        *(float4*)(dp + 4) = o1;
    }
}

// ---------- top-20 selection: one wave per query, u64-key tournament ----------
__device__ __forceinline__ unsigned mapf(float f) {
    unsigned u = __float_as_uint(f);
    return (u & 0x80000000u) ? ~u : (u | 0x80000000u);
}

__global__ __launch_bounds__(256) void k_select(const float* __restrict__ Db,
                                                int* __restrict__ idxout, int qbase) {
    const unsigned long long SENT = ~0ull;
    int ql   = blockIdx.x * 4 + (threadIdx.x >> 6);   // local row in slab
    int lane = threadIdx.x & 63;
    const float* row = Db + (size_t)ql * N_;
    int qg = qbase + ql;                              // global query in batch

    unsigned long long b0 = SENT, b1 = SENT;
    unsigned long long emask = 0;                     // popped elements of my chunk
#pragma unroll 8
    for (int j = 0; j < 64; ++j) {
        float v = row[j * 64 + lane];                 // coalesced
        unsigned long long key = ((unsigned long long)mapf(v) << 32) | (unsigned)(j * 64 + lane);
        if (key < b1) { if (key < b0) { b1 = b0; b0 = key; } else b1 = key; }
    }
    for (int k = 0; k < KNN_; ++k) {
        if (b0 == SENT) {                             // rare refill
            b1 = SENT;
            for (int j = 0; j < 64; ++j) {
                if ((emask >> j) & 1ull) continue;
                float v = row[j * 64 + lane];
                unsigned long long key = ((unsigned long long)mapf(v) << 32) | (unsigned)(j * 64 + lane);
                if (key < b1) { if (key < b0) { b1 = b0; b0 = key; } else b1 = key; }
            }
        }
        unsigned long long m = b0;
#pragma unroll
        for (int s = 32; s > 0; s >>= 1) {
            unsigned long long o = (unsigned long long)__shfl_xor((long long)m, s, 64);
            if (o < m) m = o;
        }
        unsigned idx = (unsigned)(m & 0xFFFFFFFFull);
        if (lane == (int)(idx & 63u)) {               // owner pops
            emask |= 1ull << (idx >> 6);
            b0 = b1; b1 = SENT;
        }
        if (lane == 0) idxout[qg * KNN_ + k] = (int)idx;
    }
}

// ---------- build projection P[K=C][2O]: [wA^T | (wB-wA)^T], bias2[2O]=[0|bias] ----------
__global__ void k_prepP(const float* __restrict__ w, const float* __restrict__ bias,
                        int C, int O, float* __restrict__ P, float* __restrict__ bias2) {
    int i = blockIdx.x * blockDim.x + threadIdx.x;
    int O2 = 2 * O;
    if (i < O2) bias2[i] = (i < O) ? 0.f : bias[i - O];
    int total = C * O2;
    if (i >= total) return;
    int k = i / O2, col = i % O2;
    float v;
    if (col < O) {
        v = w[(size_t)col * 2 * C + k];                               // wA^T
    } else {
        int o = col - O;
        v = w[(size_t)o * 2 * C + C + k] - w[(size_t)o * 2 * C + k]; // (wB - wA)^T
    }
    P[i] = v;
}

// ---------- transpose w[O][K] -> wT[K][O] ----------
__global__ void k_transp(const float* __restrict__ w, int O, int K, float* __restrict__ wT) {
    int i = blockIdx.x * blockDim.x + threadIdx.x;
    if (i >= O * K) return;
    int k = i / O, o = i % O;
    wT[i] = w[(size_t)o * K + k];
}

// ---------- tiled f32 GEMM: C[M,N] = A[M,K](lda) @ Bm[K,N] (+bias per col, opt leaky) ----------
__global__ __launch_bounds__(256) void k_gemm(const float* __restrict__ A, int lda,
                                              const float* __restrict__ Bm,
                                              float* __restrict__ Cm, int ldc,
                                              int M, int N, int K,
                                              const float* __restrict__ bias, int leaky) {
    __shared__ float As[16][65];
    __shared__ float Bs[16][64];
    int tid = threadIdx.x;
    int row0 = blockIdx.y * 64, col0 = blockIdx.x * 64;
    int tr = tid >> 4, tc = tid & 15;
    float acc[4][4] = {{0.f}};
    for (int kt = 0; kt < K; kt += 16) {
#pragma unroll
        for (int i = 0; i < 4; ++i) {           // A tile: 64 rows x 16 k
            int e = tid + 256 * i;
            int r = e >> 4, kk = e & 15;
            int gr = row0 + r, gk = kt + kk;
            float v = 0.f;
            if (gr < M && gk < K) v = A[(size_t)gr * lda + gk];
            As[kk][r] = v;
        }
#pragma unroll
        for (int i = 0; i < 4; ++i) {           // B tile: 16 k x 64 cols
            int e = tid + 256 * i;
            int kk = e >> 6, c = e & 63;
            int gk = kt + kk, gc = col0 + c;
            float v = 0.f;
            if (gk < K && gc < N) v = Bm[(size_t)gk * N + gc];
            Bs[kk][c] = v;
        }
        __syncthreads();
#pragma unroll
        for (int kk = 0; kk < 16; ++kk) {
            float a[4], bv[4];
#pragma unroll
            for (int i = 0; i < 4; ++i) a[i] = As[kk][tr + 16 * i];
#pragma unroll
            for (int j = 0; j < 4; ++j) bv[j] = Bs[kk][tc + 16 * j];
#pragma unroll
            for (int i = 0; i < 4; ++i)
#pragma unroll
                for (int j = 0; j < 4; ++j) acc[i][j] += a[i] * bv[j];
        }
        __syncthreads();
    }
#pragma unroll
    for (int i = 0; i < 4; ++i) {
        int r = row0 + tr + 16 * i;
        if (r >= M) continue;
#pragma unroll
        for (int j = 0; j < 4; ++j) {
            int c = col0 + tc + 16 * j;
            if (c >= N) continue;
            float v = acc[i][j];
            if (bias) v += bias[c];
            if (leaky) v = v >= 0.f ? v : SLOPE * v;
            Cm[(size_t)r * ldc + c] = v;
        }
    }
}

// ---------- gather-max epilogue ----------
__global__ void k_gathermax(const float* __restrict__ Y, int O, int R,
                            const int* __restrict__ idx, int kc,
                            float* __restrict__ out, int ldo, int ooff) {
    extern __shared__ int sidx[];
    int br = blockIdx.x;
    int b  = br / R;
    int o  = threadIdx.x;
    if (o < kc) sidx[o] = idx[(size_t)br * kc + o];
    __syncthreads();
    int O2 = 2 * O;
    float z = Y[(size_t)br * O2 + O + o];
    float best = -FLT_MAX;
    for (int k = 0; k < kc; ++k) {
        int m = sidx[k];
        best = fmaxf(best, Y[(size_t)(b * R + m) * O2 + o]);
    }
    float r = z + best;
    out[(size_t)br * ldo + ooff + o] = r >= 0.f ? r : SLOPE * r;
}

// ---------- channel -> (ptr, stride) map for the concatenated 451-dim feature ----------
__device__ __forceinline__ void chan_map(int b, int c,
                                         const float* Vf, const float* l1,
                                         const float* l2, const float* l3,
                                         const float*& p, int& st) {
    if (c < 3)        { st = 3;   p = Vf + (size_t)b * N_ * 3   + c; }
    else if (c < 67)  { st = 64;  p = l1 + (size_t)b * N_ * 64  + (c - 3); }
    else if (c < 195) { st = 128; p = l2 + (size_t)b * N_ * 128 + (c - 67); }
    else              { st = 256; p = l3 + (size_t)b * N_ * 256 + (c - 195); }
}

// ---------- pooling phase 1: grid = B*NSLAB; partial sums over a 256-point slab ----------
// ppool[(b*NSLAB+slab)*J_ + j][451], psw[(b*NSLAB+slab)*J_ + j]
__global__ __launch_bounds__(256) void k_pool2(const float* __restrict__ Vf,
                                               const float* __restrict__ l1,
                                               const float* __restrict__ l2,
                                               const float* __restrict__ l3,
                                               const float* __restrict__ W,
                                               float* __restrict__ ppool,
                                               float* __restrict__ psw) {
    __shared__ float Wl[SLABN][J_];   // [n][j], row = 96B (float4-aligned)
    int blk  = blockIdx.x;
    int b    = blk / NSLAB, slab = blk % NSLAB;
    int n0   = slab * SLABN;
    int tid  = threadIdx.x;

    for (int e = tid; e < J_ * SLABN; e += 256) {
        int j = e / SLABN, n = e % SLABN;
        Wl[n][j] = W[((size_t)b * J_ + j) * N_ + n0 + n];   // coalesced over n
    }
    __syncthreads();

    if (tid < J_) {                    // per-joint W partial sum
        float s = 0.f;
        for (int n = 0; n < SLABN; ++n) s += Wl[n][tid];
        psw[(size_t)blk * J_ + tid] = s;
    }

    int c0 = tid, c1 = tid + 256;
    const float *p0, *p1 = nullptr; int s0, s1 = 0;
    chan_map(b, c0, Vf, l1, l2, l3, p0, s0);
    bool has1 = (c1 < 451);
    if (has1) chan_map(b, c1, Vf, l1, l2, l3, p1, s1);

    float acc0[J_], acc1[J_];
#pragma unroll
    for (int j = 0; j < J_; ++j) { acc0[j] = 0.f; acc1[j] = 0.f; }

    for (int n = 0; n < SLABN; ++n) {
        float v0 = p0[(size_t)(n0 + n) * s0];
        float v1 = has1 ? p1[(size_t)(n0 + n) * s1] : 0.f;
        const float* wn = &Wl[n][0];
#pragma unroll
        for (int q = 0; q < J_ / 4; ++q) {
            float4 w4 = *(const float4*)(wn + 4 * q);   // broadcast, conflict-free
            acc0[4*q+0] += w4.x * v0;  acc1[4*q+0] += w4.x * v1;
            acc0[4*q+1] += w4.y * v0;  acc1[4*q+1] += w4.y * v1;
            acc0[4*q+2] += w4.z * v0;  acc1[4*q+2] += w4.z * v1;
            acc0[4*q+3] += w4.w * v0;  acc1[4*q+3] += w4.w * v1;
        }
    }
    float* pp = ppool + (size_t)blk * J_ * 451;
#pragma unroll
    for (int j = 0; j < J_; ++j) {
        pp[(size_t)j * 451 + c0] = acc0[j];
        if (has1) pp[(size_t)j * 451 + c1] = acc1[j];
    }
}

// ---------- pooling phase 2: grid = B*J_; reduce NSLAB partials, divide by sumW ----------
__global__ __launch_bounds__(256) void k_poolred(const float* __restrict__ ppool,
                                                 const float* __restrict__ psw,
                                                 float* __restrict__ pooled) {
    int bj = blockIdx.x;               // b*J_ + j
    int b  = bj / J_, j = bj % J_;
    int tid = threadIdx.x;

    float sw = 0.f;
    for (int sl = 0; sl < NSLAB; ++sl) sw += psw[(size_t)(b * NSLAB + sl) * J_ + j];
    float inv = 1.f / (sw + 1e-5f);

    for (int c = tid; c < 451; c += 256) {
        float s = 0.f;
        for (int sl = 0; sl < NSLAB; ++sl)
            s += ppool[((size_t)(b * NSLAB + sl) * J_ + j) * 451 + c];
        pooled[(size_t)bj * 451 + c] = s * inv;
    }
}

extern "C" void kernel_launch(void* const* d_in, const int* in_sizes, int n_in,
                              void* d_out, int out_size, void* d_ws, size_t ws_size,
                              hipStream_t stream) {
    const float* V  = (const float*)d_in[0];   // [4,4096,3]
    const float* W  = (const float*)d_in[1];   // [4,24,4096]
    const int* ringIdx = (const int*)d_in[2];  // [4,24,4]
    const float* g1w = (const float*)d_in[3];
    const float* g1b = (const float*)d_in[4];
    const float* g2w = (const float*)d_in[5];
    const float* g2b = (const float*)d_in[6];
    const float* g3w = (const float*)d_in[7];
    const float* g3b = (const float*)d_in[8];
    const float* s1w = (const float*)d_in[9];
    const float* s1b = (const float*)d_in[10];
    const float* s2w = (const float*)d_in[11];
    const float* s2b = (const float*)d_in[12];
    const float* s3w = (const float*)d_in[13];
    const float* s3b = (const float*)d_in[14];
    const float* m1w = (const float*)d_in[15];
    const float* m1b = (const float*)d_in[16];
    const float* m2w = (const float*)d_in[17];
    const float* m2b = (const float*)d_in[18];
    const float* m3w = (const float*)d_in[19];
    const float* m3b = (const float*)d_in[20];
    (void)ws_size; (void)n_in; (void)in_sizes; (void)out_size;

    // ---- workspace layout (floats), ~62.5 MB ----
    float* ws = (float*)d_ws;
    size_t off = 0;
    float* l1 = ws + off; off += (size_t)B_ * N_ * 64;    // 4MB
    float* l2 = ws + off; off += (size_t)B_ * N_ * 128;   // 8MB
    float* l3 = ws + off; off += (size_t)B_ * N_ * 256;   // 16MB
    float* xx = ws + off; off += (size_t)B_ * N_;
    // D slab (32MB) aliases Y (max 32MB) and ppool/psw (2.8MB):
    //   D dead before k_gemm writes Y; Y dead before next k_dist writes D;
    //   ppool written after layer-3 gathermax (Y dead), consumed by k_poolred
    //   before skeleton conv s1 re-writes Y.
    float* D  = ws + off; off += (size_t)ROWT * N_;
    float* Y  = D;
    float* ppool = D;
    float* psw   = D + (size_t)B_ * NSLAB * J_ * 451;
    int* knnIdx = (int*)(ws + off); off += (size_t)B_ * N_ * KNN_;
    float* pooled = ws + off; off += (size_t)B_ * J_ * 451;
    float* joints = ws + off; off += (size_t)B_ * J_ * 448;
    float* h1 = ws + off; off += (size_t)B_ * J_ * 512;
    float* h2 = ws + off; off += (size_t)B_ * J_ * 256;
    float* P  = ws + off; off += (size_t)451 * 512;       // reused for all P / wT
    float* bias2 = ws + off; off += 512;

    const int M = B_ * N_;   // 16384
    const int MJ = B_ * J_;  // 96

    // ======== geoNet layer 1: C=3 -> O=64 ========
    k_norm<<<(M + 255) / 256, 256, 0, stream>>>(V, xx, 3);
    for (int b = 0; b < B_; ++b)
        for (int rb = 0; rb < N_; rb += ROWT) {
            k_dist<<<dim3(32, ROWT / 128), 256, 0, stream>>>(V + (size_t)b * N_ * 3, 3, xx + b * N_, D, rb);
            k_select<<<ROWT / 4, 256, 0, stream>>>(D, knnIdx + (size_t)b * N_ * KNN_, rb);
        }
    k_prepP<<<(3 * 128 + 255) / 256, 256, 0, stream>>>(g1w, g1b, 3, 64, P, bias2);
    k_gemm<<<dim3(2, M / 64), 256, 0, stream>>>(V, 3, P, Y, 128, M, 128, 3, bias2, 0);
    k_gathermax<<<M, 64, KNN_ * sizeof(int), stream>>>(Y, 64, N_, knnIdx, KNN_, l1, 64, 0);

    // ======== layer 2: C=64 -> O=128 ========
    k_norm<<<(M + 255) / 256, 256, 0, stream>>>(l1, xx, 64);
    for (int b = 0; b < B_; ++b)
        for (int rb = 0; rb < N_; rb += ROWT) {
            k_dist<<<dim3(32, ROWT / 128), 256, 0, stream>>>(l1 + (size_t)b * N_ * 64, 64, xx + b * N_, D, rb);
            k_select<<<ROWT / 4, 256, 0, stream>>>(D, knnIdx + (size_t)b * N_ * KNN_, rb);
        }
    k_prepP<<<(64 * 256 + 255) / 256, 256, 0, stream>>>(g2w, g2b, 64, 128, P, bias2);
    k_gemm<<<dim3(4, M / 64), 256, 0, stream>>>(l1, 64, P, Y, 256, M, 256, 64, bias2, 0);
    k_gathermax<<<M, 128, KNN_ * sizeof(int), stream>>>(Y, 128, N_, knnIdx, KNN_, l2, 128, 0);

    // ======== layer 3: C=128 -> O=256 ========
    k_norm<<<(M + 255) / 256, 256, 0, stream>>>(l2, xx, 128);
    for (int b = 0; b < B_; ++b)
        for (int rb = 0; rb < N_; rb += ROWT) {
            k_dist<<<dim3(32, ROWT / 128), 256, 0, stream>>>(l2 + (size_t)b * N_ * 128, 128, xx + b * N_, D, rb);
            k_select<<<ROWT / 4, 256, 0, stream>>>(D, knnIdx + (size_t)b * N_ * KNN_, rb);
        }
    k_prepP<<<(128 * 512 + 255) / 256, 256, 0, stream>>>(g3w, g3b, 128, 256, P, bias2);
    k_gemm<<<dim3(8, M / 64), 256, 0, stream>>>(l2, 128, P, Y, 512, M, 512, 128, bias2, 0);
    k_gathermax<<<M, 256, KNN_ * sizeof(int), stream>>>(Y, 256, N_, knnIdx, KNN_, l3, 256, 0);

    // ======== pooling onto joints (two-phase) ========
    k_pool2<<<B_ * NSLAB, 256, 0, stream>>>(V, l1, l2, l3, W, ppool, psw);
    k_poolred<<<MJ, 256, 0, stream>>>(ppool, psw, pooled);

    // ======== skeleton conv 1: C=451 -> O=256 ========
    k_prepP<<<(451 * 512 + 255) / 256, 256, 0, stream>>>(s1w, s1b, 451, 256, P, bias2);
    k_gemm<<<dim3(8, 2), 256, 0, stream>>>(pooled, 451, P, Y, 512, MJ, 512, 451, bias2, 0);
    k_gathermax<<<MJ, 256, KR_ * sizeof(int), stream>>>(Y, 256, J_, ringIdx, KR_, joints, 448, 0);

    // ======== skeleton conv 2: C=256 -> O=128 ========
    k_prepP<<<(256 * 256 + 255) / 256, 256, 0, stream>>>(s2w, s2b, 256, 128, P, bias2);
    k_gemm<<<dim3(4, 2), 256, 0, stream>>>(joints, 448, P, Y, 256, MJ, 256, 256, bias2, 0);
    k_gathermax<<<MJ, 128, KR_ * sizeof(int), stream>>>(Y, 128, J_, ringIdx, KR_, joints, 448, 256);

    // ======== skeleton conv 3: C=128 -> O=64 ========
    k_prepP<<<(128 * 128 + 255) / 256, 256, 0, stream>>>(s3w, s3b, 128, 64, P, bias2);
    k_gemm<<<dim3(2, 2), 256, 0, stream>>>(joints + 256, 448, P, Y, 128, MJ, 128, 128, bias2, 0);
    k_gathermax<<<MJ, 64, KR_ * sizeof(int), stream>>>(Y, 64, J_, ringIdx, KR_, joints, 448, 384);

    // ======== joint MLP ========
    k_transp<<<(512 * 448 + 255) / 256, 256, 0, stream>>>(m1w, 512, 448, P);
    k_gemm<<<dim3(8, 2), 256, 0, stream>>>(joints, 448, P, h1, 512, MJ, 512, 448, m1b, 1);
    k_transp<<<(256 * 512 + 255) / 256, 256, 0, stream>>>(m2w, 256, 512, P);
    k_gemm<<<dim3(4, 2), 256, 0, stream>>>(h1, 512, P, h2, 256, MJ, 256, 512, m2b, 1);
    k_transp<<<(3 * 256 + 255) / 256, 256, 0, stream>>>(m3w, 3, 256, P);
    k_gemm<<<dim3(1, 2), 256, 0, stream>>>(h2, 256, P, (float*)d_out, 3, MJ, 3, 256, m3b, 0);
}

// Round 7
// 2443.806 us; speedup vs baseline: 4.3667x; 1.4531x over previous
//
#include <hip/hip_runtime.h>
#include <hip/hip_bf16.h>
#include <float.h>

// Problem constants (from reference setup_inputs)
#define B_   4
#define N_   4096
#define J_   24
#define KR_  4
#define KNN_ 20
#define SLOPE 0.2f
#define ROWT 2048   // rows per distance slab (slab = ROWT x N_ f32 = 32 MB)
#define SLABN 256   // points per pooling slab
#define NSLAB (N_ / SLABN)   // 16

// ---------- per-point squared norm ----------
__global__ void k_norm(const float* __restrict__ h, float* __restrict__ xx, int C) {
    int i = blockIdx.x * blockDim.x + threadIdx.x;  // b*N + n
    if (i >= B_ * N_) return;
    const float* hp = h + (size_t)i * C;
    float s = 0.f;
    for (int c = 0; c < C; ++c) { float v = hp[c]; s += v * v; }
    xx[i] = s;
}

// ---------- distance GEMM, one row-slab of one batch ----------
// D[grow-rowbase, m] = xx[grow] + xx[m] - 2*dot(X[grow], X[m])
__global__ __launch_bounds__(256) void k_dist(const float* __restrict__ X, int C,
                                              const float* __restrict__ xxb,
                                              float* __restrict__ D, int rowbase) {
    __shared__ float As[16][136];   // [k][row], 136*4=544B rows: float4-aligned
    __shared__ float Bs[16][136];
    int tid = threadIdx.x;
    int row0 = rowbase + blockIdx.y * 128;   // global row
    int col0 = blockIdx.x * 128;             // global col
    int tr = tid >> 4, tc = tid & 15;
    float acc[8][8] = {{0.f}};
    for (int kt = 0; kt < C; kt += 16) {
#pragma unroll
        for (int i = 0; i < 8; ++i) {
            int e = tid + 256 * i;
            int r = e >> 4, kk = e & 15;     // r in [0,128), kk in [0,16)
            int gk = kt + kk;
            As[kk][r] = (gk < C) ? X[(size_t)(row0 + r) * C + gk] : 0.f;
            Bs[kk][r] = (gk < C) ? X[(size_t)(col0 + r) * C + gk] : 0.f;
        }
        __syncthreads();
#pragma unroll
        for (int kk = 0; kk < 16; ++kk) {
            float a[8], bv[8];
            *(float4*)&a[0]  = *(const float4*)&As[kk][tr * 8];
            *(float4*)&a[4]  = *(const float4*)&As[kk][tr * 8 + 4];
            *(float4*)&bv[0] = *(const float4*)&Bs[kk][tc * 8];
            *(float4*)&bv[4] = *(const float4*)&Bs[kk][tc * 8 + 4];
#pragma unroll
            for (int i = 0; i < 8; ++i)
#pragma unroll
                for (int j = 0; j < 8; ++j) acc[i][j] += a[i] * bv[j];
        }
        __syncthreads();
    }
    float xc[8];
#pragma unroll
    for (int j = 0; j < 8; ++j) xc[j] = xxb[col0 + tc * 8 + j];
#pragma unroll
    for (int i = 0; i < 8; ++i) {
        int grow = row0 + tr * 8 + i;
        float xr = xxb[grow];
        float4 o0, o1;
        o0.x = xr + xc[0] - 2.f * acc[i][0];
        o0.y = xr + xc[1] - 2.f * acc[i][1];
        o0.z = xr + xc[2] - 2.f * acc[i][2];
        o0.w = xr + xc[3] - 2.f * acc[i][3];
        o1.x = xr + xc[4] - 2.f * acc[i][4];
        o1.y = xr + xc[5] - 2.f * acc[i][5];
        o1.z = xr + xc[6] - 2.f * acc[i][6];
        o1.w = xr + xc[7] - 2.f * acc[i][7];
        float* dp = D + (size_t)(grow - rowbase) * N_ + col0 + tc * 8;
        *(float4*)dp       = o0;
        *(float4*)(dp + 4) = o1;
    }
}

// ---------- selection phase 1: one wave per quarter-row; exact quarter top-20 ----------
// key = (monotone_map(dist) << 32) | global_col  -> u64 min = (smallest dist, smallest idx)
__device__ __forceinline__ unsigned mapf(float f) {
    unsigned u = __float_as_uint(f);
    return (u & 0x80000000u) ? ~u : (u | 0x80000000u);
}

__global__ __launch_bounds__(256) void k_sel1(const float* __restrict__ Db,
                                              unsigned long long* __restrict__ qc) {
    const unsigned long long SENT = ~0ull;
    int ql   = blockIdx.x;                    // local row in slab
    int wv   = threadIdx.x >> 6;              // quarter 0..3
    int lane = threadIdx.x & 63;
    int gbase = wv * 1024 + lane * 16;        // lane owns 16 contiguous cols
    const float* seg = Db + (size_t)ql * N_ + gbase;

    float4 v4[4];
    v4[0] = *(const float4*)(seg);
    v4[1] = *(const float4*)(seg + 4);
    v4[2] = *(const float4*)(seg + 8);
    v4[3] = *(const float4*)(seg + 12);
    const float* vv = (const float*)v4;

    unsigned long long b0 = SENT, b1 = SENT;
    unsigned emask = 0;                       // popped elements of my 16
#pragma unroll
    for (int t = 0; t < 16; ++t) {
        unsigned long long key = ((unsigned long long)mapf(vv[t]) << 32) | (unsigned)(gbase + t);
        if (key < b1) { if (key < b0) { b1 = b0; b0 = key; } else b1 = key; }
    }
    unsigned long long* out = qc + ((size_t)ql * 4 + wv) * KNN_;
    for (int k = 0; k < KNN_; ++k) {
        if (b0 == SENT) {                     // rare refill: rescan my 16 (L2-hot)
            b1 = SENT;
            for (int t = 0; t < 16; ++t) {
                if ((emask >> t) & 1u) continue;
                unsigned long long key = ((unsigned long long)mapf(seg[t]) << 32) | (unsigned)(gbase + t);
                if (key < b1) { if (key < b0) { b1 = b0; b0 = key; } else b1 = key; }
            }
        }
        unsigned long long m = b0;
#pragma unroll
        for (int s = 32; s > 0; s >>= 1) {
            unsigned long long o = (unsigned long long)__shfl_xor((long long)m, s, 64);
            if (o < m) m = o;
        }
        if (m == b0) {                        // unique keys -> exactly one owner
            emask |= 1u << ((unsigned)m & 15u);
            b0 = b1; b1 = SENT;
        }
        if (lane == 0) out[k] = m;
    }
}

// ---------- selection phase 2: one wave per row; merge 4x20 candidates (refill-free) ----------
__global__ __launch_bounds__(256) void k_sel2(const unsigned long long* __restrict__ qc,
                                              int* __restrict__ idxout, int qbase) {
    const unsigned long long SENT = ~0ull;
    int ql   = blockIdx.x * 4 + (threadIdx.x >> 6);
    int lane = threadIdx.x & 63;
    const unsigned long long* row = qc + (size_t)ql * 80;

    unsigned long long b0 = row[lane];                        // cands 0..63
    unsigned long long b1 = (lane < 16) ? row[64 + lane] : SENT;  // cands 64..79
    if (b1 < b0) { unsigned long long t = b0; b0 = b1; b1 = t; }

    int qg = qbase + ql;
    for (int k = 0; k < KNN_; ++k) {
        unsigned long long m = b0;
#pragma unroll
        for (int s = 32; s > 0; s >>= 1) {
            unsigned long long o = (unsigned long long)__shfl_xor((long long)m, s, 64);
            if (o < m) m = o;
        }
        if (m == b0) { b0 = b1; b1 = SENT; }  // <=2 cands/lane -> never refills
        if (lane == 0) idxout[qg * KNN_ + k] = (int)(unsigned)m;
    }
}

// ---------- build projection P[K=C][2O]: [wA^T | (wB-wA)^T], bias2[2O]=[0|bias] ----------
__global__ void k_prepP(const float* __restrict__ w, const float* __restrict__ bias,
                        int C, int O, float* __restrict__ P, float* __restrict__ bias2) {
    int i = blockIdx.x * blockDim.x + threadIdx.x;
    int O2 = 2 * O;
    if (i < O2) bias2[i] = (i < O) ? 0.f : bias[i - O];
    int total = C * O2;
    if (i >= total) return;
    int k = i / O2, col = i % O2;
    float v;
    if (col < O) {
        v = w[(size_t)col * 2 * C + k];                               // wA^T
    } else {
        int o = col - O;
        v = w[(size_t)o * 2 * C + C + k] - w[(size_t)o * 2 * C + k]; // (wB - wA)^T
    }
    P[i] = v;
}

// ---------- transpose w[O][K] -> wT[K][O] ----------
__global__ void k_transp(const float* __restrict__ w, int O, int K, float* __restrict__ wT) {
    int i = blockIdx.x * blockDim.x + threadIdx.x;
    if (i >= O * K) return;
    int k = i / O, o = i % O;
    wT[i] = w[(size_t)o * K + k];
}

// ---------- tiled f32 GEMM: C[M,N] = A[M,K](lda) @ Bm[K,N] (+bias per col, opt leaky) ----------
__global__ __launch_bounds__(256) void k_gemm(const float* __restrict__ A, int lda,
                                              const float* __restrict__ Bm,
                                              float* __restrict__ Cm, int ldc,
                                              int M, int N, int K,
                                              const float* __restrict__ bias, int leaky) {
    __shared__ float As[16][65];
    __shared__ float Bs[16][64];
    int tid = threadIdx.x;
    int row0 = blockIdx.y * 64, col0 = blockIdx.x * 64;
    int tr = tid >> 4, tc = tid & 15;
    float acc[4][4] = {{0.f}};
    for (int kt = 0; kt < K; kt += 16) {
#pragma unroll
        for (int i = 0; i < 4; ++i) {           // A tile: 64 rows x 16 k
            int e = tid + 256 * i;
            int r = e >> 4, kk = e & 15;
            int gr = row0 + r, gk = kt + kk;
            float v = 0.f;
            if (gr < M && gk < K) v = A[(size_t)gr * lda + gk];
            As[kk][r] = v;
        }
#pragma unroll
        for (int i = 0; i < 4; ++i) {           // B tile: 16 k x 64 cols
            int e = tid + 256 * i;
            int kk = e >> 6, c = e & 63;
            int gk = kt + kk, gc = col0 + c;
            float v = 0.f;
            if (gk < K && gc < N) v = Bm[(size_t)gk * N + gc];
            Bs[kk][c] = v;
        }
        __syncthreads();
#pragma unroll
        for (int kk = 0; kk < 16; ++kk) {
            float a[4], bv[4];
#pragma unroll
            for (int i = 0; i < 4; ++i) a[i] = As[kk][tr + 16 * i];
#pragma unroll
            for (int j = 0; j < 4; ++j) bv[j] = Bs[kk][tc + 16 * j];
#pragma unroll
            for (int i = 0; i < 4; ++i)
#pragma unroll
                for (int j = 0; j < 4; ++j) acc[i][j] += a[i] * bv[j];
        }
        __syncthreads();
    }
#pragma unroll
    for (int i = 0; i < 4; ++i) {
        int r = row0 + tr + 16 * i;
        if (r >= M) continue;
#pragma unroll
        for (int j = 0; j < 4; ++j) {
            int c = col0 + tc + 16 * j;
            if (c >= N) continue;
            float v = acc[i][j];
            if (bias) v += bias[c];
            if (leaky) v = v >= 0.f ? v : SLOPE * v;
            Cm[(size_t)r * ldc + c] = v;
        }
    }
}

// ---------- gather-max epilogue ----------
__global__ void k_gathermax(const float* __restrict__ Y, int O, int R,
                            const int* __restrict__ idx, int kc,
                            float* __restrict__ out, int ldo, int ooff) {
    extern __shared__ int sidx[];
    int br = blockIdx.x;
    int b  = br / R;
    int o  = threadIdx.x;
    if (o < kc) sidx[o] = idx[(size_t)br * kc + o];
    __syncthreads();
    int O2 = 2 * O;
    float z = Y[(size_t)br * O2 + O + o];
    float best = -FLT_MAX;
    for (int k = 0; k < kc; ++k) {
        int m = sidx[k];
        best = fmaxf(best, Y[(size_t)(b * R + m) * O2 + o]);
    }
    float r = z + best;
    out[(size_t)br * ldo + ooff + o] = r >= 0.f ? r : SLOPE * r;
}

// ---------- channel -> (ptr, stride) map for the concatenated 451-dim feature ----------
__device__ __forceinline__ void chan_map(int b, int c,
                                         const float* Vf, const float* l1,
                                         const float* l2, const float* l3,
                                         const float*& p, int& st) {
    if (c < 3)        { st = 3;   p = Vf + (size_t)b * N_ * 3   + c; }
    else if (c < 67)  { st = 64;  p = l1 + (size_t)b * N_ * 64  + (c - 3); }
    else if (c < 195) { st = 128; p = l2 + (size_t)b * N_ * 128 + (c - 67); }
    else              { st = 256; p = l3 + (size_t)b * N_ * 256 + (c - 195); }
}

// ---------- pooling phase 1: grid = B*NSLAB; partial sums over a 256-point slab ----------
__global__ __launch_bounds__(256) void k_pool2(const float* __restrict__ Vf,
                                               const float* __restrict__ l1,
                                               const float* __restrict__ l2,
                                               const float* __restrict__ l3,
                                               const float* __restrict__ W,
                                               float* __restrict__ ppool,
                                               float* __restrict__ psw) {
    __shared__ float Wl[SLABN][J_];   // [n][j], row = 96B (float4-aligned)
    int blk  = blockIdx.x;
    int b    = blk / NSLAB, slab = blk % NSLAB;
    int n0   = slab * SLABN;
    int tid  = threadIdx.x;

    for (int e = tid; e < J_ * SLABN; e += 256) {
        int j = e / SLABN, n = e % SLABN;
        Wl[n][j] = W[((size_t)b * J_ + j) * N_ + n0 + n];   // coalesced over n
    }
    __syncthreads();

    if (tid < J_) {                    // per-joint W partial sum
        float s = 0.f;
        for (int n = 0; n < SLABN; ++n) s += Wl[n][tid];
        psw[(size_t)blk * J_ + tid] = s;
    }

    int c0 = tid, c1 = tid + 256;
    const float *p0, *p1 = nullptr; int s0, s1 = 0;
    chan_map(b, c0, Vf, l1, l2, l3, p0, s0);
    bool has1 = (c1 < 451);
    if (has1) chan_map(b, c1, Vf, l1, l2, l3, p1, s1);

    float acc0[J_], acc1[J_];
#pragma unroll
    for (int j = 0; j < J_; ++j) { acc0[j] = 0.f; acc1[j] = 0.f; }

    for (int n = 0; n < SLABN; ++n) {
        float v0 = p0[(size_t)(n0 + n) * s0];
        float v1 = has1 ? p1[(size_t)(n0 + n) * s1] : 0.f;
        const float* wn = &Wl[n][0];
#pragma unroll
        for (int q = 0; q < J_ / 4; ++q) {
            float4 w4 = *(const float4*)(wn + 4 * q);   // broadcast, conflict-free
            acc0[4*q+0] += w4.x * v0;  acc1[4*q+0] += w4.x * v1;
            acc0[4*q+1] += w4.y * v0;  acc1[4*q+1] += w4.y * v1;
            acc0[4*q+2] += w4.z * v0;  acc1[4*q+2] += w4.z * v1;
            acc0[4*q+3] += w4.w * v0;  acc1[4*q+3] += w4.w * v1;
        }
    }
    float* pp = ppool + (size_t)blk * J_ * 451;
#pragma unroll
    for (int j = 0; j < J_; ++j) {
        pp[(size_t)j * 451 + c0] = acc0[j];
        if (has1) pp[(size_t)j * 451 + c1] = acc1[j];
    }
}

// ---------- pooling phase 2: grid = B*J_; reduce NSLAB partials, divide by sumW ----------
__global__ __launch_bounds__(256) void k_poolred(const float* __restrict__ ppool,
                                                 const float* __restrict__ psw,
                                                 float* __restrict__ pooled) {
    int bj = blockIdx.x;               // b*J_ + j
    int b  = bj / J_, j = bj % J_;
    int tid = threadIdx.x;

    float sw = 0.f;
    for (int sl = 0; sl < NSLAB; ++sl) sw += psw[(size_t)(b * NSLAB + sl) * J_ + j];
    float inv = 1.f / (sw + 1e-5f);

    for (int c = tid; c < 451; c += 256) {
        float s = 0.f;
        for (int sl = 0; sl < NSLAB; ++sl)
            s += ppool[((size_t)(b * NSLAB + sl) * J_ + j) * 451 + c];
        pooled[(size_t)bj * 451 + c] = s * inv;
    }
}

extern "C" void kernel_launch(void* const* d_in, const int* in_sizes, int n_in,
                              void* d_out, int out_size, void* d_ws, size_t ws_size,
                              hipStream_t stream) {
    const float* V  = (const float*)d_in[0];   // [4,4096,3]
    const float* W  = (const float*)d_in[1];   // [4,24,4096]
    const int* ringIdx = (const int*)d_in[2];  // [4,24,4]
    const float* g1w = (const float*)d_in[3];
    const float* g1b = (const float*)d_in[4];
    const float* g2w = (const float*)d_in[5];
    const float* g2b = (const float*)d_in[6];
    const float* g3w = (const float*)d_in[7];
    const float* g3b = (const float*)d_in[8];
    const float* s1w = (const float*)d_in[9];
    const float* s1b = (const float*)d_in[10];
    const float* s2w = (const float*)d_in[11];
    const float* s2b = (const float*)d_in[12];
    const float* s3w = (const float*)d_in[13];
    const float* s3b = (const float*)d_in[14];
    const float* m1w = (const float*)d_in[15];
    const float* m1b = (const float*)d_in[16];
    const float* m2w = (const float*)d_in[17];
    const float* m2b = (const float*)d_in[18];
    const float* m3w = (const float*)d_in[19];
    const float* m3b = (const float*)d_in[20];
    (void)ws_size; (void)n_in; (void)in_sizes; (void)out_size;

    // ---- workspace layout (floats), ~62.5 MB ----
    float* ws = (float*)d_ws;
    size_t off = 0;
    float* l1 = ws + off; off += (size_t)B_ * N_ * 64;    // 4MB
    float* l2 = ws + off; off += (size_t)B_ * N_ * 128;   // 8MB
    float* l3 = ws + off; off += (size_t)B_ * N_ * 256;   // 16MB
    float* xx = ws + off; off += (size_t)B_ * N_;
    // D slab (32MB) aliases Y (max 32MB) and ppool/psw (2.8MB);
    // qc (1.31MB) aliases l3 (dead until layer-3 gathermax, after last select).
    float* D  = ws + off; off += (size_t)ROWT * N_;
    float* Y  = D;
    float* ppool = D;
    float* psw   = D + (size_t)B_ * NSLAB * J_ * 451;
    unsigned long long* qc = (unsigned long long*)l3;     // ROWT*4*20*8B = 1.31MB
    int* knnIdx = (int*)(ws + off); off += (size_t)B_ * N_ * KNN_;
    float* pooled = ws + off; off += (size_t)B_ * J_ * 451;
    float* joints = ws + off; off += (size_t)B_ * J_ * 448;
    float* h1 = ws + off; off += (size_t)B_ * J_ * 512;
    float* h2 = ws + off; off += (size_t)B_ * J_ * 256;
    float* P  = ws + off; off += (size_t)451 * 512;       // reused for all P / wT
    float* bias2 = ws + off; off += 512;

    const int M = B_ * N_;   // 16384
    const int MJ = B_ * J_;  // 96

    // ======== geoNet layer 1: C=3 -> O=64 ========
    k_norm<<<(M + 255) / 256, 256, 0, stream>>>(V, xx, 3);
    for (int b = 0; b < B_; ++b)
        for (int rb = 0; rb < N_; rb += ROWT) {
            k_dist<<<dim3(32, ROWT / 128), 256, 0, stream>>>(V + (size_t)b * N_ * 3, 3, xx + b * N_, D, rb);
            k_sel1<<<ROWT, 256, 0, stream>>>(D, qc);
            k_sel2<<<ROWT / 4, 256, 0, stream>>>(qc, knnIdx + (size_t)b * N_ * KNN_, rb);
        }
    k_prepP<<<(3 * 128 + 255) / 256, 256, 0, stream>>>(g1w, g1b, 3, 64, P, bias2);
    k_gemm<<<dim3(2, M / 64), 256, 0, stream>>>(V, 3, P, Y, 128, M, 128, 3, bias2, 0);
    k_gathermax<<<M, 64, KNN_ * sizeof(int), stream>>>(Y, 64, N_, knnIdx, KNN_, l1, 64, 0);

    // ======== layer 2: C=64 -> O=128 ========
    k_norm<<<(M + 255) / 256, 256, 0, stream>>>(l1, xx, 64);
    for (int b = 0; b < B_; ++b)
        for (int rb = 0; rb < N_; rb += ROWT) {
            k_dist<<<dim3(32, ROWT / 128), 256, 0, stream>>>(l1 + (size_t)b * N_ * 64, 64, xx + b * N_, D, rb);
            k_sel1<<<ROWT, 256, 0, stream>>>(D, qc);
            k_sel2<<<ROWT / 4, 256, 0, stream>>>(qc, knnIdx + (size_t)b * N_ * KNN_, rb);
        }
    k_prepP<<<(64 * 256 + 255) / 256, 256, 0, stream>>>(g2w, g2b, 64, 128, P, bias2);
    k_gemm<<<dim3(4, M / 64), 256, 0, stream>>>(l1, 64, P, Y, 256, M, 256, 64, bias2, 0);
    k_gathermax<<<M, 128, KNN_ * sizeof(int), stream>>>(Y, 128, N_, knnIdx, KNN_, l2, 128, 0);

    // ======== layer 3: C=128 -> O=256 ========
    k_norm<<<(M + 255) / 256, 256, 0, stream>>>(l2, xx, 128);
    for (int b = 0; b < B_; ++b)
        for (int rb = 0; rb < N_; rb += ROWT) {
            k_dist<<<dim3(32, ROWT / 128), 256, 0, stream>>>(l2 + (size_t)b * N_ * 128, 128, xx + b * N_, D, rb);
            k_sel1<<<ROWT, 256, 0, stream>>>(D, qc);
            k_sel2<<<ROWT / 4, 256, 0, stream>>>(qc, knnIdx + (size_t)b * N_ * KNN_, rb);
        }
    k_prepP<<<(128 * 512 + 255) / 256, 256, 0, stream>>>(g3w, g3b, 128, 256, P, bias2);
    k_gemm<<<dim3(8, M / 64), 256, 0, stream>>>(l2, 128, P, Y, 512, M, 512, 128, bias2, 0);
    k_gathermax<<<M, 256, KNN_ * sizeof(int), stream>>>(Y, 256, N_, knnIdx, KNN_, l3, 256, 0);

    // ======== pooling onto joints (two-phase) ========
    k_pool2<<<B_ * NSLAB, 256, 0, stream>>>(V, l1, l2, l3, W, ppool, psw);
    k_poolred<<<MJ, 256, 0, stream>>>(ppool, psw, pooled);

    // ======== skeleton conv 1: C=451 -> O=256 ========
    k_prepP<<<(451 * 512 + 255) / 256, 256, 0, stream>>>(s1w, s1b, 451, 256, P, bias2);
    k_gemm<<<dim3(8, 2), 256, 0, stream>>>(pooled, 451, P, Y, 512, MJ, 512, 451, bias2, 0);
    k_gathermax<<<MJ, 256, KR_ * sizeof(int), stream>>>(Y, 256, J_, ringIdx, KR_, joints, 448, 0);

    // ======== skeleton conv 2: C=256 -> O=128 ========
    k_prepP<<<(256 * 256 + 255) / 256, 256, 0, stream>>>(s2w, s2b, 256, 128, P, bias2);
    k_gemm<<<dim3(4, 2), 256, 0, stream>>>(joints, 448, P, Y, 256, MJ, 256, 256, bias2, 0);
    k_gathermax<<<MJ, 128, KR_ * sizeof(int), stream>>>(Y, 128, J_, ringIdx, KR_, joints, 448, 256);

    // ======== skeleton conv 3: C=128 -> O=64 ========
    k_prepP<<<(128 * 128 + 255) / 256, 256, 0, stream>>>(s3w, s3b, 128, 64, P, bias2);
    k_gemm<<<dim3(2, 2), 256, 0, stream>>>(joints + 256, 448, P, Y, 128, MJ, 128, 128, bias2, 0);
    k_gathermax<<<MJ, 64, KR_ * sizeof(int), stream>>>(Y, 64, J_, ringIdx, KR_, joints, 448, 384);

    // ======== joint MLP ========
    k_transp<<<(512 * 448 + 255) / 256, 256, 0, stream>>>(m1w, 512, 448, P);
    k_gemm<<<dim3(8, 2), 256, 0, stream>>>(joints, 448, P, h1, 512, MJ, 512, 448, m1b, 1);
    k_transp<<<(256 * 512 + 255) / 256, 256, 0, stream>>>(m2w, 256, 512, P);
    k_gemm<<<dim3(4, 2), 256, 0, stream>>>(h1, 512, P, h2, 256, MJ, 256, 512, m2b, 1);
    k_transp<<<(3 * 256 + 255) / 256, 256, 0, stream>>>(m3w, 3, 256, P);
    k_gemm<<<dim3(1, 2), 256, 0, stream>>>(h2, 256, P, (float*)d_out, 3, MJ, 3, 256, m3b, 0);
}

// Round 8
// 2269.739 us; speedup vs baseline: 4.7016x; 1.0767x over previous
//
#include <hip/hip_runtime.h>
#include <hip/hip_bf16.h>
#include <float.h>

// Problem constants (from reference setup_inputs)
#define B_   4
#define N_   4096
#define J_   24
#define KR_  4
#define KNN_ 20
#define SLOPE 0.2f
#define ROWT 2048   // rows per distance slab (slab = ROWT x N_ f32 = 32 MB)
#define SLABN 256   // points per pooling slab
#define NSLAB (N_ / SLABN)   // 16

// ---------- per-point squared norm ----------
__global__ void k_norm(const float* __restrict__ h, float* __restrict__ xx, int C) {
    int i = blockIdx.x * blockDim.x + threadIdx.x;  // b*N + n
    if (i >= B_ * N_) return;
    const float* hp = h + (size_t)i * C;
    float s = 0.f;
    for (int c = 0; c < C; ++c) { float v = hp[c]; s += v * v; }
    xx[i] = s;
}

// ---------- distance GEMM, one row-slab of one batch ----------
// D[grow-rowbase, m] = xx[grow] + xx[m] - 2*dot(X[grow], X[m])
__global__ __launch_bounds__(256) void k_dist(const float* __restrict__ X, int C,
                                              const float* __restrict__ xxb,
                                              float* __restrict__ D, int rowbase) {
    __shared__ float As[16][136];   // [k][row], 136*4=544B rows: float4-aligned
    __shared__ float Bs[16][136];
    int tid = threadIdx.x;
    int row0 = rowbase + blockIdx.y * 128;   // global row
    int col0 = blockIdx.x * 128;             // global col
    int tr = tid >> 4, tc = tid & 15;
    float acc[8][8] = {{0.f}};
    for (int kt = 0; kt < C; kt += 16) {
#pragma unroll
        for (int i = 0; i < 8; ++i) {
            int e = tid + 256 * i;
            int r = e >> 4, kk = e & 15;     // r in [0,128), kk in [0,16)
            int gk = kt + kk;
            As[kk][r] = (gk < C) ? X[(size_t)(row0 + r) * C + gk] : 0.f;
            Bs[kk][r] = (gk < C) ? X[(size_t)(col0 + r) * C + gk] : 0.f;
        }
        __syncthreads();
#pragma unroll
        for (int kk = 0; kk < 16; ++kk) {
            float a[8], bv[8];
            *(float4*)&a[0]  = *(const float4*)&As[kk][tr * 8];
            *(float4*)&a[4]  = *(const float4*)&As[kk][tr * 8 + 4];
            *(float4*)&bv[0] = *(const float4*)&Bs[kk][tc * 8];
            *(float4*)&bv[4] = *(const float4*)&Bs[kk][tc * 8 + 4];
#pragma unroll
            for (int i = 0; i < 8; ++i)
#pragma unroll
                for (int j = 0; j < 8; ++j) acc[i][j] += a[i] * bv[j];
        }
        __syncthreads();
    }
    float xc[8];
#pragma unroll
    for (int j = 0; j < 8; ++j) xc[j] = xxb[col0 + tc * 8 + j];
#pragma unroll
    for (int i = 0; i < 8; ++i) {
        int grow = row0 + tr * 8 + i;
        float xr = xxb[grow];
        float4 o0, o1;
        o0.x = xr + xc[0] - 2.f * acc[i][0];
        o0.y = xr + xc[1] - 2.f * acc[i][1];
        o0.z = xr + xc[2] - 2.f * acc[i][2];
        o0.w = xr + xc[3] - 2.f * acc[i][3];
        o1.x = xr + xc[4] - 2.f * acc[i][4];
        o1.y = xr + xc[5] - 2.f * acc[i][5];
        o1.z = xr + xc[6] - 2.f * acc[i][6];
        o1.w = xr + xc[7] - 2.f * acc[i][7];
        float* dp = D + (size_t)(grow - rowbase) * N_ + col0 + tc * 8;
        *(float4*)dp       = o0;
        *(float4*)(dp + 4) = o1;
    }
}

// ---------- selection phase 1: one wave per quarter-row; exact quarter top-20 ----------
__device__ __forceinline__ unsigned mapf(float f) {
    unsigned u = __float_as_uint(f);
    return (u & 0x80000000u) ? ~u : (u | 0x80000000u);
}

__global__ __launch_bounds__(256) void k_sel1(const float* __restrict__ Db,
                                              unsigned long long* __restrict__ qc) {
    const unsigned long long SENT = ~0ull;
    int ql   = blockIdx.x;                    // local row in slab
    int wv   = threadIdx.x >> 6;              // quarter 0..3
    int lane = threadIdx.x & 63;
    int gbase = wv * 1024 + lane * 16;        // lane owns 16 contiguous cols
    const float* seg = Db + (size_t)ql * N_ + gbase;

    float4 v4[4];
    v4[0] = *(const float4*)(seg);
    v4[1] = *(const float4*)(seg + 4);
    v4[2] = *(const float4*)(seg + 8);
    v4[3] = *(const float4*)(seg + 12);
    const float* vv = (const float*)v4;

    unsigned long long b0 = SENT, b1 = SENT;
    unsigned emask = 0;                       // popped elements of my 16
#pragma unroll
    for (int t = 0; t < 16; ++t) {
        unsigned long long key = ((unsigned long long)mapf(vv[t]) << 32) | (unsigned)(gbase + t);
        if (key < b1) { if (key < b0) { b1 = b0; b0 = key; } else b1 = key; }
    }
    unsigned long long* out = qc + ((size_t)ql * 4 + wv) * KNN_;
    for (int k = 0; k < KNN_; ++k) {
        if (b0 == SENT) {                     // rare refill: rescan my 16 (L2-hot)
            b1 = SENT;
            for (int t = 0; t < 16; ++t) {
                if ((emask >> t) & 1u) continue;
                unsigned long long key = ((unsigned long long)mapf(seg[t]) << 32) | (unsigned)(gbase + t);
                if (key < b1) { if (key < b0) { b1 = b0; b0 = key; } else b1 = key; }
            }
        }
        unsigned long long m = b0;
#pragma unroll
        for (int s = 32; s > 0; s >>= 1) {
            unsigned long long o = (unsigned long long)__shfl_xor((long long)m, s, 64);
            if (o < m) m = o;
        }
        if (m == b0) {                        // unique keys -> exactly one owner
            emask |= 1u << ((unsigned)m & 15u);
            b0 = b1; b1 = SENT;
        }
        if (lane == 0) out[k] = m;
    }
}

// ---------- selection phase 2: one wave per row; merge 4x20 candidates (refill-free) ----------
__global__ __launch_bounds__(256) void k_sel2(const unsigned long long* __restrict__ qc,
                                              int* __restrict__ idxout, int qbase) {
    const unsigned long long SENT = ~0ull;
    int ql   = blockIdx.x * 4 + (threadIdx.x >> 6);
    int lane = threadIdx.x & 63;
    const unsigned long long* row = qc + (size_t)ql * 80;

    unsigned long long b0 = row[lane];                        // cands 0..63
    unsigned long long b1 = (lane < 16) ? row[64 + lane] : SENT;  // cands 64..79
    if (b1 < b0) { unsigned long long t = b0; b0 = b1; b1 = t; }

    int qg = qbase + ql;
    for (int k = 0; k < KNN_; ++k) {
        unsigned long long m = b0;
#pragma unroll
        for (int s = 32; s > 0; s >>= 1) {
            unsigned long long o = (unsigned long long)__shfl_xor((long long)m, s, 64);
            if (o < m) m = o;
        }
        if (m == b0) { b0 = b1; b1 = SENT; }  // <=2 cands/lane -> never refills
        if (lane == 0) idxout[qg * KNN_ + k] = (int)(unsigned)m;
    }
}

// ---------- build projection P[K=C][2O]: [wA^T | (wB-wA)^T], bias2[2O]=[0|bias] ----------
__global__ void k_prepP(const float* __restrict__ w, const float* __restrict__ bias,
                        int C, int O, float* __restrict__ P, float* __restrict__ bias2) {
    int i = blockIdx.x * blockDim.x + threadIdx.x;
    int O2 = 2 * O;
    if (i < O2) bias2[i] = (i < O) ? 0.f : bias[i - O];
    int total = C * O2;
    if (i >= total) return;
    int k = i / O2, col = i % O2;
    float v;
    if (col < O) {
        v = w[(size_t)col * 2 * C + k];                               // wA^T
    } else {
        int o = col - O;
        v = w[(size_t)o * 2 * C + C + k] - w[(size_t)o * 2 * C + k]; // (wB - wA)^T
    }
    P[i] = v;
}

// ---------- transpose w[O][K] -> wT[K][O] ----------
__global__ void k_transp(const float* __restrict__ w, int O, int K, float* __restrict__ wT) {
    int i = blockIdx.x * blockDim.x + threadIdx.x;
    if (i >= O * K) return;
    int k = i / O, o = i % O;
    wT[i] = w[(size_t)o * K + k];
}

// ---------- tiled f32 GEMM (large M): C[M,N] = A[M,K](lda) @ Bm[K,N] ----------
__global__ __launch_bounds__(256) void k_gemm(const float* __restrict__ A, int lda,
                                              const float* __restrict__ Bm,
                                              float* __restrict__ Cm, int ldc,
                                              int M, int N, int K,
                                              const float* __restrict__ bias, int leaky) {
    __shared__ float As[16][65];
    __shared__ float Bs[16][64];
    int tid = threadIdx.x;
    int row0 = blockIdx.y * 64, col0 = blockIdx.x * 64;
    int tr = tid >> 4, tc = tid & 15;
    float acc[4][4] = {{0.f}};
    for (int kt = 0; kt < K; kt += 16) {
#pragma unroll
        for (int i = 0; i < 4; ++i) {           // A tile: 64 rows x 16 k
            int e = tid + 256 * i;
            int r = e >> 4, kk = e & 15;
            int gr = row0 + r, gk = kt + kk;
            float v = 0.f;
            if (gr < M && gk < K) v = A[(size_t)gr * lda + gk];
            As[kk][r] = v;
        }
#pragma unroll
        for (int i = 0; i < 4; ++i) {           // B tile: 16 k x 64 cols
            int e = tid + 256 * i;
            int kk = e >> 6, c = e & 63;
            int gk = kt + kk, gc = col0 + c;
            float v = 0.f;
            if (gk < K && gc < N) v = Bm[(size_t)gk * N + gc];
            Bs[kk][c] = v;
        }
        __syncthreads();
#pragma unroll
        for (int kk = 0; kk < 16; ++kk) {
            float a[4], bv[4];
#pragma unroll
            for (int i = 0; i < 4; ++i) a[i] = As[kk][tr + 16 * i];
#pragma unroll
            for (int j = 0; j < 4; ++j) bv[j] = Bs[kk][tc + 16 * j];
#pragma unroll
            for (int i = 0; i < 4; ++i)
#pragma unroll
                for (int j = 0; j < 4; ++j) acc[i][j] += a[i] * bv[j];
        }
        __syncthreads();
    }
#pragma unroll
    for (int i = 0; i < 4; ++i) {
        int r = row0 + tr + 16 * i;
        if (r >= M) continue;
#pragma unroll
        for (int j = 0; j < 4; ++j) {
            int c = col0 + tc + 16 * j;
            if (c >= N) continue;
            float v = acc[i][j];
            if (bias) v += bias[c];
            if (leaky) v = v >= 0.f ? v : SLOPE * v;
            Cm[(size_t)r * ldc + c] = v;
        }
    }
}

// ---------- small-M GEMM: grid = (M rows) x (col chunks of 256) ----------
// A row staged in LDS (broadcast reads); Bm reads coalesced across threads;
// K-loop unrolls into many independent outstanding loads. For tiny M the
// 64x64-tile k_gemm is latency-bound at 16 blocks; this gives M*N/256 blocks.
__global__ __launch_bounds__(256) void k_sgemm(const float* __restrict__ A, int lda,
                                               const float* __restrict__ Bm,
                                               float* __restrict__ Cm, int ldc,
                                               int N, int K,
                                               const float* __restrict__ bias, int leaky) {
    extern __shared__ float Arow[];          // K floats
    int r   = blockIdx.x;
    int c0  = blockIdx.y * 256;
    int tid = threadIdx.x;
    for (int k = tid; k < K; k += 256) Arow[k] = A[(size_t)r * lda + k];
    __syncthreads();
    int c = c0 + tid;
    if (c >= N) return;
    float acc = bias ? bias[c] : 0.f;
    for (int k = 0; k < K; ++k) acc += Arow[k] * Bm[(size_t)k * N + c];
    if (leaky) acc = acc >= 0.f ? acc : SLOPE * acc;
    Cm[(size_t)r * ldc + c] = acc;
}

// ---------- gather-max epilogue ----------
__global__ void k_gathermax(const float* __restrict__ Y, int O, int R,
                            const int* __restrict__ idx, int kc,
                            float* __restrict__ out, int ldo, int ooff) {
    extern __shared__ int sidx[];
    int br = blockIdx.x;
    int b  = br / R;
    int o  = threadIdx.x;
    if (o < kc) sidx[o] = idx[(size_t)br * kc + o];
    __syncthreads();
    int O2 = 2 * O;
    float z = Y[(size_t)br * O2 + O + o];
    float best = -FLT_MAX;
    for (int k = 0; k < kc; ++k) {
        int m = sidx[k];
        best = fmaxf(best, Y[(size_t)(b * R + m) * O2 + o]);
    }
    float r = z + best;
    out[(size_t)br * ldo + ooff + o] = r >= 0.f ? r : SLOPE * r;
}

// ---------- channel -> (ptr, stride) map for the concatenated 451-dim feature ----------
__device__ __forceinline__ void chan_map(int b, int c,
                                         const float* Vf, const float* l1,
                                         const float* l2, const float* l3,
                                         const float*& p, int& st) {
    if (c < 3)        { st = 3;   p = Vf + (size_t)b * N_ * 3   + c; }
    else if (c < 67)  { st = 64;  p = l1 + (size_t)b * N_ * 64  + (c - 3); }
    else if (c < 195) { st = 128; p = l2 + (size_t)b * N_ * 128 + (c - 67); }
    else              { st = 256; p = l3 + (size_t)b * N_ * 256 + (c - 195); }
}

// ---------- pooling phase 1: grid = B*NSLAB; partial sums over a 256-point slab ----------
__global__ __launch_bounds__(256) void k_pool2(const float* __restrict__ Vf,
                                               const float* __restrict__ l1,
                                               const float* __restrict__ l2,
                                               const float* __restrict__ l3,
                                               const float* __restrict__ W,
                                               float* __restrict__ ppool,
                                               float* __restrict__ psw) {
    __shared__ float Wl[SLABN][J_];   // [n][j], row = 96B (float4-aligned)
    int blk  = blockIdx.x;
    int b    = blk / NSLAB, slab = blk % NSLAB;
    int n0   = slab * SLABN;
    int tid  = threadIdx.x;

    for (int e = tid; e < J_ * SLABN; e += 256) {
        int j = e / SLABN, n = e % SLABN;
        Wl[n][j] = W[((size_t)b * J_ + j) * N_ + n0 + n];   // coalesced over n
    }
    __syncthreads();

    if (tid < J_) {                    // per-joint W partial sum
        float s = 0.f;
        for (int n = 0; n < SLABN; ++n) s += Wl[n][tid];
        psw[(size_t)blk * J_ + tid] = s;
    }

    int c0 = tid, c1 = tid + 256;
    const float *p0, *p1 = nullptr; int s0, s1 = 0;
    chan_map(b, c0, Vf, l1, l2, l3, p0, s0);
    bool has1 = (c1 < 451);
    if (has1) chan_map(b, c1, Vf, l1, l2, l3, p1, s1);

    float acc0[J_], acc1[J_];
#pragma unroll
    for (int j = 0; j < J_; ++j) { acc0[j] = 0.f; acc1[j] = 0.f; }

    for (int n = 0; n < SLABN; ++n) {
        float v0 = p0[(size_t)(n0 + n) * s0];
        float v1 = has1 ? p1[(size_t)(n0 + n) * s1] : 0.f;
        const float* wn = &Wl[n][0];
#pragma unroll
        for (int q = 0; q < J_ / 4; ++q) {
            float4 w4 = *(const float4*)(wn + 4 * q);   // broadcast, conflict-free
            acc0[4*q+0] += w4.x * v0;  acc1[4*q+0] += w4.x * v1;
            acc0[4*q+1] += w4.y * v0;  acc1[4*q+1] += w4.y * v1;
            acc0[4*q+2] += w4.z * v0;  acc1[4*q+2] += w4.z * v1;
            acc0[4*q+3] += w4.w * v0;  acc1[4*q+3] += w4.w * v1;
        }
    }
    float* pp = ppool + (size_t)blk * J_ * 451;
#pragma unroll
    for (int j = 0; j < J_; ++j) {
        pp[(size_t)j * 451 + c0] = acc0[j];
        if (has1) pp[(size_t)j * 451 + c1] = acc1[j];
    }
}

// ---------- pooling phase 2: grid = B*J_; reduce NSLAB partials, divide by sumW ----------
__global__ __launch_bounds__(256) void k_poolred(const float* __restrict__ ppool,
                                                 const float* __restrict__ psw,
                                                 float* __restrict__ pooled) {
    int bj = blockIdx.x;               // b*J_ + j
    int b  = bj / J_, j = bj % J_;
    int tid = threadIdx.x;

    float sw = 0.f;
    for (int sl = 0; sl < NSLAB; ++sl) sw += psw[(size_t)(b * NSLAB + sl) * J_ + j];
    float inv = 1.f / (sw + 1e-5f);

    for (int c = tid; c < 451; c += 256) {
        float s = 0.f;
        for (int sl = 0; sl < NSLAB; ++sl)
            s += ppool[((size_t)(b * NSLAB + sl) * J_ + j) * 451 + c];
        pooled[(size_t)bj * 451 + c] = s * inv;
    }
}

extern "C" void kernel_launch(void* const* d_in, const int* in_sizes, int n_in,
                              void* d_out, int out_size, void* d_ws, size_t ws_size,
                              hipStream_t stream) {
    const float* V  = (const float*)d_in[0];   // [4,4096,3]
    const float* W  = (const float*)d_in[1];   // [4,24,4096]
    const int* ringIdx = (const int*)d_in[2];  // [4,24,4]
    const float* g1w = (const float*)d_in[3];
    const float* g1b = (const float*)d_in[4];
    const float* g2w = (const float*)d_in[5];
    const float* g2b = (const float*)d_in[6];
    const float* g3w = (const float*)d_in[7];
    const float* g3b = (const float*)d_in[8];
    const float* s1w = (const float*)d_in[9];
    const float* s1b = (const float*)d_in[10];
    const float* s2w = (const float*)d_in[11];
    const float* s2b = (const float*)d_in[12];
    const float* s3w = (const float*)d_in[13];
    const float* s3b = (const float*)d_in[14];
    const float* m1w = (const float*)d_in[15];
    const float* m1b = (const float*)d_in[16];
    const float* m2w = (const float*)d_in[17];
    const float* m2b = (const float*)d_in[18];
    const float* m3w = (const float*)d_in[19];
    const float* m3b = (const float*)d_in[20];
    (void)ws_size; (void)n_in; (void)in_sizes; (void)out_size;

    // ---- workspace layout (floats), ~62.5 MB ----
    float* ws = (float*)d_ws;
    size_t off = 0;
    float* l1 = ws + off; off += (size_t)B_ * N_ * 64;    // 4MB
    float* l2 = ws + off; off += (size_t)B_ * N_ * 128;   // 8MB
    float* l3 = ws + off; off += (size_t)B_ * N_ * 256;   // 16MB
    float* xx = ws + off; off += (size_t)B_ * N_;
    // D slab (32MB) aliases Y (max 32MB) and ppool/psw (2.8MB);
    // qc (1.31MB) aliases l3 (dead until layer-3 gathermax, after last select).
    float* D  = ws + off; off += (size_t)ROWT * N_;
    float* Y  = D;
    float* ppool = D;
    float* psw   = D + (size_t)B_ * NSLAB * J_ * 451;
    unsigned long long* qc = (unsigned long long*)l3;     // ROWT*4*20*8B = 1.31MB
    int* knnIdx = (int*)(ws + off); off += (size_t)B_ * N_ * KNN_;
    float* pooled = ws + off; off += (size_t)B_ * J_ * 451;
    float* joints = ws + off; off += (size_t)B_ * J_ * 448;
    float* h1 = ws + off; off += (size_t)B_ * J_ * 512;
    float* h2 = ws + off; off += (size_t)B_ * J_ * 256;
    float* P  = ws + off; off += (size_t)451 * 512;       // reused for all P / wT
    float* bias2 = ws + off; off += 512;

    const int M = B_ * N_;   // 16384
    const int MJ = B_ * J_;  // 96

    // ======== geoNet layer 1: C=3 -> O=64 ========
    k_norm<<<(M + 255) / 256, 256, 0, stream>>>(V, xx, 3);
    for (int b = 0; b < B_; ++b)
        for (int rb = 0; rb < N_; rb += ROWT) {
            k_dist<<<dim3(32, ROWT / 128), 256, 0, stream>>>(V + (size_t)b * N_ * 3, 3, xx + b * N_, D, rb);
            k_sel1<<<ROWT, 256, 0, stream>>>(D, qc);
            k_sel2<<<ROWT / 4, 256, 0, stream>>>(qc, knnIdx + (size_t)b * N_ * KNN_, rb);
        }
    k_prepP<<<(3 * 128 + 255) / 256, 256, 0, stream>>>(g1w, g1b, 3, 64, P, bias2);
    k_gemm<<<dim3(2, M / 64), 256, 0, stream>>>(V, 3, P, Y, 128, M, 128, 3, bias2, 0);
    k_gathermax<<<M, 64, KNN_ * sizeof(int), stream>>>(Y, 64, N_, knnIdx, KNN_, l1, 64, 0);

    // ======== layer 2: C=64 -> O=128 ========
    k_norm<<<(M + 255) / 256, 256, 0, stream>>>(l1, xx, 64);
    for (int b = 0; b < B_; ++b)
        for (int rb = 0; rb < N_; rb += ROWT) {
            k_dist<<<dim3(32, ROWT / 128), 256, 0, stream>>>(l1 + (size_t)b * N_ * 64, 64, xx + b * N_, D, rb);
            k_sel1<<<ROWT, 256, 0, stream>>>(D, qc);
            k_sel2<<<ROWT / 4, 256, 0, stream>>>(qc, knnIdx + (size_t)b * N_ * KNN_, rb);
        }
    k_prepP<<<(64 * 256 + 255) / 256, 256, 0, stream>>>(g2w, g2b, 64, 128, P, bias2);
    k_gemm<<<dim3(4, M / 64), 256, 0, stream>>>(l1, 64, P, Y, 256, M, 256, 64, bias2, 0);
    k_gathermax<<<M, 128, KNN_ * sizeof(int), stream>>>(Y, 128, N_, knnIdx, KNN_, l2, 128, 0);

    // ======== layer 3: C=128 -> O=256 ========
    k_norm<<<(M + 255) / 256, 256, 0, stream>>>(l2, xx, 128);
    for (int b = 0; b < B_; ++b)
        for (int rb = 0; rb < N_; rb += ROWT) {
            k_dist<<<dim3(32, ROWT / 128), 256, 0, stream>>>(l2 + (size_t)b * N_ * 128, 128, xx + b * N_, D, rb);
            k_sel1<<<ROWT, 256, 0, stream>>>(D, qc);
            k_sel2<<<ROWT / 4, 256, 0, stream>>>(qc, knnIdx + (size_t)b * N_ * KNN_, rb);
        }
    k_prepP<<<(128 * 512 + 255) / 256, 256, 0, stream>>>(g3w, g3b, 128, 256, P, bias2);
    k_gemm<<<dim3(8, M / 64), 256, 0, stream>>>(l2, 128, P, Y, 512, M, 512, 128, bias2, 0);
    k_gathermax<<<M, 256, KNN_ * sizeof(int), stream>>>(Y, 256, N_, knnIdx, KNN_, l3, 256, 0);

    // ======== pooling onto joints (two-phase) ========
    k_pool2<<<B_ * NSLAB, 256, 0, stream>>>(V, l1, l2, l3, W, ppool, psw);
    k_poolred<<<MJ, 256, 0, stream>>>(ppool, psw, pooled);

    // ======== skeleton conv 1: C=451 -> O=256 (small-M GEMM path) ========
    k_prepP<<<(451 * 512 + 255) / 256, 256, 0, stream>>>(s1w, s1b, 451, 256, P, bias2);
    k_sgemm<<<dim3(MJ, 2), 256, 451 * sizeof(float), stream>>>(pooled, 451, P, Y, 512, 512, 451, bias2, 0);
    k_gathermax<<<MJ, 256, KR_ * sizeof(int), stream>>>(Y, 256, J_, ringIdx, KR_, joints, 448, 0);

    // ======== skeleton conv 2: C=256 -> O=128 ========
    k_prepP<<<(256 * 256 + 255) / 256, 256, 0, stream>>>(s2w, s2b, 256, 128, P, bias2);
    k_sgemm<<<dim3(MJ, 1), 256, 256 * sizeof(float), stream>>>(joints, 448, P, Y, 256, 256, 256, bias2, 0);
    k_gathermax<<<MJ, 128, KR_ * sizeof(int), stream>>>(Y, 128, J_, ringIdx, KR_, joints, 448, 256);

    // ======== skeleton conv 3: C=128 -> O=64 ========
    k_prepP<<<(128 * 128 + 255) / 256, 256, 0, stream>>>(s3w, s3b, 128, 64, P, bias2);
    k_sgemm<<<dim3(MJ, 1), 256, 128 * sizeof(float), stream>>>(joints + 256, 448, P, Y, 128, 128, 128, bias2, 0);
    k_gathermax<<<MJ, 64, KR_ * sizeof(int), stream>>>(Y, 64, J_, ringIdx, KR_, joints, 448, 384);

    // ======== joint MLP ========
    k_transp<<<(512 * 448 + 255) / 256, 256, 0, stream>>>(m1w, 512, 448, P);
    k_sgemm<<<dim3(MJ, 2), 256, 448 * sizeof(float), stream>>>(joints, 448, P, h1, 512, 512, 448, m1b, 1);
    k_transp<<<(256 * 512 + 255) / 256, 256, 0, stream>>>(m2w, 256, 512, P);
    k_sgemm<<<dim3(MJ, 1), 256, 512 * sizeof(float), stream>>>(h1, 512, P, h2, 256, 256, 512, m2b, 1);
    k_transp<<<(3 * 256 + 255) / 256, 256, 0, stream>>>(m3w, 3, 256, P);
    k_sgemm<<<dim3(MJ, 1), 256, 256 * sizeof(float), stream>>>(h2, 256, P, (float*)d_out, 3, 3, 256, m3b, 0);
}

// Round 9
// 1902.659 us; speedup vs baseline: 5.6087x; 1.1929x over previous
//
#include <hip/hip_runtime.h>
#include <hip/hip_bf16.h>
#include <float.h>

// Problem constants (from reference setup_inputs)
#define B_   4
#define N_   4096
#define J_   24
#define KR_  4
#define KNN_ 20
#define SLOPE 0.2f
#define SLABN 64             // points per pooling slab
#define NSLAB (N_ / SLABN)   // 64

// ---------- per-point squared norm (only needed for V; layers get it from gathermax) ----------
__global__ void k_norm(const float* __restrict__ h, float* __restrict__ xx, int C) {
    int i = blockIdx.x * blockDim.x + threadIdx.x;  // b*N + n
    if (i >= B_ * N_) return;
    const float* hp = h + (size_t)i * C;
    float s = 0.f;
    for (int c = 0; c < C; ++c) { float v = hp[c]; s += v * v; }
    xx[i] = s;
}

// ---------- distance GEMM, one row-slab of one batch ----------
// D[grow-rowbase, m] = xx[grow] + xx[m] - 2*dot(X[grow], X[m])
__global__ __launch_bounds__(256) void k_dist(const float* __restrict__ X, int C,
                                              const float* __restrict__ xxb,
                                              float* __restrict__ D, int rowbase) {
    __shared__ float As[16][136];   // [k][row], 136*4=544B rows: float4-aligned
    __shared__ float Bs[16][136];
    int tid = threadIdx.x;
    int row0 = rowbase + blockIdx.y * 128;   // global row
    int col0 = blockIdx.x * 128;             // global col
    int tr = tid >> 4, tc = tid & 15;
    float acc[8][8] = {{0.f}};
    for (int kt = 0; kt < C; kt += 16) {
#pragma unroll
        for (int i = 0; i < 8; ++i) {
            int e = tid + 256 * i;
            int r = e >> 4, kk = e & 15;     // r in [0,128), kk in [0,16)
            int gk = kt + kk;
            As[kk][r] = (gk < C) ? X[(size_t)(row0 + r) * C + gk] : 0.f;
            Bs[kk][r] = (gk < C) ? X[(size_t)(col0 + r) * C + gk] : 0.f;
        }
        __syncthreads();
#pragma unroll
        for (int kk = 0; kk < 16; ++kk) {
            float a[8], bv[8];
            *(float4*)&a[0]  = *(const float4*)&As[kk][tr * 8];
            *(float4*)&a[4]  = *(const float4*)&As[kk][tr * 8 + 4];
            *(float4*)&bv[0] = *(const float4*)&Bs[kk][tc * 8];
            *(float4*)&bv[4] = *(const float4*)&Bs[kk][tc * 8 + 4];
#pragma unroll
            for (int i = 0; i < 8; ++i)
#pragma unroll
                for (int j = 0; j < 8; ++j) acc[i][j] += a[i] * bv[j];
        }
        __syncthreads();
    }
    float xc[8];
#pragma unroll
    for (int j = 0; j < 8; ++j) xc[j] = xxb[col0 + tc * 8 + j];
#pragma unroll
    for (int i = 0; i < 8; ++i) {
        int grow = row0 + tr * 8 + i;
        float xr = xxb[grow];
        float4 o0, o1;
        o0.x = xr + xc[0] - 2.f * acc[i][0];
        o0.y = xr + xc[1] - 2.f * acc[i][1];
        o0.z = xr + xc[2] - 2.f * acc[i][2];
        o0.w = xr + xc[3] - 2.f * acc[i][3];
        o1.x = xr + xc[4] - 2.f * acc[i][4];
        o1.y = xr + xc[5] - 2.f * acc[i][5];
        o1.z = xr + xc[6] - 2.f * acc[i][6];
        o1.w = xr + xc[7] - 2.f * acc[i][7];
        float* dp = D + (size_t)(grow - rowbase) * N_ + col0 + tc * 8;
        *(float4*)dp       = o0;
        *(float4*)(dp + 4) = o1;
    }
}

// ---------- fused top-20 selection: one block per row ----------
// Waves 0-3 each produce their quarter's exact top-20 (u64 keys) into LDS;
// wave 0 merges the 80 candidates refill-free. Same key order as lax.top_k.
__device__ __forceinline__ unsigned mapf(float f) {
    unsigned u = __float_as_uint(f);
    return (u & 0x80000000u) ? ~u : (u | 0x80000000u);
}

__global__ __launch_bounds__(256) void k_sel(const float* __restrict__ Db,
                                             int* __restrict__ idxout, int qbase) {
    const unsigned long long SENT = ~0ull;
    __shared__ unsigned long long qcs[80];
    int ql   = blockIdx.x;                    // local row in slab
    int wv   = threadIdx.x >> 6;              // quarter 0..3
    int lane = threadIdx.x & 63;
    int gbase = wv * 1024 + lane * 16;        // lane owns 16 contiguous cols
    const float* seg = Db + (size_t)ql * N_ + gbase;

    float4 v4[4];
    v4[0] = *(const float4*)(seg);
    v4[1] = *(const float4*)(seg + 4);
    v4[2] = *(const float4*)(seg + 8);
    v4[3] = *(const float4*)(seg + 12);
    const float* vv = (const float*)v4;

    unsigned long long b0 = SENT, b1 = SENT;
    unsigned emask = 0;                       // popped elements of my 16
#pragma unroll
    for (int t = 0; t < 16; ++t) {
        unsigned long long key = ((unsigned long long)mapf(vv[t]) << 32) | (unsigned)(gbase + t);
        if (key < b1) { if (key < b0) { b1 = b0; b0 = key; } else b1 = key; }
    }
    for (int k = 0; k < KNN_; ++k) {
        if (b0 == SENT) {                     // rare refill: rescan my 16 (L2-hot)
            b1 = SENT;
            for (int t = 0; t < 16; ++t) {
                if ((emask >> t) & 1u) continue;
                unsigned long long key = ((unsigned long long)mapf(seg[t]) << 32) | (unsigned)(gbase + t);
                if (key < b1) { if (key < b0) { b1 = b0; b0 = key; } else b1 = key; }
            }
        }
        unsigned long long m = b0;
#pragma unroll
        for (int s = 32; s > 0; s >>= 1) {
            unsigned long long o = (unsigned long long)__shfl_xor((long long)m, s, 64);
            if (o < m) m = o;
        }
        if (m == b0) {                        // unique keys -> exactly one owner
            emask |= 1u << ((unsigned)m & 15u);
            b0 = b1; b1 = SENT;
        }
        if (lane == 0) qcs[wv * KNN_ + k] = m;
    }
    __syncthreads();
    if (wv == 0) {                            // merge 80 candidates, refill-free
        unsigned long long c0 = qcs[lane];
        unsigned long long c1 = (lane < 16) ? qcs[64 + lane] : SENT;
        if (c1 < c0) { unsigned long long t = c0; c0 = c1; c1 = t; }
        int qg = qbase + ql;
        for (int k = 0; k < KNN_; ++k) {
            unsigned long long m = c0;
#pragma unroll
            for (int s = 32; s > 0; s >>= 1) {
                unsigned long long o = (unsigned long long)__shfl_xor((long long)m, s, 64);
                if (o < m) m = o;
            }
            if (m == c0) { c0 = c1; c1 = SENT; }
            if (lane == 0) idxout[qg * KNN_ + k] = (int)(unsigned)m;
        }
    }
}

// ---------- build projection P[K=C][2O]: [wA^T | (wB-wA)^T], bias2[2O]=[0|bias] ----------
__global__ void k_prepP(const float* __restrict__ w, const float* __restrict__ bias,
                        int C, int O, float* __restrict__ P, float* __restrict__ bias2) {
    int i = blockIdx.x * blockDim.x + threadIdx.x;
    int O2 = 2 * O;
    if (i < O2) bias2[i] = (i < O) ? 0.f : bias[i - O];
    int total = C * O2;
    if (i >= total) return;
    int k = i / O2, col = i % O2;
    float v;
    if (col < O) {
        v = w[(size_t)col * 2 * C + k];                               // wA^T
    } else {
        int o = col - O;
        v = w[(size_t)o * 2 * C + C + k] - w[(size_t)o * 2 * C + k]; // (wB - wA)^T
    }
    P[i] = v;
}

// ---------- transpose w[O][K] -> wT[K][O] ----------
__global__ void k_transp(const float* __restrict__ w, int O, int K, float* __restrict__ wT) {
    int i = blockIdx.x * blockDim.x + threadIdx.x;
    if (i >= O * K) return;
    int k = i / O, o = i % O;
    wT[i] = w[(size_t)o * K + k];
}

// ---------- tiled f32 GEMM (large M): contiguous 4x4 blocks, float4 LDS reads ----------
__global__ __launch_bounds__(256) void k_gemm(const float* __restrict__ A, int lda,
                                              const float* __restrict__ Bm,
                                              float* __restrict__ Cm, int ldc,
                                              int M, int N, int K,
                                              const float* __restrict__ bias, int leaky) {
    __shared__ float As[16][68];   // 68*4=272B rows keep float4 alignment
    __shared__ float Bs[16][68];
    int tid = threadIdx.x;
    int row0 = blockIdx.y * 64, col0 = blockIdx.x * 64;
    int tr = tid >> 4, tc = tid & 15;
    float acc[4][4] = {{0.f}};
    for (int kt = 0; kt < K; kt += 16) {
#pragma unroll
        for (int i = 0; i < 4; ++i) {           // A tile: 64 rows x 16 k
            int e = tid + 256 * i;
            int r = e >> 4, kk = e & 15;
            int gr = row0 + r, gk = kt + kk;
            float v = 0.f;
            if (gr < M && gk < K) v = A[(size_t)gr * lda + gk];
            As[kk][r] = v;
        }
#pragma unroll
        for (int i = 0; i < 4; ++i) {           // B tile: 16 k x 64 cols
            int e = tid + 256 * i;
            int kk = e >> 6, c = e & 63;
            int gk = kt + kk, gc = col0 + c;
            float v = 0.f;
            if (gk < K && gc < N) v = Bm[(size_t)gk * N + gc];
            Bs[kk][c] = v;
        }
        __syncthreads();
#pragma unroll
        for (int kk = 0; kk < 16; ++kk) {
            float a[4], bv[4];
            *(float4*)&a[0]  = *(const float4*)&As[kk][tr * 4];   // ds_read_b128
            *(float4*)&bv[0] = *(const float4*)&Bs[kk][tc * 4];
#pragma unroll
            for (int i = 0; i < 4; ++i)
#pragma unroll
                for (int j = 0; j < 4; ++j) acc[i][j] += a[i] * bv[j];
        }
        __syncthreads();
    }
#pragma unroll
    for (int i = 0; i < 4; ++i) {
        int r = row0 + tr * 4 + i;
        if (r >= M) continue;
#pragma unroll
        for (int j = 0; j < 4; ++j) {
            int c = col0 + tc * 4 + j;
            if (c >= N) continue;
            float v = acc[i][j];
            if (bias) v += bias[c];
            if (leaky) v = v >= 0.f ? v : SLOPE * v;
            Cm[(size_t)r * ldc + c] = v;
        }
    }
}

// ---------- small-M GEMM: grid = (M rows) x (col chunks of 256) ----------
__global__ __launch_bounds__(256) void k_sgemm(const float* __restrict__ A, int lda,
                                               const float* __restrict__ Bm,
                                               float* __restrict__ Cm, int ldc,
                                               int N, int K,
                                               const float* __restrict__ bias, int leaky) {
    extern __shared__ float Arow[];          // K floats
    int r   = blockIdx.x;
    int c0  = blockIdx.y * 256;
    int tid = threadIdx.x;
    for (int k = tid; k < K; k += 256) Arow[k] = A[(size_t)r * lda + k];
    __syncthreads();
    int c = c0 + tid;
    if (c >= N) return;
    float acc = bias ? bias[c] : 0.f;
    for (int k = 0; k < K; ++k) acc += Arow[k] * Bm[(size_t)k * N + c];
    if (leaky) acc = acc >= 0.f ? acc : SLOPE * acc;
    Cm[(size_t)r * ldc + c] = acc;
}

// ---------- gather-max epilogue (+ optional fused row-norm for next layer's dist) ----------
// Block covers ALL O channels of row br, so it can block-reduce sum(out^2) -> xxout[br].
__global__ void k_gathermax(const float* __restrict__ Y, int O, int R,
                            const int* __restrict__ idx, int kc,
                            float* __restrict__ out, int ldo, int ooff,
                            float* __restrict__ xxout) {
    extern __shared__ int sidx[];
    __shared__ float red[256];
    int br = blockIdx.x;
    int b  = br / R;
    int o  = threadIdx.x;
    if (o < kc) sidx[o] = idx[(size_t)br * kc + o];
    __syncthreads();
    int O2 = 2 * O;
    float z = Y[(size_t)br * O2 + O + o];
    float best = -FLT_MAX;
    for (int k = 0; k < kc; ++k) {
        int m = sidx[k];
        best = fmaxf(best, Y[(size_t)(b * R + m) * O2 + o]);
    }
    float r = z + best;
    r = r >= 0.f ? r : SLOPE * r;
    out[(size_t)br * ldo + ooff + o] = r;
    if (xxout) {
        red[o] = r * r;
        __syncthreads();
        for (int s = blockDim.x >> 1; s > 0; s >>= 1) {
            if (o < s) red[o] += red[o + s];
            __syncthreads();
        }
        if (o == 0) xxout[br] = red[0];
    }
}

// ---------- channel -> (ptr, stride) map for the concatenated 451-dim feature ----------
__device__ __forceinline__ void chan_map(int b, int c,
                                         const float* Vf, const float* l1,
                                         const float* l2, const float* l3,
                                         const float*& p, int& st) {
    if (c < 3)        { st = 3;   p = Vf + (size_t)b * N_ * 3   + c; }
    else if (c < 67)  { st = 64;  p = l1 + (size_t)b * N_ * 64  + (c - 3); }
    else if (c < 195) { st = 128; p = l2 + (size_t)b * N_ * 128 + (c - 67); }
    else              { st = 256; p = l3 + (size_t)b * N_ * 256 + (c - 195); }
}

// ---------- pooling phase 1: grid = B*NSLAB; partial sums over a SLABN-point slab ----------
__global__ __launch_bounds__(256) void k_pool2(const float* __restrict__ Vf,
                                               const float* __restrict__ l1,
                                               const float* __restrict__ l2,
                                               const float* __restrict__ l3,
                                               const float* __restrict__ W,
                                               float* __restrict__ ppool,
                                               float* __restrict__ psw) {
    __shared__ float Wl[SLABN][J_];   // [n][j], row = 96B (float4-aligned)
    int blk  = blockIdx.x;
    int b    = blk / NSLAB, slab = blk % NSLAB;
    int n0   = slab * SLABN;
    int tid  = threadIdx.x;

    for (int e = tid; e < J_ * SLABN; e += 256) {
        int j = e / SLABN, n = e % SLABN;
        Wl[n][j] = W[((size_t)b * J_ + j) * N_ + n0 + n];   // coalesced over n
    }
    __syncthreads();

    if (tid < J_) {                    // per-joint W partial sum
        float s = 0.f;
        for (int n = 0; n < SLABN; ++n) s += Wl[n][tid];
        psw[(size_t)blk * J_ + tid] = s;
    }

    int c0 = tid, c1 = tid + 256;
    const float *p0, *p1 = nullptr; int s0, s1 = 0;
    chan_map(b, c0, Vf, l1, l2, l3, p0, s0);
    bool has1 = (c1 < 451);
    if (has1) chan_map(b, c1, Vf, l1, l2, l3, p1, s1);

    float acc0[J_], acc1[J_];
#pragma unroll
    for (int j = 0; j < J_; ++j) { acc0[j] = 0.f; acc1[j] = 0.f; }

    for (int n = 0; n < SLABN; ++n) {
        float v0 = p0[(size_t)(n0 + n) * s0];
        float v1 = has1 ? p1[(size_t)(n0 + n) * s1] : 0.f;
        const float* wn = &Wl[n][0];
#pragma unroll
        for (int q = 0; q < J_ / 4; ++q) {
            float4 w4 = *(const float4*)(wn + 4 * q);   // broadcast, conflict-free
            acc0[4*q+0] += w4.x * v0;  acc1[4*q+0] += w4.x * v1;
            acc0[4*q+1] += w4.y * v0;  acc1[4*q+1] += w4.y * v1;
            acc0[4*q+2] += w4.z * v0;  acc1[4*q+2] += w4.z * v1;
            acc0[4*q+3] += w4.w * v0;  acc1[4*q+3] += w4.w * v1;
        }
    }
    float* pp = ppool + (size_t)blk * J_ * 451;
#pragma unroll
    for (int j = 0; j < J_; ++j) {
        pp[(size_t)j * 451 + c0] = acc0[j];
        if (has1) pp[(size_t)j * 451 + c1] = acc1[j];
    }
}

// ---------- pooling phase 2: grid = B*J_; reduce NSLAB partials, divide by sumW ----------
__global__ __launch_bounds__(256) void k_poolred(const float* __restrict__ ppool,
                                                 const float* __restrict__ psw,
                                                 float* __restrict__ pooled) {
    int bj = blockIdx.x;               // b*J_ + j
    int b  = bj / J_, j = bj % J_;
    int tid = threadIdx.x;

    float sw = 0.f;
    for (int sl = 0; sl < NSLAB; ++sl) sw += psw[(size_t)(b * NSLAB + sl) * J_ + j];
    float inv = 1.f / (sw + 1e-5f);

    for (int c = tid; c < 451; c += 256) {
        float s = 0.f;
        for (int sl = 0; sl < NSLAB; ++sl)
            s += ppool[((size_t)(b * NSLAB + sl) * J_ + j) * 451 + c];
        pooled[(size_t)bj * 451 + c] = s * inv;
    }
}

extern "C" void kernel_launch(void* const* d_in, const int* in_sizes, int n_in,
                              void* d_out, int out_size, void* d_ws, size_t ws_size,
                              hipStream_t stream) {
    const float* V  = (const float*)d_in[0];   // [4,4096,3]
    const float* W  = (const float*)d_in[1];   // [4,24,4096]
    const int* ringIdx = (const int*)d_in[2];  // [4,24,4]
    const float* g1w = (const float*)d_in[3];
    const float* g1b = (const float*)d_in[4];
    const float* g2w = (const float*)d_in[5];
    const float* g2b = (const float*)d_in[6];
    const float* g3w = (const float*)d_in[7];
    const float* g3b = (const float*)d_in[8];
    const float* s1w = (const float*)d_in[9];
    const float* s1b = (const float*)d_in[10];
    const float* s2w = (const float*)d_in[11];
    const float* s2b = (const float*)d_in[12];
    const float* s3w = (const float*)d_in[13];
    const float* s3b = (const float*)d_in[14];
    const float* m1w = (const float*)d_in[15];
    const float* m1b = (const float*)d_in[16];
    const float* m2w = (const float*)d_in[17];
    const float* m2b = (const float*)d_in[18];
    const float* m3w = (const float*)d_in[19];
    const float* m3b = (const float*)d_in[20];
    (void)n_in; (void)in_sizes; (void)out_size;

    // ---- choose distance-slab size from available workspace ----
    auto layout_bytes = [](int rowt) -> size_t {
        size_t f = 0;
        f += (size_t)B_ * N_ * 64 + (size_t)B_ * N_ * 128 + (size_t)B_ * N_ * 256;
        f += (size_t)B_ * N_;                 // xx
        f += (size_t)rowt * N_;               // D / Y / ppool region
        f += (size_t)B_ * N_ * KNN_;          // knnIdx (ints)
        f += (size_t)B_ * J_ * 451 + (size_t)B_ * J_ * 448;
        f += (size_t)B_ * J_ * 512 + (size_t)B_ * J_ * 256;
        f += (size_t)451 * 512 + 512;
        return f * 4;
    };
    const int rowt = (ws_size >= layout_bytes(4096)) ? 4096 : 2048;

    // ---- workspace layout (floats) ----
    float* ws = (float*)d_ws;
    size_t off = 0;
    float* l1 = ws + off; off += (size_t)B_ * N_ * 64;    // 4MB
    float* l2 = ws + off; off += (size_t)B_ * N_ * 128;   // 8MB
    float* l3 = ws + off; off += (size_t)B_ * N_ * 256;   // 16MB
    float* xx = ws + off; off += (size_t)B_ * N_;
    // D slab aliases Y (max 32MB) and ppool/psw (11MB): D dead before k_gemm
    // writes Y; Y dead before next k_dist writes D; ppool lives between the
    // layer-3 gathermax and skeleton conv 1.
    float* D  = ws + off; off += (size_t)rowt * N_;
    float* Y  = D;
    float* ppool = D;
    float* psw   = D + (size_t)B_ * NSLAB * J_ * 451;
    int* knnIdx = (int*)(ws + off); off += (size_t)B_ * N_ * KNN_;
    float* pooled = ws + off; off += (size_t)B_ * J_ * 451;
    float* joints = ws + off; off += (size_t)B_ * J_ * 448;
    float* h1 = ws + off; off += (size_t)B_ * J_ * 512;
    float* h2 = ws + off; off += (size_t)B_ * J_ * 256;
    float* P  = ws + off; off += (size_t)451 * 512;       // reused for all P / wT
    float* bias2 = ws + off; off += 512;

    const int M = B_ * N_;   // 16384
    const int MJ = B_ * J_;  // 96

    // ======== geoNet layer 1: C=3 -> O=64 ========
    k_norm<<<(M + 255) / 256, 256, 0, stream>>>(V, xx, 3);
    for (int b = 0; b < B_; ++b)
        for (int rb = 0; rb < N_; rb += rowt) {
            k_dist<<<dim3(32, rowt / 128), 256, 0, stream>>>(V + (size_t)b * N_ * 3, 3, xx + b * N_, D, rb);
            k_sel<<<rowt, 256, 0, stream>>>(D, knnIdx + (size_t)b * N_ * KNN_, rb);
        }
    k_prepP<<<(3 * 128 + 255) / 256, 256, 0, stream>>>(g1w, g1b, 3, 64, P, bias2);
    k_gemm<<<dim3(2, M / 64), 256, 0, stream>>>(V, 3, P, Y, 128, M, 128, 3, bias2, 0);
    k_gathermax<<<M, 64, KNN_ * sizeof(int), stream>>>(Y, 64, N_, knnIdx, KNN_, l1, 64, 0, xx);

    // ======== layer 2: C=64 -> O=128 ========
    for (int b = 0; b < B_; ++b)
        for (int rb = 0; rb < N_; rb += rowt) {
            k_dist<<<dim3(32, rowt / 128), 256, 0, stream>>>(l1 + (size_t)b * N_ * 64, 64, xx + b * N_, D, rb);
            k_sel<<<rowt, 256, 0, stream>>>(D, knnIdx + (size_t)b * N_ * KNN_, rb);
        }
    k_prepP<<<(64 * 256 + 255) / 256, 256, 0, stream>>>(g2w, g2b, 64, 128, P, bias2);
    k_gemm<<<dim3(4, M / 64), 256, 0, stream>>>(l1, 64, P, Y, 256, M, 256, 64, bias2, 0);
    k_gathermax<<<M, 128, KNN_ * sizeof(int), stream>>>(Y, 128, N_, knnIdx, KNN_, l2, 128, 0, xx);

    // ======== layer 3: C=128 -> O=256 ========
    for (int b = 0; b < B_; ++b)
        for (int rb = 0; rb < N_; rb += rowt) {
            k_dist<<<dim3(32, rowt / 128), 256, 0, stream>>>(l2 + (size_t)b * N_ * 128, 128, xx + b * N_, D, rb);
            k_sel<<<rowt, 256, 0, stream>>>(D, knnIdx + (size_t)b * N_ * KNN_, rb);
        }
    k_prepP<<<(128 * 512 + 255) / 256, 256, 0, stream>>>(g3w, g3b, 128, 256, P, bias2);
    k_gemm<<<dim3(8, M / 64), 256, 0, stream>>>(l2, 128, P, Y, 512, M, 512, 128, bias2, 0);
    k_gathermax<<<M, 256, KNN_ * sizeof(int), stream>>>(Y, 256, N_, knnIdx, KNN_, l3, 256, 0, nullptr);

    // ======== pooling onto joints (two-phase) ========
    k_pool2<<<B_ * NSLAB, 256, 0, stream>>>(V, l1, l2, l3, W, ppool, psw);
    k_poolred<<<MJ, 256, 0, stream>>>(ppool, psw, pooled);

    // ======== skeleton conv 1: C=451 -> O=256 (small-M GEMM path) ========
    k_prepP<<<(451 * 512 + 255) / 256, 256, 0, stream>>>(s1w, s1b, 451, 256, P, bias2);
    k_sgemm<<<dim3(MJ, 2), 256, 451 * sizeof(float), stream>>>(pooled, 451, P, Y, 512, 512, 451, bias2, 0);
    k_gathermax<<<MJ, 256, KR_ * sizeof(int), stream>>>(Y, 256, J_, ringIdx, KR_, joints, 448, 0, nullptr);

    // ======== skeleton conv 2: C=256 -> O=128 ========
    k_prepP<<<(256 * 256 + 255) / 256, 256, 0, stream>>>(s2w, s2b, 256, 128, P, bias2);
    k_sgemm<<<dim3(MJ, 1), 256, 256 * sizeof(float), stream>>>(joints, 448, P, Y, 256, 256, 256, bias2, 0);
    k_gathermax<<<MJ, 128, KR_ * sizeof(int), stream>>>(Y, 128, J_, ringIdx, KR_, joints, 448, 256, nullptr);

    // ======== skeleton conv 3: C=128 -> O=64 ========
    k_prepP<<<(128 * 128 + 255) / 256, 256, 0, stream>>>(s3w, s3b, 128, 64, P, bias2);
    k_sgemm<<<dim3(MJ, 1), 256, 128 * sizeof(float), stream>>>(joints + 256, 448, P, Y, 128, 128, 128, bias2, 0);
    k_gathermax<<<MJ, 64, KR_ * sizeof(int), stream>>>(Y, 64, J_, ringIdx, KR_, joints, 448, 384, nullptr);

    // ======== joint MLP ========
    k_transp<<<(512 * 448 + 255) / 256, 256, 0, stream>>>(m1w, 512, 448, P);
    k_sgemm<<<dim3(MJ, 2), 256, 448 * sizeof(float), stream>>>(joints, 448, P, h1, 512, 512, 448, m1b, 1);
    k_transp<<<(256 * 512 + 255) / 256, 256, 0, stream>>>(m2w, 256, 512, P);
    k_sgemm<<<dim3(MJ, 1), 256, 512 * sizeof(float), stream>>>(h1, 512, P, h2, 256, 256, 512, m2b, 1);
    k_transp<<<(3 * 256 + 255) / 256, 256, 0, stream>>>(m3w, 3, 256, P);
    k_sgemm<<<dim3(MJ, 1), 256, 256 * sizeof(float), stream>>>(h2, 256, P, (float*)d_out, 3, 3, 256, m3b, 0);
}

// Round 10
// 1758.235 us; speedup vs baseline: 6.0694x; 1.0821x over previous
//
#include <hip/hip_runtime.h>
#include <hip/hip_bf16.h>
#include <float.h>

// Problem constants (from reference setup_inputs)
#define B_   4
#define N_   4096
#define J_   24
#define KR_  4
#define KNN_ 20
#define SLOPE 0.2f
#define SLABN 64             // points per pooling slab
#define NSLAB (N_ / SLABN)   // 64

// ---------- per-point squared norm (for V; later layers get it from gathermax) ----------
__global__ void k_norm(const float* __restrict__ h, float* __restrict__ xx, int C) {
    int i = blockIdx.x * blockDim.x + threadIdx.x;  // b*N + n
    if (i >= B_ * N_) return;
    const float* hp = h + (size_t)i * C;
    float s = 0.f;
    for (int c = 0; c < C; ++c) { float v = hp[c]; s += v * v; }
    xx[i] = s;
}

// ---------- distance GEMM, one row-slab of one batch ----------
// D[grow-rowbase, m] = xx[grow] + xx[m] - 2*dot(X[grow], X[m])
// Thread owns a (4+4)x(4+4) split block: quads at tr*4 / 64+tr*4, tc*4 / 64+tc*4.
// -> LDS b128 reads are 2-way/broadcast (free), stores are dense 256B runs.
// LDS row stride 132 (=4 mod 32): staging writes 2-way instead of 4-way.
__global__ __launch_bounds__(256) void k_dist(const float* __restrict__ X, int C,
                                              const float* __restrict__ xxb,
                                              float* __restrict__ D, int rowbase) {
    __shared__ float As[16][132];
    __shared__ float Bs[16][132];
    int tid = threadIdx.x;
    int row0 = rowbase + blockIdx.y * 128;   // global row
    int col0 = blockIdx.x * 128;             // global col
    int tr = tid >> 4, tc = tid & 15;
    float acc[8][8] = {{0.f}};
    for (int kt = 0; kt < C; kt += 16) {
#pragma unroll
        for (int i = 0; i < 8; ++i) {
            int e = tid + 256 * i;
            int r = e >> 4, kk = e & 15;     // r in [0,128), kk in [0,16)
            int gk = kt + kk;
            As[kk][r] = (gk < C) ? X[(size_t)(row0 + r) * C + gk] : 0.f;
            Bs[kk][r] = (gk < C) ? X[(size_t)(col0 + r) * C + gk] : 0.f;
        }
        __syncthreads();
#pragma unroll
        for (int kk = 0; kk < 16; ++kk) {
            float a[8], bv[8];
            *(float4*)&a[0]  = *(const float4*)&As[kk][tr * 4];
            *(float4*)&a[4]  = *(const float4*)&As[kk][64 + tr * 4];
            *(float4*)&bv[0] = *(const float4*)&Bs[kk][tc * 4];
            *(float4*)&bv[4] = *(const float4*)&Bs[kk][64 + tc * 4];
#pragma unroll
            for (int i = 0; i < 8; ++i)
#pragma unroll
                for (int j = 0; j < 8; ++j) acc[i][j] += a[i] * bv[j];
        }
        __syncthreads();
    }
    float xc[8];
#pragma unroll
    for (int j = 0; j < 4; ++j) {
        xc[j]     = xxb[col0 + tc * 4 + j];
        xc[4 + j] = xxb[col0 + 64 + tc * 4 + j];
    }
#pragma unroll
    for (int i = 0; i < 8; ++i) {
        int lr = (i < 4) ? (tr * 4 + i) : (64 + tr * 4 + (i - 4));
        int grow = row0 + lr;
        float xr = xxb[grow];
        float4 o0, o1;
        o0.x = xr + xc[0] - 2.f * acc[i][0];
        o0.y = xr + xc[1] - 2.f * acc[i][1];
        o0.z = xr + xc[2] - 2.f * acc[i][2];
        o0.w = xr + xc[3] - 2.f * acc[i][3];
        o1.x = xr + xc[4] - 2.f * acc[i][4];
        o1.y = xr + xc[5] - 2.f * acc[i][5];
        o1.z = xr + xc[6] - 2.f * acc[i][6];
        o1.w = xr + xc[7] - 2.f * acc[i][7];
        float* dp = D + (size_t)(grow - rowbase) * N_ + col0;
        *(float4*)(dp + tc * 4)      = o0;
        *(float4*)(dp + 64 + tc * 4) = o1;
    }
}

// ---------- key mapping: monotone f32 -> u32 ----------
__device__ __forceinline__ unsigned mapf(float f) {
    unsigned u = __float_as_uint(f);
    return (u & 0x80000000u) ? ~u : (u | 0x80000000u);
}

// ---------- fused top-20 selection over materialized D: one block per row ----------
__global__ __launch_bounds__(256) void k_sel(const float* __restrict__ Db,
                                             int* __restrict__ idxout, int qbase) {
    const unsigned long long SENT = ~0ull;
    __shared__ unsigned long long qcs[80];
    int ql   = blockIdx.x;                    // local row in slab
    int wv   = threadIdx.x >> 6;              // quarter 0..3
    int lane = threadIdx.x & 63;
    int gbase = wv * 1024 + lane * 16;        // lane owns 16 contiguous cols
    const float* seg = Db + (size_t)ql * N_ + gbase;

    float4 v4[4];
    v4[0] = *(const float4*)(seg);
    v4[1] = *(const float4*)(seg + 4);
    v4[2] = *(const float4*)(seg + 8);
    v4[3] = *(const float4*)(seg + 12);
    const float* vv = (const float*)v4;

    unsigned long long b0 = SENT, b1 = SENT;
    unsigned emask = 0;                       // popped elements of my 16
#pragma unroll
    for (int t = 0; t < 16; ++t) {
        unsigned long long key = ((unsigned long long)mapf(vv[t]) << 32) | (unsigned)(gbase + t);
        if (key < b1) { if (key < b0) { b1 = b0; b0 = key; } else b1 = key; }
    }
    for (int k = 0; k < KNN_; ++k) {
        if (b0 == SENT) {                     // rare refill: rescan my 16 (L2-hot)
            b1 = SENT;
            for (int t = 0; t < 16; ++t) {
                if ((emask >> t) & 1u) continue;
                unsigned long long key = ((unsigned long long)mapf(seg[t]) << 32) | (unsigned)(gbase + t);
                if (key < b1) { if (key < b0) { b1 = b0; b0 = key; } else b1 = key; }
            }
        }
        unsigned long long m = b0;
#pragma unroll
        for (int s = 32; s > 0; s >>= 1) {
            unsigned long long o = (unsigned long long)__shfl_xor((long long)m, s, 64);
            if (o < m) m = o;
        }
        if (m == b0) {                        // unique keys -> exactly one owner
            emask |= 1u << ((unsigned)m & 15u);
            b0 = b1; b1 = SENT;
        }
        if (lane == 0) qcs[wv * KNN_ + k] = m;
    }
    __syncthreads();
    if (wv == 0) {                            // merge 80 candidates, refill-free
        unsigned long long c0 = qcs[lane];
        unsigned long long c1 = (lane < 16) ? qcs[64 + lane] : SENT;
        if (c1 < c0) { unsigned long long t = c0; c0 = c1; c1 = t; }
        int qg = qbase + ql;
        for (int k = 0; k < KNN_; ++k) {
            unsigned long long m = c0;
#pragma unroll
            for (int s = 32; s > 0; s >>= 1) {
                unsigned long long o = (unsigned long long)__shfl_xor((long long)m, s, 64);
                if (o < m) m = o;
            }
            if (m == c0) { c0 = c1; c1 = SENT; }
            if (lane == 0) idxout[qg * KNN_ + k] = (int)(unsigned)m;
        }
    }
}

// ---------- layer-1 fused dist+select (C=3): no D materialization ----------
// d = xx[q] + xx[m] - 2*fma-chain dot, same op order as k_dist -> bit-identical.
__global__ __launch_bounds__(256) void k_selC3(const float* __restrict__ Xb,
                                               const float* __restrict__ xxb,
                                               int* __restrict__ idxout) {
    const unsigned long long SENT = ~0ull;
    __shared__ unsigned long long qcs[80];
    int q    = blockIdx.x;
    int wv   = threadIdx.x >> 6;
    int lane = threadIdx.x & 63;
    int gbase = wv * 1024 + lane * 16;        // lane owns 16 contiguous points

    float qx = Xb[q * 3], qy = Xb[q * 3 + 1], qz = Xb[q * 3 + 2];
    float xxq = xxb[q];

    float pts[48];                            // xyz of my 16 points, in registers
    const float4* src = (const float4*)(Xb + (size_t)gbase * 3);
#pragma unroll
    for (int t = 0; t < 12; ++t) ((float4*)pts)[t] = src[t];
    float xxm[16];
#pragma unroll
    for (int t = 0; t < 16; ++t) xxm[t] = xxb[gbase + t];

    auto distf = [&](int t) -> float {
        float dot = qx * pts[3 * t];
        dot = fmaf(qy, pts[3 * t + 1], dot);
        dot = fmaf(qz, pts[3 * t + 2], dot);
        return xxq + xxm[t] - 2.f * dot;
    };

    unsigned long long b0 = SENT, b1 = SENT;
    unsigned emask = 0;
#pragma unroll
    for (int t = 0; t < 16; ++t) {
        unsigned long long key = ((unsigned long long)mapf(distf(t)) << 32) | (unsigned)(gbase + t);
        if (key < b1) { if (key < b0) { b1 = b0; b0 = key; } else b1 = key; }
    }
    for (int k = 0; k < KNN_; ++k) {
        if (b0 == SENT) {                     // rare refill: recompute from registers
            b1 = SENT;
            for (int t = 0; t < 16; ++t) {
                if ((emask >> t) & 1u) continue;
                unsigned long long key = ((unsigned long long)mapf(distf(t)) << 32) | (unsigned)(gbase + t);
                if (key < b1) { if (key < b0) { b1 = b0; b0 = key; } else b1 = key; }
            }
        }
        unsigned long long m = b0;
#pragma unroll
        for (int s = 32; s > 0; s >>= 1) {
            unsigned long long o = (unsigned long long)__shfl_xor((long long)m, s, 64);
            if (o < m) m = o;
        }
        if (m == b0) {
            emask |= 1u << ((unsigned)m & 15u);
            b0 = b1; b1 = SENT;
        }
        if (lane == 0) qcs[wv * KNN_ + k] = m;
    }
    __syncthreads();
    if (wv == 0) {
        unsigned long long c0 = qcs[lane];
        unsigned long long c1 = (lane < 16) ? qcs[64 + lane] : SENT;
        if (c1 < c0) { unsigned long long t = c0; c0 = c1; c1 = t; }
        for (int k = 0; k < KNN_; ++k) {
            unsigned long long m = c0;
#pragma unroll
            for (int s = 32; s > 0; s >>= 1) {
                unsigned long long o = (unsigned long long)__shfl_xor((long long)m, s, 64);
                if (o < m) m = o;
            }
            if (m == c0) { c0 = c1; c1 = SENT; }
            if (lane == 0) idxout[q * KNN_ + k] = (int)(unsigned)m;
        }
    }
}

// ---------- build projection P[K=C][2O]: [wA^T | (wB-wA)^T], bias2[2O]=[0|bias] ----------
__global__ void k_prepP(const float* __restrict__ w, const float* __restrict__ bias,
                        int C, int O, float* __restrict__ P, float* __restrict__ bias2) {
    int i = blockIdx.x * blockDim.x + threadIdx.x;
    int O2 = 2 * O;
    if (i < O2) bias2[i] = (i < O) ? 0.f : bias[i - O];
    int total = C * O2;
    if (i >= total) return;
    int k = i / O2, col = i % O2;
    float v;
    if (col < O) {
        v = w[(size_t)col * 2 * C + k];                               // wA^T
    } else {
        int o = col - O;
        v = w[(size_t)o * 2 * C + C + k] - w[(size_t)o * 2 * C + k]; // (wB - wA)^T
    }
    P[i] = v;
}

// ---------- transpose w[O][K] -> wT[K][O] ----------
__global__ void k_transp(const float* __restrict__ w, int O, int K, float* __restrict__ wT) {
    int i = blockIdx.x * blockDim.x + threadIdx.x;
    if (i >= O * K) return;
    int k = i / O, o = i % O;
    wT[i] = w[(size_t)o * K + k];
}

// ---------- tiled f32 GEMM (large M): contiguous 4x4 blocks, float4 LDS reads ----------
__global__ __launch_bounds__(256) void k_gemm(const float* __restrict__ A, int lda,
                                              const float* __restrict__ Bm,
                                              float* __restrict__ Cm, int ldc,
                                              int M, int N, int K,
                                              const float* __restrict__ bias, int leaky) {
    __shared__ float As[16][68];
    __shared__ float Bs[16][68];
    int tid = threadIdx.x;
    int row0 = blockIdx.y * 64, col0 = blockIdx.x * 64;
    int tr = tid >> 4, tc = tid & 15;
    float acc[4][4] = {{0.f}};
    for (int kt = 0; kt < K; kt += 16) {
#pragma unroll
        for (int i = 0; i < 4; ++i) {           // A tile: 64 rows x 16 k
            int e = tid + 256 * i;
            int r = e >> 4, kk = e & 15;
            int gr = row0 + r, gk = kt + kk;
            float v = 0.f;
            if (gr < M && gk < K) v = A[(size_t)gr * lda + gk];
            As[kk][r] = v;
        }
#pragma unroll
        for (int i = 0; i < 4; ++i) {           // B tile: 16 k x 64 cols
            int e = tid + 256 * i;
            int kk = e >> 6, c = e & 63;
            int gk = kt + kk, gc = col0 + c;
            float v = 0.f;
            if (gk < K && gc < N) v = Bm[(size_t)gk * N + gc];
            Bs[kk][c] = v;
        }
        __syncthreads();
#pragma unroll
        for (int kk = 0; kk < 16; ++kk) {
            float a[4], bv[4];
            *(float4*)&a[0]  = *(const float4*)&As[kk][tr * 4];
            *(float4*)&bv[0] = *(const float4*)&Bs[kk][tc * 4];
#pragma unroll
            for (int i = 0; i < 4; ++i)
#pragma unroll
                for (int j = 0; j < 4; ++j) acc[i][j] += a[i] * bv[j];
        }
        __syncthreads();
    }
#pragma unroll
    for (int i = 0; i < 4; ++i) {
        int r = row0 + tr * 4 + i;
        if (r >= M) continue;
#pragma unroll
        for (int j = 0; j < 4; ++j) {
            int c = col0 + tc * 4 + j;
            if (c >= N) continue;
            float v = acc[i][j];
            if (bias) v += bias[c];
            if (leaky) v = v >= 0.f ? v : SLOPE * v;
            Cm[(size_t)r * ldc + c] = v;
        }
    }
}

// ---------- small-M GEMM: grid = (M rows) x (col chunks of 256) ----------
__global__ __launch_bounds__(256) void k_sgemm(const float* __restrict__ A, int lda,
                                               const float* __restrict__ Bm,
                                               float* __restrict__ Cm, int ldc,
                                               int N, int K,
                                               const float* __restrict__ bias, int leaky) {
    extern __shared__ float Arow[];          // K floats
    int r   = blockIdx.x;
    int c0  = blockIdx.y * 256;
    int tid = threadIdx.x;
    for (int k = tid; k < K; k += 256) Arow[k] = A[(size_t)r * lda + k];
    __syncthreads();
    int c = c0 + tid;
    if (c >= N) return;
    float acc = bias ? bias[c] : 0.f;
    for (int k = 0; k < K; ++k) acc += Arow[k] * Bm[(size_t)k * N + c];
    if (leaky) acc = acc >= 0.f ? acc : SLOPE * acc;
    Cm[(size_t)r * ldc + c] = acc;
}

// ---------- gather-max epilogue (+ optional fused row-norm for next layer's dist) ----------
__global__ void k_gathermax(const float* __restrict__ Y, int O, int R,
                            const int* __restrict__ idx, int kc,
                            float* __restrict__ out, int ldo, int ooff,
                            float* __restrict__ xxout) {
    extern __shared__ int sidx[];
    __shared__ float red[256];
    int br = blockIdx.x;
    int b  = br / R;
    int o  = threadIdx.x;
    if (o < kc) sidx[o] = idx[(size_t)br * kc + o];
    __syncthreads();
    int O2 = 2 * O;
    float z = Y[(size_t)br * O2 + O + o];
    float best = -FLT_MAX;
    for (int k = 0; k < kc; ++k) {
        int m = sidx[k];
        best = fmaxf(best, Y[(size_t)(b * R + m) * O2 + o]);
    }
    float r = z + best;
    r = r >= 0.f ? r : SLOPE * r;
    out[(size_t)br * ldo + ooff + o] = r;
    if (xxout) {
        red[o] = r * r;
        __syncthreads();
        for (int s = blockDim.x >> 1; s > 0; s >>= 1) {
            if (o < s) red[o] += red[o + s];
            __syncthreads();
        }
        if (o == 0) xxout[br] = red[0];
    }
}

// ---------- channel -> (ptr, stride) map for the concatenated 451-dim feature ----------
__device__ __forceinline__ void chan_map(int b, int c,
                                         const float* Vf, const float* l1,
                                         const float* l2, const float* l3,
                                         const float*& p, int& st) {
    if (c < 3)        { st = 3;   p = Vf + (size_t)b * N_ * 3   + c; }
    else if (c < 67)  { st = 64;  p = l1 + (size_t)b * N_ * 64  + (c - 3); }
    else if (c < 195) { st = 128; p = l2 + (size_t)b * N_ * 128 + (c - 67); }
    else              { st = 256; p = l3 + (size_t)b * N_ * 256 + (c - 195); }
}

// ---------- pooling phase 1: grid = B*NSLAB; partial sums over a SLABN-point slab ----------
__global__ __launch_bounds__(256) void k_pool2(const float* __restrict__ Vf,
                                               const float* __restrict__ l1,
                                               const float* __restrict__ l2,
                                               const float* __restrict__ l3,
                                               const float* __restrict__ W,
                                               float* __restrict__ ppool,
                                               float* __restrict__ psw) {
    __shared__ float Wl[SLABN][J_];
    int blk  = blockIdx.x;
    int b    = blk / NSLAB, slab = blk % NSLAB;
    int n0   = slab * SLABN;
    int tid  = threadIdx.x;

    for (int e = tid; e < J_ * SLABN; e += 256) {
        int j = e / SLABN, n = e % SLABN;
        Wl[n][j] = W[((size_t)b * J_ + j) * N_ + n0 + n];
    }
    __syncthreads();

    if (tid < J_) {
        float s = 0.f;
        for (int n = 0; n < SLABN; ++n) s += Wl[n][tid];
        psw[(size_t)blk * J_ + tid] = s;
    }

    int c0 = tid, c1 = tid + 256;
    const float *p0, *p1 = nullptr; int s0, s1 = 0;
    chan_map(b, c0, Vf, l1, l2, l3, p0, s0);
    bool has1 = (c1 < 451);
    if (has1) chan_map(b, c1, Vf, l1, l2, l3, p1, s1);

    float acc0[J_], acc1[J_];
#pragma unroll
    for (int j = 0; j < J_; ++j) { acc0[j] = 0.f; acc1[j] = 0.f; }

    for (int n = 0; n < SLABN; ++n) {
        float v0 = p0[(size_t)(n0 + n) * s0];
        float v1 = has1 ? p1[(size_t)(n0 + n) * s1] : 0.f;
        const float* wn = &Wl[n][0];
#pragma unroll
        for (int q = 0; q < J_ / 4; ++q) {
            float4 w4 = *(const float4*)(wn + 4 * q);
            acc0[4*q+0] += w4.x * v0;  acc1[4*q+0] += w4.x * v1;
            acc0[4*q+1] += w4.y * v0;  acc1[4*q+1] += w4.y * v1;
            acc0[4*q+2] += w4.z * v0;  acc1[4*q+2] += w4.z * v1;
            acc0[4*q+3] += w4.w * v0;  acc1[4*q+3] += w4.w * v1;
        }
    }
    float* pp = ppool + (size_t)blk * J_ * 451;
#pragma unroll
    for (int j = 0; j < J_; ++j) {
        pp[(size_t)j * 451 + c0] = acc0[j];
        if (has1) pp[(size_t)j * 451 + c1] = acc1[j];
    }
}

// ---------- pooling phase 2 ----------
__global__ __launch_bounds__(256) void k_poolred(const float* __restrict__ ppool,
                                                 const float* __restrict__ psw,
                                                 float* __restrict__ pooled) {
    int bj = blockIdx.x;
    int b  = bj / J_, j = bj % J_;
    int tid = threadIdx.x;

    float sw = 0.f;
    for (int sl = 0; sl < NSLAB; ++sl) sw += psw[(size_t)(b * NSLAB + sl) * J_ + j];
    float inv = 1.f / (sw + 1e-5f);

    for (int c = tid; c < 451; c += 256) {
        float s = 0.f;
        for (int sl = 0; sl < NSLAB; ++sl)
            s += ppool[((size_t)(b * NSLAB + sl) * J_ + j) * 451 + c];
        pooled[(size_t)bj * 451 + c] = s * inv;
    }
}

extern "C" void kernel_launch(void* const* d_in, const int* in_sizes, int n_in,
                              void* d_out, int out_size, void* d_ws, size_t ws_size,
                              hipStream_t stream) {
    const float* V  = (const float*)d_in[0];
    const float* W  = (const float*)d_in[1];
    const int* ringIdx = (const int*)d_in[2];
    const float* g1w = (const float*)d_in[3];
    const float* g1b = (const float*)d_in[4];
    const float* g2w = (const float*)d_in[5];
    const float* g2b = (const float*)d_in[6];
    const float* g3w = (const float*)d_in[7];
    const float* g3b = (const float*)d_in[8];
    const float* s1w = (const float*)d_in[9];
    const float* s1b = (const float*)d_in[10];
    const float* s2w = (const float*)d_in[11];
    const float* s2b = (const float*)d_in[12];
    const float* s3w = (const float*)d_in[13];
    const float* s3b = (const float*)d_in[14];
    const float* m1w = (const float*)d_in[15];
    const float* m1b = (const float*)d_in[16];
    const float* m2w = (const float*)d_in[17];
    const float* m2b = (const float*)d_in[18];
    const float* m3w = (const float*)d_in[19];
    const float* m3b = (const float*)d_in[20];
    (void)n_in; (void)in_sizes; (void)out_size;

    // ---- choose distance-slab size from available workspace ----
    auto layout_bytes = [](int rowt) -> size_t {
        size_t f = 0;
        f += (size_t)B_ * N_ * 64 + (size_t)B_ * N_ * 128 + (size_t)B_ * N_ * 256;
        f += (size_t)B_ * N_;                 // xx
        f += (size_t)rowt * N_;               // D / Y / ppool region
        f += (size_t)B_ * N_ * KNN_;          // knnIdx (ints)
        f += (size_t)B_ * J_ * 451 + (size_t)B_ * J_ * 448;
        f += (size_t)B_ * J_ * 512 + (size_t)B_ * J_ * 256;
        f += (size_t)451 * 512 + 512;
        return f * 4;
    };
    const int rowt = (ws_size >= layout_bytes(4096)) ? 4096 : 2048;

    // ---- workspace layout (floats) ----
    float* ws = (float*)d_ws;
    size_t off = 0;
    float* l1 = ws + off; off += (size_t)B_ * N_ * 64;
    float* l2 = ws + off; off += (size_t)B_ * N_ * 128;
    float* l3 = ws + off; off += (size_t)B_ * N_ * 256;
    float* xx = ws + off; off += (size_t)B_ * N_;
    float* D  = ws + off; off += (size_t)rowt * N_;
    float* Y  = D;
    float* ppool = D;
    float* psw   = D + (size_t)B_ * NSLAB * J_ * 451;
    int* knnIdx = (int*)(ws + off); off += (size_t)B_ * N_ * KNN_;
    float* pooled = ws + off; off += (size_t)B_ * J_ * 451;
    float* joints = ws + off; off += (size_t)B_ * J_ * 448;
    float* h1 = ws + off; off += (size_t)B_ * J_ * 512;
    float* h2 = ws + off; off += (size_t)B_ * J_ * 256;
    float* P  = ws + off; off += (size_t)451 * 512;
    float* bias2 = ws + off; off += 512;

    const int M = B_ * N_;   // 16384
    const int MJ = B_ * J_;  // 96

    // ======== geoNet layer 1: C=3 -> O=64 (fused dist+select, no D) ========
    k_norm<<<(M + 255) / 256, 256, 0, stream>>>(V, xx, 3);
    for (int b = 0; b < B_; ++b)
        k_selC3<<<N_, 256, 0, stream>>>(V + (size_t)b * N_ * 3, xx + b * N_,
                                        knnIdx + (size_t)b * N_ * KNN_);
    k_prepP<<<(3 * 128 + 255) / 256, 256, 0, stream>>>(g1w, g1b, 3, 64, P, bias2);
    k_gemm<<<dim3(2, M / 64), 256, 0, stream>>>(V, 3, P, Y, 128, M, 128, 3, bias2, 0);
    k_gathermax<<<M, 64, KNN_ * sizeof(int), stream>>>(Y, 64, N_, knnIdx, KNN_, l1, 64, 0, xx);

    // ======== layer 2: C=64 -> O=128 ========
    for (int b = 0; b < B_; ++b)
        for (int rb = 0; rb < N_; rb += rowt) {
            k_dist<<<dim3(32, rowt / 128), 256, 0, stream>>>(l1 + (size_t)b * N_ * 64, 64, xx + b * N_, D, rb);
            k_sel<<<rowt, 256, 0, stream>>>(D, knnIdx + (size_t)b * N_ * KNN_, rb);
        }
    k_prepP<<<(64 * 256 + 255) / 256, 256, 0, stream>>>(g2w, g2b, 64, 128, P, bias2);
    k_gemm<<<dim3(4, M / 64), 256, 0, stream>>>(l1, 64, P, Y, 256, M, 256, 64, bias2, 0);
    k_gathermax<<<M, 128, KNN_ * sizeof(int), stream>>>(Y, 128, N_, knnIdx, KNN_, l2, 128, 0, xx);

    // ======== layer 3: C=128 -> O=256 ========
    for (int b = 0; b < B_; ++b)
        for (int rb = 0; rb < N_; rb += rowt) {
            k_dist<<<dim3(32, rowt / 128), 256, 0, stream>>>(l2 + (size_t)b * N_ * 128, 128, xx + b * N_, D, rb);
            k_sel<<<rowt, 256, 0, stream>>>(D, knnIdx + (size_t)b * N_ * KNN_, rb);
        }
    k_prepP<<<(128 * 512 + 255) / 256, 256, 0, stream>>>(g3w, g3b, 128, 256, P, bias2);
    k_gemm<<<dim3(8, M / 64), 256, 0, stream>>>(l2, 128, P, Y, 512, M, 512, 128, bias2, 0);
    k_gathermax<<<M, 256, KNN_ * sizeof(int), stream>>>(Y, 256, N_, knnIdx, KNN_, l3, 256, 0, nullptr);

    // ======== pooling onto joints (two-phase) ========
    k_pool2<<<B_ * NSLAB, 256, 0, stream>>>(V, l1, l2, l3, W, ppool, psw);
    k_poolred<<<MJ, 256, 0, stream>>>(ppool, psw, pooled);

    // ======== skeleton conv 1: C=451 -> O=256 ========
    k_prepP<<<(451 * 512 + 255) / 256, 256, 0, stream>>>(s1w, s1b, 451, 256, P, bias2);
    k_sgemm<<<dim3(MJ, 2), 256, 451 * sizeof(float), stream>>>(pooled, 451, P, Y, 512, 512, 451, bias2, 0);
    k_gathermax<<<MJ, 256, KR_ * sizeof(int), stream>>>(Y, 256, J_, ringIdx, KR_, joints, 448, 0, nullptr);

    // ======== skeleton conv 2: C=256 -> O=128 ========
    k_prepP<<<(256 * 256 + 255) / 256, 256, 0, stream>>>(s2w, s2b, 256, 128, P, bias2);
    k_sgemm<<<dim3(MJ, 1), 256, 256 * sizeof(float), stream>>>(joints, 448, P, Y, 256, 256, 256, bias2, 0);
    k_gathermax<<<MJ, 128, KR_ * sizeof(int), stream>>>(Y, 128, J_, ringIdx, KR_, joints, 448, 256, nullptr);

    // ======== skeleton conv 3: C=128 -> O=64 ========
    k_prepP<<<(128 * 128 + 255) / 256, 256, 0, stream>>>(s3w, s3b, 128, 64, P, bias2);
    k_sgemm<<<dim3(MJ, 1), 256, 128 * sizeof(float), stream>>>(joints + 256, 448, P, Y, 128, 128, 128, bias2, 0);
    k_gathermax<<<MJ, 64, KR_ * sizeof(int), stream>>>(Y, 64, J_, ringIdx, KR_, joints, 448, 384, nullptr);

    // ======== joint MLP ========
    k_transp<<<(512 * 448 + 255) / 256, 256, 0, stream>>>(m1w, 512, 448, P);
    k_sgemm<<<dim3(MJ, 2), 256, 448 * sizeof(float), stream>>>(joints, 448, P, h1, 512, 512, 448, m1b, 1);
    k_transp<<<(256 * 512 + 255) / 256, 256, 0, stream>>>(m2w, 256, 512, P);
    k_sgemm<<<dim3(MJ, 1), 256, 512 * sizeof(float), stream>>>(h1, 512, P, h2, 256, 256, 512, m2b, 1);
    k_transp<<<(3 * 256 + 255) / 256, 256, 0, stream>>>(m3w, 3, 256, P);
    k_sgemm<<<dim3(MJ, 1), 256, 256 * sizeof(float), stream>>>(h2, 256, P, (float*)d_out, 3, 3, 256, m3b, 0);
}

// Round 11
// 1527.791 us; speedup vs baseline: 6.9849x; 1.1508x over previous
//
#include <hip/hip_runtime.h>
#include <hip/hip_bf16.h>
#include <float.h>

// Problem constants (from reference setup_inputs)
#define B_   4
#define N_   4096
#define J_   24
#define KR_  4
#define KNN_ 20
#define SLOPE 0.2f
#define SLABN 64             // points per pooling slab
#define NSLAB (N_ / SLABN)   // 64

// ---------- per-point squared norm (for V; later layers get it from gathermax) ----------
__global__ void k_norm(const float* __restrict__ h, float* __restrict__ xx, int C) {
    int i = blockIdx.x * blockDim.x + threadIdx.x;  // b*N + n
    if (i >= B_ * N_) return;
    const float* hp = h + (size_t)i * C;
    float s = 0.f;
    for (int c = 0; c < C; ++c) { float v = hp[c]; s += v * v; }
    xx[i] = s;
}

// ---------- distance GEMM, one row-slab of one batch ----------
// Thread owns a (4+4)x(4+4) split block -> LDS b128 reads 2-way/broadcast (free),
// dense 256B store runs; LDS row stride 132 (=4 mod 32): staging writes 2-way.
__global__ __launch_bounds__(256) void k_dist(const float* __restrict__ X, int C,
                                              const float* __restrict__ xxb,
                                              float* __restrict__ D, int rowbase) {
    __shared__ float As[16][132];
    __shared__ float Bs[16][132];
    int tid = threadIdx.x;
    int row0 = rowbase + blockIdx.y * 128;   // global row
    int col0 = blockIdx.x * 128;             // global col
    int tr = tid >> 4, tc = tid & 15;
    float acc[8][8] = {{0.f}};
    for (int kt = 0; kt < C; kt += 16) {
#pragma unroll
        for (int i = 0; i < 8; ++i) {
            int e = tid + 256 * i;
            int r = e >> 4, kk = e & 15;
            int gk = kt + kk;
            As[kk][r] = (gk < C) ? X[(size_t)(row0 + r) * C + gk] : 0.f;
            Bs[kk][r] = (gk < C) ? X[(size_t)(col0 + r) * C + gk] : 0.f;
        }
        __syncthreads();
#pragma unroll
        for (int kk = 0; kk < 16; ++kk) {
            float a[8], bv[8];
            *(float4*)&a[0]  = *(const float4*)&As[kk][tr * 4];
            *(float4*)&a[4]  = *(const float4*)&As[kk][64 + tr * 4];
            *(float4*)&bv[0] = *(const float4*)&Bs[kk][tc * 4];
            *(float4*)&bv[4] = *(const float4*)&Bs[kk][64 + tc * 4];
#pragma unroll
            for (int i = 0; i < 8; ++i)
#pragma unroll
                for (int j = 0; j < 8; ++j) acc[i][j] += a[i] * bv[j];
        }
        __syncthreads();
    }
    float xc[8];
#pragma unroll
    for (int j = 0; j < 4; ++j) {
        xc[j]     = xxb[col0 + tc * 4 + j];
        xc[4 + j] = xxb[col0 + 64 + tc * 4 + j];
    }
#pragma unroll
    for (int i = 0; i < 8; ++i) {
        int lr = (i < 4) ? (tr * 4 + i) : (64 + tr * 4 + (i - 4));
        int grow = row0 + lr;
        float xr = xxb[grow];
        float4 o0, o1;
        o0.x = xr + xc[0] - 2.f * acc[i][0];
        o0.y = xr + xc[1] - 2.f * acc[i][1];
        o0.z = xr + xc[2] - 2.f * acc[i][2];
        o0.w = xr + xc[3] - 2.f * acc[i][3];
        o1.x = xr + xc[4] - 2.f * acc[i][4];
        o1.y = xr + xc[5] - 2.f * acc[i][5];
        o1.z = xr + xc[6] - 2.f * acc[i][6];
        o1.w = xr + xc[7] - 2.f * acc[i][7];
        float* dp = D + (size_t)(grow - rowbase) * N_ + col0;
        *(float4*)(dp + tc * 4)      = o0;
        *(float4*)(dp + 64 + tc * 4) = o1;
    }
}

// ---------- key mapping: monotone f32 -> u32 ----------
__device__ __forceinline__ unsigned mapf(float f) {
    unsigned u = __float_as_uint(f);
    return (u & 0x80000000u) ? ~u : (u | 0x80000000u);
}

// ---------- fused top-20 selection over materialized D: one block per row ----------
// Phase 1 (per wave = quarter): 32-bit value tournament + ballot owner pick.
// Exact tie semantics: lanes own disjoint ascending index ranges, so lowest
// tied lane == smallest index. Phase 2 merge keeps full u64 keys.
__global__ __launch_bounds__(256) void k_sel(const float* __restrict__ Db,
                                             int* __restrict__ idxout, int qbase) {
    const unsigned long long SENT = ~0ull;
    const unsigned INV = 0xFFFFFFFFu;
    __shared__ unsigned long long qcs[80];
    int ql   = blockIdx.x;
    int wv   = threadIdx.x >> 6;              // quarter 0..3
    int lane = threadIdx.x & 63;
    int gbase = wv * 1024 + lane * 16;        // lane owns 16 contiguous cols
    const float* seg = Db + (size_t)ql * N_ + gbase;

    float4 v4[4];
    v4[0] = *(const float4*)(seg);
    v4[1] = *(const float4*)(seg + 4);
    v4[2] = *(const float4*)(seg + 8);
    v4[3] = *(const float4*)(seg + 12);
    const float* vv = (const float*)v4;

    unsigned b0v = INV, b0i = INV, b1v = INV, b1i = INV;
    unsigned emask = 0;
#pragma unroll
    for (int t = 0; t < 16; ++t) {            // strict < keeps (value,index) order
        unsigned kv = mapf(vv[t]);
        if (kv < b1v) {
            if (kv < b0v) { b1v = b0v; b1i = b0i; b0v = kv; b0i = (unsigned)(gbase + t); }
            else          { b1v = kv; b1i = (unsigned)(gbase + t); }
        }
    }
    for (int k = 0; k < KNN_; ++k) {
        if (b0i == INV) {                     // rare refill: rescan my 16 (L2-hot)
            b1v = INV; b1i = INV;
            for (int t = 0; t < 16; ++t) {
                if ((emask >> t) & 1u) continue;
                unsigned kv = mapf(seg[t]);
                if (kv < b1v) {
                    if (kv < b0v) { b1v = b0v; b1i = b0i; b0v = kv; b0i = (unsigned)(gbase + t); }
                    else          { b1v = kv; b1i = (unsigned)(gbase + t); }
                }
            }
        }
        unsigned m = b0v;
#pragma unroll
        for (int s = 32; s > 0; s >>= 1) {
            unsigned o = (unsigned)__shfl_xor((int)m, s, 64);
            m = (o < m) ? o : m;
        }
        unsigned long long ball = __ballot(b0v == m);
        int owner = __ffsll((long long)ball) - 1;
        unsigned idx = (unsigned)__shfl((int)b0i, owner, 64);
        if (lane == owner) {
            emask |= 1u << (b0i & 15u);
            b0v = b1v; b0i = b1i; b1v = INV; b1i = INV;
        }
        if (lane == 0) qcs[wv * KNN_ + k] = ((unsigned long long)m << 32) | idx;
    }
    __syncthreads();
    if (wv == 0) {                            // merge 80 candidates, refill-free (u64)
        unsigned long long c0 = qcs[lane];
        unsigned long long c1 = (lane < 16) ? qcs[64 + lane] : SENT;
        if (c1 < c0) { unsigned long long t = c0; c0 = c1; c1 = t; }
        int qg = qbase + ql;
        for (int k = 0; k < KNN_; ++k) {
            unsigned long long m = c0;
#pragma unroll
            for (int s = 32; s > 0; s >>= 1) {
                unsigned long long o = (unsigned long long)__shfl_xor((long long)m, s, 64);
                if (o < m) m = o;
            }
            if (m == c0) { c0 = c1; c1 = SENT; }
            if (lane == 0) idxout[qg * KNN_ + k] = (int)(unsigned)m;
        }
    }
}

// ---------- layer-1 fused dist+select (C=3): no D materialization ----------
__global__ __launch_bounds__(256) void k_selC3(const float* __restrict__ Xb,
                                               const float* __restrict__ xxb,
                                               int* __restrict__ idxout) {
    const unsigned long long SENT = ~0ull;
    const unsigned INV = 0xFFFFFFFFu;
    __shared__ unsigned long long qcs[80];
    int q    = blockIdx.x;
    int wv   = threadIdx.x >> 6;
    int lane = threadIdx.x & 63;
    int gbase = wv * 1024 + lane * 16;        // lane owns 16 contiguous points

    float qx = Xb[q * 3], qy = Xb[q * 3 + 1], qz = Xb[q * 3 + 2];
    float xxq = xxb[q];

    float pts[48];
    const float4* src = (const float4*)(Xb + (size_t)gbase * 3);
#pragma unroll
    for (int t = 0; t < 12; ++t) ((float4*)pts)[t] = src[t];
    float xxm[16];
#pragma unroll
    for (int t = 0; t < 16; ++t) xxm[t] = xxb[gbase + t];

    auto distf = [&](int t) -> float {
        float dot = qx * pts[3 * t];
        dot = fmaf(qy, pts[3 * t + 1], dot);
        dot = fmaf(qz, pts[3 * t + 2], dot);
        return xxq + xxm[t] - 2.f * dot;
    };

    unsigned b0v = INV, b0i = INV, b1v = INV, b1i = INV;
    unsigned emask = 0;
#pragma unroll
    for (int t = 0; t < 16; ++t) {
        unsigned kv = mapf(distf(t));
        if (kv < b1v) {
            if (kv < b0v) { b1v = b0v; b1i = b0i; b0v = kv; b0i = (unsigned)(gbase + t); }
            else          { b1v = kv; b1i = (unsigned)(gbase + t); }
        }
    }
    for (int k = 0; k < KNN_; ++k) {
        if (b0i == INV) {                     // refill: recompute from registers
            b1v = INV; b1i = INV;
            for (int t = 0; t < 16; ++t) {
                if ((emask >> t) & 1u) continue;
                unsigned kv = mapf(distf(t));
                if (kv < b1v) {
                    if (kv < b0v) { b1v = b0v; b1i = b0i; b0v = kv; b0i = (unsigned)(gbase + t); }
                    else          { b1v = kv; b1i = (unsigned)(gbase + t); }
                }
            }
        }
        unsigned m = b0v;
#pragma unroll
        for (int s = 32; s > 0; s >>= 1) {
            unsigned o = (unsigned)__shfl_xor((int)m, s, 64);
            m = (o < m) ? o : m;
        }
        unsigned long long ball = __ballot(b0v == m);
        int owner = __ffsll((long long)ball) - 1;
        unsigned idx = (unsigned)__shfl((int)b0i, owner, 64);
        if (lane == owner) {
            emask |= 1u << (b0i & 15u);
            b0v = b1v; b0i = b1i; b1v = INV; b1i = INV;
        }
        if (lane == 0) qcs[wv * KNN_ + k] = ((unsigned long long)m << 32) | idx;
    }
    __syncthreads();
    if (wv == 0) {
        unsigned long long c0 = qcs[lane];
        unsigned long long c1 = (lane < 16) ? qcs[64 + lane] : SENT;
        if (c1 < c0) { unsigned long long t = c0; c0 = c1; c1 = t; }
        for (int k = 0; k < KNN_; ++k) {
            unsigned long long m = c0;
#pragma unroll
            for (int s = 32; s > 0; s >>= 1) {
                unsigned long long o = (unsigned long long)__shfl_xor((long long)m, s, 64);
                if (o < m) m = o;
            }
            if (m == c0) { c0 = c1; c1 = SENT; }
            if (lane == 0) idxout[q * KNN_ + k] = (int)(unsigned)m;
        }
    }
}

// ---------- fused weight prep: all 6 projections + 3 transposes in one launch ----------
__device__ __forceinline__ void prepP_elem(const float* __restrict__ w,
                                           const float* __restrict__ bias,
                                           int C, int O, float* __restrict__ P,
                                           float* __restrict__ b2, int i) {
    int O2 = 2 * O;
    if (i < O2) b2[i] = (i < O) ? 0.f : bias[i - O];
    if (i >= C * O2) return;
    int k = i / O2, col = i % O2;
    float v;
    if (col < O) v = w[(size_t)col * 2 * C + k];
    else { int o = col - O; v = w[(size_t)o * 2 * C + C + k] - w[(size_t)o * 2 * C + k]; }
    P[i] = v;
}
__device__ __forceinline__ void transp_elem(const float* __restrict__ w, int O, int K,
                                            float* __restrict__ wT, int i) {
    if (i >= O * K) return;
    int k = i / O, o = i % O;
    wT[i] = w[(size_t)o * K + k];
}

__global__ void k_prepall(const float* g1w, const float* g1b,
                          const float* g2w, const float* g2b,
                          const float* g3w, const float* g3b,
                          const float* s1w, const float* s1b,
                          const float* s2w, const float* s2b,
                          const float* s3w, const float* s3b,
                          const float* m1w, const float* m2w, const float* m3w,
                          float* P1, float* P2, float* P3, float* P4, float* P5,
                          float* P6, float* P7, float* P8, float* P9,
                          float* bb1, float* bb2, float* bb3,
                          float* bb4, float* bb5, float* bb6) {
    int i = blockIdx.x * 256 + threadIdx.x;
    switch (blockIdx.y) {
        case 0: prepP_elem(g1w, g1b, 3,   64,  P1, bb1, i); break;
        case 1: prepP_elem(g2w, g2b, 64,  128, P2, bb2, i); break;
        case 2: prepP_elem(g3w, g3b, 128, 256, P3, bb3, i); break;
        case 3: prepP_elem(s1w, s1b, 451, 256, P4, bb4, i); break;
        case 4: prepP_elem(s2w, s2b, 256, 128, P5, bb5, i); break;
        case 5: prepP_elem(s3w, s3b, 128, 64,  P6, bb6, i); break;
        case 6: transp_elem(m1w, 512, 448, P7, i); break;
        case 7: transp_elem(m2w, 256, 512, P8, i); break;
        case 8: transp_elem(m3w, 3,   256, P9, i); break;
    }
}

// ---------- tiled f32 GEMM (large M) ----------
__global__ __launch_bounds__(256) void k_gemm(const float* __restrict__ A, int lda,
                                              const float* __restrict__ Bm,
                                              float* __restrict__ Cm, int ldc,
                                              int M, int N, int K,
                                              const float* __restrict__ bias, int leaky) {
    __shared__ float As[16][68];
    __shared__ float Bs[16][68];
    int tid = threadIdx.x;
    int row0 = blockIdx.y * 64, col0 = blockIdx.x * 64;
    int tr = tid >> 4, tc = tid & 15;
    float acc[4][4] = {{0.f}};
    for (int kt = 0; kt < K; kt += 16) {
#pragma unroll
        for (int i = 0; i < 4; ++i) {
            int e = tid + 256 * i;
            int r = e >> 4, kk = e & 15;
            int gr = row0 + r, gk = kt + kk;
            float v = 0.f;
            if (gr < M && gk < K) v = A[(size_t)gr * lda + gk];
            As[kk][r] = v;
        }
#pragma unroll
        for (int i = 0; i < 4; ++i) {
            int e = tid + 256 * i;
            int kk = e >> 6, c = e & 63;
            int gk = kt + kk, gc = col0 + c;
            float v = 0.f;
            if (gk < K && gc < N) v = Bm[(size_t)gk * N + gc];
            Bs[kk][c] = v;
        }
        __syncthreads();
#pragma unroll
        for (int kk = 0; kk < 16; ++kk) {
            float a[4], bv[4];
            *(float4*)&a[0]  = *(const float4*)&As[kk][tr * 4];
            *(float4*)&bv[0] = *(const float4*)&Bs[kk][tc * 4];
#pragma unroll
            for (int i = 0; i < 4; ++i)
#pragma unroll
                for (int j = 0; j < 4; ++j) acc[i][j] += a[i] * bv[j];
        }
        __syncthreads();
    }
#pragma unroll
    for (int i = 0; i < 4; ++i) {
        int r = row0 + tr * 4 + i;
        if (r >= M) continue;
#pragma unroll
        for (int j = 0; j < 4; ++j) {
            int c = col0 + tc * 4 + j;
            if (c >= N) continue;
            float v = acc[i][j];
            if (bias) v += bias[c];
            if (leaky) v = v >= 0.f ? v : SLOPE * v;
            Cm[(size_t)r * ldc + c] = v;
        }
    }
}

// ---------- small-M GEMM ----------
__global__ __launch_bounds__(256) void k_sgemm(const float* __restrict__ A, int lda,
                                               const float* __restrict__ Bm,
                                               float* __restrict__ Cm, int ldc,
                                               int N, int K,
                                               const float* __restrict__ bias, int leaky) {
    extern __shared__ float Arow[];
    int r   = blockIdx.x;
    int c0  = blockIdx.y * 256;
    int tid = threadIdx.x;
    for (int k = tid; k < K; k += 256) Arow[k] = A[(size_t)r * lda + k];
    __syncthreads();
    int c = c0 + tid;
    if (c >= N) return;
    float acc = bias ? bias[c] : 0.f;
    for (int k = 0; k < K; ++k) acc += Arow[k] * Bm[(size_t)k * N + c];
    if (leaky) acc = acc >= 0.f ? acc : SLOPE * acc;
    Cm[(size_t)r * ldc + c] = acc;
}

// ---------- gather-max epilogue (+ optional fused row-norm) ----------
__global__ void k_gathermax(const float* __restrict__ Y, int O, int R,
                            const int* __restrict__ idx, int kc,
                            float* __restrict__ out, int ldo, int ooff,
                            float* __restrict__ xxout) {
    extern __shared__ int sidx[];
    __shared__ float red[256];
    int br = blockIdx.x;
    int b  = br / R;
    int o  = threadIdx.x;
    if (o < kc) sidx[o] = idx[(size_t)br * kc + o];
    __syncthreads();
    int O2 = 2 * O;
    float z = Y[(size_t)br * O2 + O + o];
    float best = -FLT_MAX;
    for (int k = 0; k < kc; ++k) {
        int m = sidx[k];
        best = fmaxf(best, Y[(size_t)(b * R + m) * O2 + o]);
    }
    float r = z + best;
    r = r >= 0.f ? r : SLOPE * r;
    out[(size_t)br * ldo + ooff + o] = r;
    if (xxout) {
        red[o] = r * r;
        __syncthreads();
        for (int s = blockDim.x >> 1; s > 0; s >>= 1) {
            if (o < s) red[o] += red[o + s];
            __syncthreads();
        }
        if (o == 0) xxout[br] = red[0];
    }
}

// ---------- channel map for the concatenated 451-dim feature ----------
__device__ __forceinline__ void chan_map(int b, int c,
                                         const float* Vf, const float* l1,
                                         const float* l2, const float* l3,
                                         const float*& p, int& st) {
    if (c < 3)        { st = 3;   p = Vf + (size_t)b * N_ * 3   + c; }
    else if (c < 67)  { st = 64;  p = l1 + (size_t)b * N_ * 64  + (c - 3); }
    else if (c < 195) { st = 128; p = l2 + (size_t)b * N_ * 128 + (c - 67); }
    else              { st = 256; p = l3 + (size_t)b * N_ * 256 + (c - 195); }
}

// ---------- pooling phase 1 ----------
__global__ __launch_bounds__(256) void k_pool2(const float* __restrict__ Vf,
                                               const float* __restrict__ l1,
                                               const float* __restrict__ l2,
                                               const float* __restrict__ l3,
                                               const float* __restrict__ W,
                                               float* __restrict__ ppool,
                                               float* __restrict__ psw) {
    __shared__ float Wl[SLABN][J_];
    int blk  = blockIdx.x;
    int b    = blk / NSLAB, slab = blk % NSLAB;
    int n0   = slab * SLABN;
    int tid  = threadIdx.x;

    for (int e = tid; e < J_ * SLABN; e += 256) {
        int j = e / SLABN, n = e % SLABN;
        Wl[n][j] = W[((size_t)b * J_ + j) * N_ + n0 + n];
    }
    __syncthreads();

    if (tid < J_) {
        float s = 0.f;
        for (int n = 0; n < SLABN; ++n) s += Wl[n][tid];
        psw[(size_t)blk * J_ + tid] = s;
    }

    int c0 = tid, c1 = tid + 256;
    const float *p0, *p1 = nullptr; int s0, s1 = 0;
    chan_map(b, c0, Vf, l1, l2, l3, p0, s0);
    bool has1 = (c1 < 451);
    if (has1) chan_map(b, c1, Vf, l1, l2, l3, p1, s1);

    float acc0[J_], acc1[J_];
#pragma unroll
    for (int j = 0; j < J_; ++j) { acc0[j] = 0.f; acc1[j] = 0.f; }

    for (int n = 0; n < SLABN; ++n) {
        float v0 = p0[(size_t)(n0 + n) * s0];
        float v1 = has1 ? p1[(size_t)(n0 + n) * s1] : 0.f;
        const float* wn = &Wl[n][0];
#pragma unroll
        for (int q = 0; q < J_ / 4; ++q) {
            float4 w4 = *(const float4*)(wn + 4 * q);
            acc0[4*q+0] += w4.x * v0;  acc1[4*q+0] += w4.x * v1;
            acc0[4*q+1] += w4.y * v0;  acc1[4*q+1] += w4.y * v1;
            acc0[4*q+2] += w4.z * v0;  acc1[4*q+2] += w4.z * v1;
            acc0[4*q+3] += w4.w * v0;  acc1[4*q+3] += w4.w * v1;
        }
    }
    float* pp = ppool + (size_t)blk * J_ * 451;
#pragma unroll
    for (int j = 0; j < J_; ++j) {
        pp[(size_t)j * 451 + c0] = acc0[j];
        if (has1) pp[(size_t)j * 451 + c1] = acc1[j];
    }
}

// ---------- pooling phase 2 ----------
__global__ __launch_bounds__(256) void k_poolred(const float* __restrict__ ppool,
                                                 const float* __restrict__ psw,
                                                 float* __restrict__ pooled) {
    int bj = blockIdx.x;
    int b  = bj / J_, j = bj % J_;
    int tid = threadIdx.x;

    float sw = 0.f;
    for (int sl = 0; sl < NSLAB; ++sl) sw += psw[(size_t)(b * NSLAB + sl) * J_ + j];
    float inv = 1.f / (sw + 1e-5f);

    for (int c = tid; c < 451; c += 256) {
        float s = 0.f;
        for (int sl = 0; sl < NSLAB; ++sl)
            s += ppool[((size_t)(b * NSLAB + sl) * J_ + j) * 451 + c];
        pooled[(size_t)bj * 451 + c] = s * inv;
    }
}

extern "C" void kernel_launch(void* const* d_in, const int* in_sizes, int n_in,
                              void* d_out, int out_size, void* d_ws, size_t ws_size,
                              hipStream_t stream) {
    const float* V  = (const float*)d_in[0];
    const float* W  = (const float*)d_in[1];
    const int* ringIdx = (const int*)d_in[2];
    const float* g1w = (const float*)d_in[3];
    const float* g1b = (const float*)d_in[4];
    const float* g2w = (const float*)d_in[5];
    const float* g2b = (const float*)d_in[6];
    const float* g3w = (const float*)d_in[7];
    const float* g3b = (const float*)d_in[8];
    const float* s1w = (const float*)d_in[9];
    const float* s1b = (const float*)d_in[10];
    const float* s2w = (const float*)d_in[11];
    const float* s2b = (const float*)d_in[12];
    const float* s3w = (const float*)d_in[13];
    const float* s3b = (const float*)d_in[14];
    const float* m1w = (const float*)d_in[15];
    const float* m1b = (const float*)d_in[16];
    const float* m2w = (const float*)d_in[17];
    const float* m2b = (const float*)d_in[18];
    const float* m3w = (const float*)d_in[19];
    const float* m3b = (const float*)d_in[20];
    (void)n_in; (void)in_sizes; (void)out_size;

    // ---- P-buffer sizes (fused weight prep) ----
    const int szP1 = 3 * 128,    szP2 = 64 * 256,  szP3 = 128 * 512;
    const int szP4 = 451 * 512,  szP5 = 256 * 256, szP6 = 128 * 128;
    const int szP7 = 448 * 512,  szP8 = 512 * 256, szP9 = 256 * 3;

    // ---- choose distance-slab size from available workspace ----
    auto layout_bytes = [&](int rowt) -> size_t {
        size_t f = 0;
        f += (size_t)B_ * N_ * 64 + (size_t)B_ * N_ * 128 + (size_t)B_ * N_ * 256;
        f += (size_t)B_ * N_;                 // xx
        f += (size_t)rowt * N_;               // D / Y / ppool region
        f += (size_t)B_ * N_ * KNN_;          // knnIdx (ints)
        f += (size_t)B_ * J_ * 451 + (size_t)B_ * J_ * 448;
        f += (size_t)B_ * J_ * 512 + (size_t)B_ * J_ * 256;
        f += (size_t)(szP1 + szP2 + szP3 + szP4 + szP5 + szP6 + szP7 + szP8 + szP9);
        f += 128 + 256 + 512 + 512 + 256 + 128;   // bias2 buffers
        return f * 4;
    };
    const int rowt = (ws_size >= layout_bytes(4096)) ? 4096 : 2048;

    // ---- workspace layout (floats) ----
    float* ws = (float*)d_ws;
    size_t off = 0;
    float* l1 = ws + off; off += (size_t)B_ * N_ * 64;
    float* l2 = ws + off; off += (size_t)B_ * N_ * 128;
    float* l3 = ws + off; off += (size_t)B_ * N_ * 256;
    float* xx = ws + off; off += (size_t)B_ * N_;
    float* D  = ws + off; off += (size_t)rowt * N_;
    float* Y  = D;
    float* ppool = D;
    float* psw   = D + (size_t)B_ * NSLAB * J_ * 451;
    int* knnIdx = (int*)(ws + off); off += (size_t)B_ * N_ * KNN_;
    float* pooled = ws + off; off += (size_t)B_ * J_ * 451;
    float* joints = ws + off; off += (size_t)B_ * J_ * 448;
    float* h1 = ws + off; off += (size_t)B_ * J_ * 512;
    float* h2 = ws + off; off += (size_t)B_ * J_ * 256;
    float* P1 = ws + off; off += szP1;
    float* P2 = ws + off; off += szP2;
    float* P3 = ws + off; off += szP3;
    float* P4 = ws + off; off += szP4;
    float* P5 = ws + off; off += szP5;
    float* P6 = ws + off; off += szP6;
    float* P7 = ws + off; off += szP7;
    float* P8 = ws + off; off += szP8;
    float* P9 = ws + off; off += szP9;
    float* bb1 = ws + off; off += 128;
    float* bb2 = ws + off; off += 256;
    float* bb3 = ws + off; off += 512;
    float* bb4 = ws + off; off += 512;
    float* bb5 = ws + off; off += 256;
    float* bb6 = ws + off; off += 128;

    const int M = B_ * N_;   // 16384
    const int MJ = B_ * J_;  // 96

    // ---- all weight prep in one launch (independent of data flow) ----
    k_prepall<<<dim3((szP4 + 255) / 256, 9), 256, 0, stream>>>(
        g1w, g1b, g2w, g2b, g3w, g3b, s1w, s1b, s2w, s2b, s3w, s3b,
        m1w, m2w, m3w, P1, P2, P3, P4, P5, P6, P7, P8, P9,
        bb1, bb2, bb3, bb4, bb5, bb6);

    // ======== geoNet layer 1: C=3 -> O=64 (fused dist+select, no D) ========
    k_norm<<<(M + 255) / 256, 256, 0, stream>>>(V, xx, 3);
    for (int b = 0; b < B_; ++b)
        k_selC3<<<N_, 256, 0, stream>>>(V + (size_t)b * N_ * 3, xx + b * N_,
                                        knnIdx + (size_t)b * N_ * KNN_);
    k_gemm<<<dim3(2, M / 64), 256, 0, stream>>>(V, 3, P1, Y, 128, M, 128, 3, bb1, 0);
    k_gathermax<<<M, 64, KNN_ * sizeof(int), stream>>>(Y, 64, N_, knnIdx, KNN_, l1, 64, 0, xx);

    // ======== layer 2: C=64 -> O=128 ========
    for (int b = 0; b < B_; ++b)
        for (int rb = 0; rb < N_; rb += rowt) {
            k_dist<<<dim3(32, rowt / 128), 256, 0, stream>>>(l1 + (size_t)b * N_ * 64, 64, xx + b * N_, D, rb);
            k_sel<<<rowt, 256, 0, stream>>>(D, knnIdx + (size_t)b * N_ * KNN_, rb);
        }
    k_gemm<<<dim3(4, M / 64), 256, 0, stream>>>(l1, 64, P2, Y, 256, M, 256, 64, bb2, 0);
    k_gathermax<<<M, 128, KNN_ * sizeof(int), stream>>>(Y, 128, N_, knnIdx, KNN_, l2, 128, 0, xx);

    // ======== layer 3: C=128 -> O=256 ========
    for (int b = 0; b < B_; ++b)
        for (int rb = 0; rb < N_; rb += rowt) {
            k_dist<<<dim3(32, rowt / 128), 256, 0, stream>>>(l2 + (size_t)b * N_ * 128, 128, xx + b * N_, D, rb);
            k_sel<<<rowt, 256, 0, stream>>>(D, knnIdx + (size_t)b * N_ * KNN_, rb);
        }
    k_gemm<<<dim3(8, M / 64), 256, 0, stream>>>(l2, 128, P3, Y, 512, M, 512, 128, bb3, 0);
    k_gathermax<<<M, 256, KNN_ * sizeof(int), stream>>>(Y, 256, N_, knnIdx, KNN_, l3, 256, 0, nullptr);

    // ======== pooling onto joints (two-phase) ========
    k_pool2<<<B_ * NSLAB, 256, 0, stream>>>(V, l1, l2, l3, W, ppool, psw);
    k_poolred<<<MJ, 256, 0, stream>>>(ppool, psw, pooled);

    // ======== skeleton convs (small-M GEMM path) ========
    k_sgemm<<<dim3(MJ, 2), 256, 451 * sizeof(float), stream>>>(pooled, 451, P4, Y, 512, 512, 451, bb4, 0);
    k_gathermax<<<MJ, 256, KR_ * sizeof(int), stream>>>(Y, 256, J_, ringIdx, KR_, joints, 448, 0, nullptr);

    k_sgemm<<<dim3(MJ, 1), 256, 256 * sizeof(float), stream>>>(joints, 448, P5, Y, 256, 256, 256, bb5, 0);
    k_gathermax<<<MJ, 128, KR_ * sizeof(int), stream>>>(Y, 128, J_, ringIdx, KR_, joints, 448, 256, nullptr);

    k_sgemm<<<dim3(MJ, 1), 256, 128 * sizeof(float), stream>>>(joints + 256, 448, P6, Y, 128, 128, 128, bb6, 0);
    k_gathermax<<<MJ, 64, KR_ * sizeof(int), stream>>>(Y, 64, J_, ringIdx, KR_, joints, 448, 384, nullptr);

    // ======== joint MLP ========
    k_sgemm<<<dim3(MJ, 2), 256, 448 * sizeof(float), stream>>>(joints, 448, P7, h1, 512, 512, 448, m1b, 1);
    k_sgemm<<<dim3(MJ, 1), 256, 512 * sizeof(float), stream>>>(h1, 512, P8, h2, 256, 256, 512, m2b, 1);
    k_sgemm<<<dim3(MJ, 1), 256, 256 * sizeof(float), stream>>>(h2, 256, P9, (float*)d_out, 3, 3, 256, m3b, 0);
}

// Round 12
// 1466.723 us; speedup vs baseline: 7.2757x; 1.0416x over previous
//
#include <hip/hip_runtime.h>
#include <hip/hip_bf16.h>
#include <float.h>

// Problem constants (from reference setup_inputs)
#define B_   4
#define N_   4096
#define J_   24
#define KR_  4
#define KNN_ 20
#define SLOPE 0.2f
#define SLABN 64             // points per pooling slab
#define NSLAB (N_ / SLABN)   // 64
#define NTILE 32             // 128-wide tiles per dim

// ---------- per-point squared norm ----------
__global__ void k_norm(const float* __restrict__ h, float* __restrict__ xx, int C) {
    int i = blockIdx.x * blockDim.x + threadIdx.x;
    if (i >= B_ * N_) return;
    const float* hp = h + (size_t)i * C;
    float s = 0.f;
    for (int c = 0; c < C; ++c) { float v = hp[c]; s += v * v; }
    xx[i] = s;
}

// ---------- symmetric distance GEMM: upper-triangular tiles only ----------
// D[n,m] = xx[n]+xx[m]-2*dot. Off-diagonal tiles also store the mirrored tile
// via LDS transpose (bit-identical: products commute, same summation order).
__global__ __launch_bounds__(256) void k_dist(const float* __restrict__ X, int C,
                                              const float* __restrict__ xxb,
                                              float* __restrict__ D) {
    __shared__ float As[16][132];
    __shared__ float Bs[16][132];
    int t = blockIdx.x;                      // linear upper-tri tile id
    int ti = 0;
    while (t >= NTILE - ti) { t -= NTILE - ti; ++ti; }
    int tj = ti + t;
    int row0 = ti * 128, col0 = tj * 128;
    int tid = threadIdx.x;
    int tr = tid >> 4, tc = tid & 15;
    float acc[8][8] = {{0.f}};
    for (int kt = 0; kt < C; kt += 16) {
#pragma unroll
        for (int i = 0; i < 8; ++i) {
            int e = tid + 256 * i;
            int r = e >> 4, kk = e & 15;
            int gk = kt + kk;
            As[kk][r] = (gk < C) ? X[(size_t)(row0 + r) * C + gk] : 0.f;
            Bs[kk][r] = (gk < C) ? X[(size_t)(col0 + r) * C + gk] : 0.f;
        }
        __syncthreads();
#pragma unroll
        for (int kk = 0; kk < 16; ++kk) {
            float a[8], bv[8];
            *(float4*)&a[0]  = *(const float4*)&As[kk][tr * 4];
            *(float4*)&a[4]  = *(const float4*)&As[kk][64 + tr * 4];
            *(float4*)&bv[0] = *(const float4*)&Bs[kk][tc * 4];
            *(float4*)&bv[4] = *(const float4*)&Bs[kk][64 + tc * 4];
#pragma unroll
            for (int i = 0; i < 8; ++i)
#pragma unroll
                for (int j = 0; j < 8; ++j) acc[i][j] += a[i] * bv[j];
        }
        __syncthreads();
    }
    float xc[8], xr[8];
#pragma unroll
    for (int j = 0; j < 4; ++j) {
        xc[j]     = xxb[col0 + tc * 4 + j];
        xc[4 + j] = xxb[col0 + 64 + tc * 4 + j];
        xr[j]     = xxb[row0 + tr * 4 + j];
        xr[4 + j] = xxb[row0 + 64 + tr * 4 + j];
    }
    // ---- direct store (rows row0.., cols col0..) ----
#pragma unroll
    for (int i = 0; i < 8; ++i) {
        int lr = (i < 4) ? (tr * 4 + i) : (64 + tr * 4 + (i - 4));
        float xri = xr[i];
        float4 o0, o1;
        o0.x = xri + xc[0] - 2.f * acc[i][0];
        o0.y = xri + xc[1] - 2.f * acc[i][1];
        o0.z = xri + xc[2] - 2.f * acc[i][2];
        o0.w = xri + xc[3] - 2.f * acc[i][3];
        o1.x = xri + xc[4] - 2.f * acc[i][4];
        o1.y = xri + xc[5] - 2.f * acc[i][5];
        o1.z = xri + xc[6] - 2.f * acc[i][6];
        o1.w = xri + xc[7] - 2.f * acc[i][7];
        float* dp = D + (size_t)(row0 + lr) * N_ + col0;
        *(float4*)(dp + tc * 4)      = o0;
        *(float4*)(dp + 64 + tc * 4) = o1;
    }
    if (ti == tj) return;
    // ---- mirrored store via LDS transpose, 4 passes of 32 dt-rows ----
    float* tb = &As[0][0];                   // 32*132 floats = As+Bs union
    for (int p = 0; p < 4; ++p) {
        __syncthreads();                     // previous pass reads done
        int h = p >> 1;                      // col half
        int tclo = (p & 1) * 8;
        if (tc >= tclo && tc < tclo + 8) {
#pragma unroll
            for (int jj = 0; jj < 4; ++jj) {
                int j = h * 4 + jj;
                int cl = h * 64 + tc * 4 + jj - 32 * p;   // 0..31
                float xcj = xc[j];
                float4 vlo, vhi;
                vlo.x = xr[0] + xcj - 2.f * acc[0][j];
                vlo.y = xr[1] + xcj - 2.f * acc[1][j];
                vlo.z = xr[2] + xcj - 2.f * acc[2][j];
                vlo.w = xr[3] + xcj - 2.f * acc[3][j];
                vhi.x = xr[4] + xcj - 2.f * acc[4][j];
                vhi.y = xr[5] + xcj - 2.f * acc[5][j];
                vhi.z = xr[6] + xcj - 2.f * acc[6][j];
                vhi.w = xr[7] + xcj - 2.f * acc[7][j];
                *(float4*)&tb[cl * 132 + tr * 4]      = vlo;
                *(float4*)&tb[cl * 132 + 64 + tr * 4] = vhi;
            }
        }
        __syncthreads();
        int rl  = tid >> 3;                  // 0..31 dt-row in pass
        int c16 = (tid & 7) * 16;
#pragma unroll
        for (int q = 0; q < 4; ++q) {
            float4 v = *(const float4*)&tb[rl * 132 + c16 + q * 4];
            *(float4*)(D + (size_t)(col0 + 32 * p + rl) * N_ + row0 + c16 + q * 4) = v;
        }
    }
}

// ---------- key mapping: monotone f32 -> u32 ----------
__device__ __forceinline__ unsigned mapf(float f) {
    unsigned u = __float_as_uint(f);
    return (u & 0x80000000u) ? ~u : (u | 0x80000000u);
}

// ---------- fused top-20 selection over materialized D ----------
__global__ __launch_bounds__(256) void k_sel(const float* __restrict__ Db,
                                             int* __restrict__ idxout, int qbase) {
    const unsigned long long SENT = ~0ull;
    const unsigned INV = 0xFFFFFFFFu;
    __shared__ unsigned long long qcs[80];
    int ql   = blockIdx.x;
    int wv   = threadIdx.x >> 6;
    int lane = threadIdx.x & 63;
    int gbase = wv * 1024 + lane * 16;
    const float* seg = Db + (size_t)ql * N_ + gbase;

    float4 v4[4];
    v4[0] = *(const float4*)(seg);
    v4[1] = *(const float4*)(seg + 4);
    v4[2] = *(const float4*)(seg + 8);
    v4[3] = *(const float4*)(seg + 12);
    const float* vv = (const float*)v4;

    unsigned b0v = INV, b0i = INV, b1v = INV, b1i = INV;
    unsigned emask = 0;
#pragma unroll
    for (int t = 0; t < 16; ++t) {
        unsigned kv = mapf(vv[t]);
        if (kv < b1v) {
            if (kv < b0v) { b1v = b0v; b1i = b0i; b0v = kv; b0i = (unsigned)(gbase + t); }
            else          { b1v = kv; b1i = (unsigned)(gbase + t); }
        }
    }
    for (int k = 0; k < KNN_; ++k) {
        if (b0i == INV) {
            b1v = INV; b1i = INV;
            for (int t = 0; t < 16; ++t) {
                if ((emask >> t) & 1u) continue;
                unsigned kv = mapf(seg[t]);
                if (kv < b1v) {
                    if (kv < b0v) { b1v = b0v; b1i = b0i; b0v = kv; b0i = (unsigned)(gbase + t); }
                    else          { b1v = kv; b1i = (unsigned)(gbase + t); }
                }
            }
        }
        unsigned m = b0v;
#pragma unroll
        for (int s = 32; s > 0; s >>= 1) {
            unsigned o = (unsigned)__shfl_xor((int)m, s, 64);
            m = (o < m) ? o : m;
        }
        unsigned long long ball = __ballot(b0v == m);
        int owner = __ffsll((long long)ball) - 1;
        unsigned idx = (unsigned)__shfl((int)b0i, owner, 64);
        if (lane == owner) {
            emask |= 1u << (b0i & 15u);
            b0v = b1v; b0i = b1i; b1v = INV; b1i = INV;
        }
        if (lane == 0) qcs[wv * KNN_ + k] = ((unsigned long long)m << 32) | idx;
    }
    __syncthreads();
    if (wv == 0) {
        unsigned long long c0 = qcs[lane];
        unsigned long long c1 = (lane < 16) ? qcs[64 + lane] : SENT;
        if (c1 < c0) { unsigned long long t = c0; c0 = c1; c1 = t; }
        int qg = qbase + ql;
        for (int k = 0; k < KNN_; ++k) {
            unsigned long long m = c0;
#pragma unroll
            for (int s = 32; s > 0; s >>= 1) {
                unsigned long long o = (unsigned long long)__shfl_xor((long long)m, s, 64);
                if (o < m) m = o;
            }
            if (m == c0) { c0 = c1; c1 = SENT; }
            if (lane == 0) idxout[qg * KNN_ + k] = (int)(unsigned)m;
        }
    }
}

// ---------- layer-1 fused dist+select (C=3), all batches in one launch ----------
__global__ __launch_bounds__(256) void k_selC3(const float* __restrict__ V,
                                               const float* __restrict__ xx,
                                               int* __restrict__ knnIdx) {
    const unsigned long long SENT = ~0ull;
    const unsigned INV = 0xFFFFFFFFu;
    __shared__ unsigned long long qcs[80];
    int b    = blockIdx.y;
    const float* Xb  = V + (size_t)b * N_ * 3;
    const float* xxb = xx + (size_t)b * N_;
    int* idxout = knnIdx + (size_t)b * N_ * KNN_;
    int q    = blockIdx.x;
    int wv   = threadIdx.x >> 6;
    int lane = threadIdx.x & 63;
    int gbase = wv * 1024 + lane * 16;

    float qx = Xb[q * 3], qy = Xb[q * 3 + 1], qz = Xb[q * 3 + 2];
    float xxq = xxb[q];

    float pts[48];
    const float4* src = (const float4*)(Xb + (size_t)gbase * 3);
#pragma unroll
    for (int t = 0; t < 12; ++t) ((float4*)pts)[t] = src[t];
    float xxm[16];
#pragma unroll
    for (int t = 0; t < 16; ++t) xxm[t] = xxb[gbase + t];

    auto distf = [&](int t) -> float {
        float dot = qx * pts[3 * t];
        dot = fmaf(qy, pts[3 * t + 1], dot);
        dot = fmaf(qz, pts[3 * t + 2], dot);
        return xxq + xxm[t] - 2.f * dot;
    };

    unsigned b0v = INV, b0i = INV, b1v = INV, b1i = INV;
    unsigned emask = 0;
#pragma unroll
    for (int t = 0; t < 16; ++t) {
        unsigned kv = mapf(distf(t));
        if (kv < b1v) {
            if (kv < b0v) { b1v = b0v; b1i = b0i; b0v = kv; b0i = (unsigned)(gbase + t); }
            else          { b1v = kv; b1i = (unsigned)(gbase + t); }
        }
    }
    for (int k = 0; k < KNN_; ++k) {
        if (b0i == INV) {
            b1v = INV; b1i = INV;
            for (int t = 0; t < 16; ++t) {
                if ((emask >> t) & 1u) continue;
                unsigned kv = mapf(distf(t));
                if (kv < b1v) {
                    if (kv < b0v) { b1v = b0v; b1i = b0i; b0v = kv; b0i = (unsigned)(gbase + t); }
                    else          { b1v = kv; b1i = (unsigned)(gbase + t); }
                }
            }
        }
        unsigned m = b0v;
#pragma unroll
        for (int s = 32; s > 0; s >>= 1) {
            unsigned o = (unsigned)__shfl_xor((int)m, s, 64);
            m = (o < m) ? o : m;
        }
        unsigned long long ball = __ballot(b0v == m);
        int owner = __ffsll((long long)ball) - 1;
        unsigned idx = (unsigned)__shfl((int)b0i, owner, 64);
        if (lane == owner) {
            emask |= 1u << (b0i & 15u);
            b0v = b1v; b0i = b1i; b1v = INV; b1i = INV;
        }
        if (lane == 0) qcs[wv * KNN_ + k] = ((unsigned long long)m << 32) | idx;
    }
    __syncthreads();
    if (wv == 0) {
        unsigned long long c0 = qcs[lane];
        unsigned long long c1 = (lane < 16) ? qcs[64 + lane] : SENT;
        if (c1 < c0) { unsigned long long t = c0; c0 = c1; c1 = t; }
        for (int k = 0; k < KNN_; ++k) {
            unsigned long long m = c0;
#pragma unroll
            for (int s = 32; s > 0; s >>= 1) {
                unsigned long long o = (unsigned long long)__shfl_xor((long long)m, s, 64);
                if (o < m) m = o;
            }
            if (m == c0) { c0 = c1; c1 = SENT; }
            if (lane == 0) idxout[q * KNN_ + k] = (int)(unsigned)m;
        }
    }
}

// ---------- fused weight prep ----------
__device__ __forceinline__ void prepP_elem(const float* __restrict__ w,
                                           const float* __restrict__ bias,
                                           int C, int O, float* __restrict__ P,
                                           float* __restrict__ b2, int i) {
    int O2 = 2 * O;
    if (i < O2) b2[i] = (i < O) ? 0.f : bias[i - O];
    if (i >= C * O2) return;
    int k = i / O2, col = i % O2;
    float v;
    if (col < O) v = w[(size_t)col * 2 * C + k];
    else { int o = col - O; v = w[(size_t)o * 2 * C + C + k] - w[(size_t)o * 2 * C + k]; }
    P[i] = v;
}
__device__ __forceinline__ void transp_elem(const float* __restrict__ w, int O, int K,
                                            float* __restrict__ wT, int i) {
    if (i >= O * K) return;
    int k = i / O, o = i % O;
    wT[i] = w[(size_t)o * K + k];
}

__global__ void k_prepall(const float* g1w, const float* g1b,
                          const float* g2w, const float* g2b,
                          const float* g3w, const float* g3b,
                          const float* s1w, const float* s1b,
                          const float* s2w, const float* s2b,
                          const float* s3w, const float* s3b,
                          const float* m1w, const float* m2w, const float* m3w,
                          float* P1, float* P2, float* P3, float* P4, float* P5,
                          float* P6, float* P7, float* P8, float* P9,
                          float* bb1, float* bb2, float* bb3,
                          float* bb4, float* bb5, float* bb6) {
    int i = blockIdx.x * 256 + threadIdx.x;
    switch (blockIdx.y) {
        case 0: prepP_elem(g1w, g1b, 3,   64,  P1, bb1, i); break;
        case 1: prepP_elem(g2w, g2b, 64,  128, P2, bb2, i); break;
        case 2: prepP_elem(g3w, g3b, 128, 256, P3, bb3, i); break;
        case 3: prepP_elem(s1w, s1b, 451, 256, P4, bb4, i); break;
        case 4: prepP_elem(s2w, s2b, 256, 128, P5, bb5, i); break;
        case 5: prepP_elem(s3w, s3b, 128, 64,  P6, bb6, i); break;
        case 6: transp_elem(m1w, 512, 448, P7, i); break;
        case 7: transp_elem(m2w, 256, 512, P8, i); break;
        case 8: transp_elem(m3w, 3,   256, P9, i); break;
    }
}

// ---------- tiled f32 GEMM (large M) ----------
__global__ __launch_bounds__(256) void k_gemm(const float* __restrict__ A, int lda,
                                              const float* __restrict__ Bm,
                                              float* __restrict__ Cm, int ldc,
                                              int M, int N, int K,
                                              const float* __restrict__ bias, int leaky) {
    __shared__ float As[16][68];
    __shared__ float Bs[16][68];
    int tid = threadIdx.x;
    int row0 = blockIdx.y * 64, col0 = blockIdx.x * 64;
    int tr = tid >> 4, tc = tid & 15;
    float acc[4][4] = {{0.f}};
    for (int kt = 0; kt < K; kt += 16) {
#pragma unroll
        for (int i = 0; i < 4; ++i) {
            int e = tid + 256 * i;
            int r = e >> 4, kk = e & 15;
            int gr = row0 + r, gk = kt + kk;
            float v = 0.f;
            if (gr < M && gk < K) v = A[(size_t)gr * lda + gk];
            As[kk][r] = v;
        }
#pragma unroll
        for (int i = 0; i < 4; ++i) {
            int e = tid + 256 * i;
            int kk = e >> 6, c = e & 63;
            int gk = kt + kk, gc = col0 + c;
            float v = 0.f;
            if (gk < K && gc < N) v = Bm[(size_t)gk * N + gc];
            Bs[kk][c] = v;
        }
        __syncthreads();
#pragma unroll
        for (int kk = 0; kk < 16; ++kk) {
            float a[4], bv[4];
            *(float4*)&a[0]  = *(const float4*)&As[kk][tr * 4];
            *(float4*)&bv[0] = *(const float4*)&Bs[kk][tc * 4];
#pragma unroll
            for (int i = 0; i < 4; ++i)
#pragma unroll
                for (int j = 0; j < 4; ++j) acc[i][j] += a[i] * bv[j];
        }
        __syncthreads();
    }
#pragma unroll
    for (int i = 0; i < 4; ++i) {
        int r = row0 + tr * 4 + i;
        if (r >= M) continue;
#pragma unroll
        for (int j = 0; j < 4; ++j) {
            int c = col0 + tc * 4 + j;
            if (c >= N) continue;
            float v = acc[i][j];
            if (bias) v += bias[c];
            if (leaky) v = v >= 0.f ? v : SLOPE * v;
            Cm[(size_t)r * ldc + c] = v;
        }
    }
}

// ---------- small-M GEMM ----------
__global__ __launch_bounds__(256) void k_sgemm(const float* __restrict__ A, int lda,
                                               const float* __restrict__ Bm,
                                               float* __restrict__ Cm, int ldc,
                                               int N, int K,
                                               const float* __restrict__ bias, int leaky) {
    extern __shared__ float Arow[];
    int r   = blockIdx.x;
    int c0  = blockIdx.y * 256;
    int tid = threadIdx.x;
    for (int k = tid; k < K; k += 256) Arow[k] = A[(size_t)r * lda + k];
    __syncthreads();
    int c = c0 + tid;
    if (c >= N) return;
    float acc = bias ? bias[c] : 0.f;
    for (int k = 0; k < K; ++k) acc += Arow[k] * Bm[(size_t)k * N + c];
    if (leaky) acc = acc >= 0.f ? acc : SLOPE * acc;
    Cm[(size_t)r * ldc + c] = acc;
}

// ---------- gather-max epilogue (+ optional fused row-norm) ----------
__global__ void k_gathermax(const float* __restrict__ Y, int O, int R,
                            const int* __restrict__ idx, int kc,
                            float* __restrict__ out, int ldo, int ooff,
                            float* __restrict__ xxout) {
    extern __shared__ int sidx[];
    __shared__ float red[256];
    int br = blockIdx.x;
    int b  = br / R;
    int o  = threadIdx.x;
    if (o < kc) sidx[o] = idx[(size_t)br * kc + o];
    __syncthreads();
    int O2 = 2 * O;
    float z = Y[(size_t)br * O2 + O + o];
    float best = -FLT_MAX;
    for (int k = 0; k < kc; ++k) {
        int m = sidx[k];
        best = fmaxf(best, Y[(size_t)(b * R + m) * O2 + o]);
    }
    float r = z + best;
    r = r >= 0.f ? r : SLOPE * r;
    out[(size_t)br * ldo + ooff + o] = r;
    if (xxout) {
        red[o] = r * r;
        __syncthreads();
        for (int s = blockDim.x >> 1; s > 0; s >>= 1) {
            if (o < s) red[o] += red[o + s];
            __syncthreads();
        }
        if (o == 0) xxout[br] = red[0];
    }
}

// ---------- channel map ----------
__device__ __forceinline__ void chan_map(int b, int c,
                                         const float* Vf, const float* l1,
                                         const float* l2, const float* l3,
                                         const float*& p, int& st) {
    if (c < 3)        { st = 3;   p = Vf + (size_t)b * N_ * 3   + c; }
    else if (c < 67)  { st = 64;  p = l1 + (size_t)b * N_ * 64  + (c - 3); }
    else if (c < 195) { st = 128; p = l2 + (size_t)b * N_ * 128 + (c - 67); }
    else              { st = 256; p = l3 + (size_t)b * N_ * 256 + (c - 195); }
}

// ---------- pooling phase 1 ----------
__global__ __launch_bounds__(256) void k_pool2(const float* __restrict__ Vf,
                                               const float* __restrict__ l1,
                                               const float* __restrict__ l2,
                                               const float* __restrict__ l3,
                                               const float* __restrict__ W,
                                               float* __restrict__ ppool,
                                               float* __restrict__ psw) {
    __shared__ float Wl[SLABN][J_];
    int blk  = blockIdx.x;
    int b    = blk / NSLAB, slab = blk % NSLAB;
    int n0   = slab * SLABN;
    int tid  = threadIdx.x;

    for (int e = tid; e < J_ * SLABN; e += 256) {
        int j = e / SLABN, n = e % SLABN;
        Wl[n][j] = W[((size_t)b * J_ + j) * N_ + n0 + n];
    }
    __syncthreads();

    if (tid < J_) {
        float s = 0.f;
        for (int n = 0; n < SLABN; ++n) s += Wl[n][tid];
        psw[(size_t)blk * J_ + tid] = s;
    }

    int c0 = tid, c1 = tid + 256;
    const float *p0, *p1 = nullptr; int s0, s1 = 0;
    chan_map(b, c0, Vf, l1, l2, l3, p0, s0);
    bool has1 = (c1 < 451);
    if (has1) chan_map(b, c1, Vf, l1, l2, l3, p1, s1);

    float acc0[J_], acc1[J_];
#pragma unroll
    for (int j = 0; j < J_; ++j) { acc0[j] = 0.f; acc1[j] = 0.f; }

    for (int n = 0; n < SLABN; ++n) {
        float v0 = p0[(size_t)(n0 + n) * s0];
        float v1 = has1 ? p1[(size_t)(n0 + n) * s1] : 0.f;
        const float* wn = &Wl[n][0];
#pragma unroll
        for (int q = 0; q < J_ / 4; ++q) {
            float4 w4 = *(const float4*)(wn + 4 * q);
            acc0[4*q+0] += w4.x * v0;  acc1[4*q+0] += w4.x * v1;
            acc0[4*q+1] += w4.y * v0;  acc1[4*q+1] += w4.y * v1;
            acc0[4*q+2] += w4.z * v0;  acc1[4*q+2] += w4.z * v1;
            acc0[4*q+3] += w4.w * v0;  acc1[4*q+3] += w4.w * v1;
        }
    }
    float* pp = ppool + (size_t)blk * J_ * 451;
#pragma unroll
    for (int j = 0; j < J_; ++j) {
        pp[(size_t)j * 451 + c0] = acc0[j];
        if (has1) pp[(size_t)j * 451 + c1] = acc1[j];
    }
}

// ---------- pooling phase 2 ----------
__global__ __launch_bounds__(256) void k_poolred(const float* __restrict__ ppool,
                                                 const float* __restrict__ psw,
                                                 float* __restrict__ pooled) {
    int bj = blockIdx.x;
    int b  = bj / J_, j = bj % J_;
    int tid = threadIdx.x;

    float sw = 0.f;
    for (int sl = 0; sl < NSLAB; ++sl) sw += psw[(size_t)(b * NSLAB + sl) * J_ + j];
    float inv = 1.f / (sw + 1e-5f);

    for (int c = tid; c < 451; c += 256) {
        float s = 0.f;
        for (int sl = 0; sl < NSLAB; ++sl)
            s += ppool[((size_t)(b * NSLAB + sl) * J_ + j) * 451 + c];
        pooled[(size_t)bj * 451 + c] = s * inv;
    }
}

extern "C" void kernel_launch(void* const* d_in, const int* in_sizes, int n_in,
                              void* d_out, int out_size, void* d_ws, size_t ws_size,
                              hipStream_t stream) {
    const float* V  = (const float*)d_in[0];
    const float* W  = (const float*)d_in[1];
    const int* ringIdx = (const int*)d_in[2];
    const float* g1w = (const float*)d_in[3];
    const float* g1b = (const float*)d_in[4];
    const float* g2w = (const float*)d_in[5];
    const float* g2b = (const float*)d_in[6];
    const float* g3w = (const float*)d_in[7];
    const float* g3b = (const float*)d_in[8];
    const float* s1w = (const float*)d_in[9];
    const float* s1b = (const float*)d_in[10];
    const float* s2w = (const float*)d_in[11];
    const float* s2b = (const float*)d_in[12];
    const float* s3w = (const float*)d_in[13];
    const float* s3b = (const float*)d_in[14];
    const float* m1w = (const float*)d_in[15];
    const float* m1b = (const float*)d_in[16];
    const float* m2w = (const float*)d_in[17];
    const float* m2b = (const float*)d_in[18];
    const float* m3w = (const float*)d_in[19];
    const float* m3b = (const float*)d_in[20];
    (void)n_in; (void)in_sizes; (void)out_size; (void)ws_size;

    const int szP1 = 3 * 128,    szP2 = 64 * 256,  szP3 = 128 * 512;
    const int szP4 = 451 * 512,  szP5 = 256 * 256, szP6 = 128 * 128;
    const int szP7 = 448 * 512,  szP8 = 512 * 256, szP9 = 256 * 3;

    // ---- workspace layout (floats); D = full N x N (64 MB, proven fit) ----
    float* ws = (float*)d_ws;
    size_t off = 0;
    float* l1 = ws + off; off += (size_t)B_ * N_ * 64;
    float* l2 = ws + off; off += (size_t)B_ * N_ * 128;
    float* l3 = ws + off; off += (size_t)B_ * N_ * 256;
    float* xx = ws + off; off += (size_t)B_ * N_;
    float* D  = ws + off; off += (size_t)N_ * N_;
    float* Y  = D;
    float* ppool = D;
    float* psw   = D + (size_t)B_ * NSLAB * J_ * 451;
    int* knnIdx = (int*)(ws + off); off += (size_t)B_ * N_ * KNN_;
    float* pooled = ws + off; off += (size_t)B_ * J_ * 451;
    float* joints = ws + off; off += (size_t)B_ * J_ * 448;
    float* h1 = ws + off; off += (size_t)B_ * J_ * 512;
    float* h2 = ws + off; off += (size_t)B_ * J_ * 256;
    float* P1 = ws + off; off += szP1;
    float* P2 = ws + off; off += szP2;
    float* P3 = ws + off; off += szP3;
    float* P4 = ws + off; off += szP4;
    float* P5 = ws + off; off += szP5;
    float* P6 = ws + off; off += szP6;
    float* P7 = ws + off; off += szP7;
    float* P8 = ws + off; off += szP8;
    float* P9 = ws + off; off += szP9;
    float* bb1 = ws + off; off += 128;
    float* bb2 = ws + off; off += 256;
    float* bb3 = ws + off; off += 512;
    float* bb4 = ws + off; off += 512;
    float* bb5 = ws + off; off += 256;
    float* bb6 = ws + off; off += 128;

    const int M = B_ * N_;   // 16384
    const int MJ = B_ * J_;  // 96
    const int NUTRI = NTILE * (NTILE + 1) / 2;   // 528 upper-tri tiles

    // ---- all weight prep in one launch ----
    k_prepall<<<dim3((szP4 + 255) / 256, 9), 256, 0, stream>>>(
        g1w, g1b, g2w, g2b, g3w, g3b, s1w, s1b, s2w, s2b, s3w, s3b,
        m1w, m2w, m3w, P1, P2, P3, P4, P5, P6, P7, P8, P9,
        bb1, bb2, bb3, bb4, bb5, bb6);

    // ======== geoNet layer 1: C=3 -> O=64 (fused dist+select, all batches) ========
    k_norm<<<(M + 255) / 256, 256, 0, stream>>>(V, xx, 3);
    k_selC3<<<dim3(N_, B_), 256, 0, stream>>>(V, xx, knnIdx);
    k_gemm<<<dim3(2, M / 64), 256, 0, stream>>>(V, 3, P1, Y, 128, M, 128, 3, bb1, 0);
    k_gathermax<<<M, 64, KNN_ * sizeof(int), stream>>>(Y, 64, N_, knnIdx, KNN_, l1, 64, 0, xx);

    // ======== layer 2: C=64 -> O=128 ========
    for (int b = 0; b < B_; ++b) {
        k_dist<<<NUTRI, 256, 0, stream>>>(l1 + (size_t)b * N_ * 64, 64, xx + b * N_, D);
        k_sel<<<N_, 256, 0, stream>>>(D, knnIdx + (size_t)b * N_ * KNN_, 0);
    }
    k_gemm<<<dim3(4, M / 64), 256, 0, stream>>>(l1, 64, P2, Y, 256, M, 256, 64, bb2, 0);
    k_gathermax<<<M, 128, KNN_ * sizeof(int), stream>>>(Y, 128, N_, knnIdx, KNN_, l2, 128, 0, xx);

    // ======== layer 3: C=128 -> O=256 ========
    for (int b = 0; b < B_; ++b) {
        k_dist<<<NUTRI, 256, 0, stream>>>(l2 + (size_t)b * N_ * 128, 128, xx + b * N_, D);
        k_sel<<<N_, 256, 0, stream>>>(D, knnIdx + (size_t)b * N_ * KNN_, 0);
    }
    k_gemm<<<dim3(8, M / 64), 256, 0, stream>>>(l2, 128, P3, Y, 512, M, 512, 128, bb3, 0);
    k_gathermax<<<M, 256, KNN_ * sizeof(int), stream>>>(Y, 256, N_, knnIdx, KNN_, l3, 256, 0, nullptr);

    // ======== pooling onto joints ========
    k_pool2<<<B_ * NSLAB, 256, 0, stream>>>(V, l1, l2, l3, W, ppool, psw);
    k_poolred<<<MJ, 256, 0, stream>>>(ppool, psw, pooled);

    // ======== skeleton convs ========
    k_sgemm<<<dim3(MJ, 2), 256, 451 * sizeof(float), stream>>>(pooled, 451, P4, Y, 512, 512, 451, bb4, 0);
    k_gathermax<<<MJ, 256, KR_ * sizeof(int), stream>>>(Y, 256, J_, ringIdx, KR_, joints, 448, 0, nullptr);

    k_sgemm<<<dim3(MJ, 1), 256, 256 * sizeof(float), stream>>>(joints, 448, P5, Y, 256, 256, 256, bb5, 0);
    k_gathermax<<<MJ, 128, KR_ * sizeof(int), stream>>>(Y, 128, J_, ringIdx, KR_, joints, 448, 256, nullptr);

    k_sgemm<<<dim3(MJ, 1), 256, 128 * sizeof(float), stream>>>(joints + 256, 448, P6, Y, 128, 128, 128, bb6, 0);
    k_gathermax<<<MJ, 64, KR_ * sizeof(int), stream>>>(Y, 64, J_, ringIdx, KR_, joints, 448, 384, nullptr);

    // ======== joint MLP ========
    k_sgemm<<<dim3(MJ, 2), 256, 448 * sizeof(float), stream>>>(joints, 448, P7, h1, 512, 512, 448, m1b, 1);
    k_sgemm<<<dim3(MJ, 1), 256, 512 * sizeof(float), stream>>>(h1, 512, P8, h2, 256, 256, 512, m2b, 1);
    k_sgemm<<<dim3(MJ, 1), 256, 256 * sizeof(float), stream>>>(h2, 256, P9, (float*)d_out, 3, 3, 256, m3b, 0);
}